// Round 13
// baseline (1170.617 us; speedup 1.0000x reference)
//
#include <hip/hip_runtime.h>
#include <hip/hip_bf16.h>

// ---------------------------------------------------------------------------
// TransformerBlock: B=2 N=2048 E=2048 H=16 G=4 D=128 HID=8192
// out = [ x2 (8.39M f32) | k_flat (8.39M) | v_flat (8.39M) | attn (134.2M) ]
// R13: REVERT gemm256 to R11 depth-2 (R12 depth-3 cost a block/CU: -28us).
//      kattn v6: PV phase reads V direct global->register, 4-deep rolling
//      prefetch (unroll-by-4, static reg names) -- replaces LDS V staging
//      whose depth-2 (~60cy slack) couldn't cover ~200cy L2 latency.
//      krope fusion (R12) kept. GeGLU R11 schedule kept.
// ---------------------------------------------------------------------------

using f32x4  = __attribute__((ext_vector_type(4))) float;
using bf16x8 = __attribute__((ext_vector_type(8))) short;
using bf16x4 = __attribute__((ext_vector_type(4))) short;
using u16x4  = __attribute__((ext_vector_type(4))) unsigned short;

#define DEV __device__ __forceinline__

// async global->LDS, 16B per lane; LDS dest must be wave-uniform base + lane*16
#define ASYNC16(lds, g)                                                        \
  __builtin_amdgcn_global_load_lds(                                           \
      (const __attribute__((address_space(1))) void*)(g),                      \
      (__attribute__((address_space(3))) void*)(lds), 16, 0, 0)

DEV unsigned short f2bf(float f) {
  unsigned int u = __float_as_uint(f);
  return (unsigned short)((u + 0x7fffu + ((u >> 16) & 1u)) >> 16);
}
DEV float bf2f(unsigned short h) {
  return __uint_as_float(((unsigned int)h) << 16);
}

DEV float waveRedSum(float v) {
#pragma unroll
  for (int o = 32; o; o >>= 1) v += __shfl_xor(v, o);
  return v;
}

// ---- transpose+convert: in f32 [K,N] -> out bf16 [N,K] ---------------------
__global__ __launch_bounds__(256) void kconvT(const float* __restrict__ in,
                                              unsigned short* __restrict__ out,
                                              int K, int N) {
  __shared__ float tile[32][33];
  int bx = blockIdx.x * 32;  // N dim
  int by = blockIdx.y * 32;  // K dim
  int tx = threadIdx.x & 31;
  int ty = threadIdx.x >> 5;  // 0..7
#pragma unroll
  for (int i = 0; i < 32; i += 8)
    tile[ty + i][tx] = in[(size_t)(by + ty + i) * N + bx + tx];
  __syncthreads();
#pragma unroll
  for (int i = 0; i < 32; i += 8)
    out[(size_t)(bx + ty + i) * K + by + tx] = f2bf(tile[tx][ty + i]);
}

// ---- RoPE + v_flat copy + bf16 casts (fused) -------------------------------
__global__ __launch_bounds__(256) void krope(const float* __restrict__ x,
                                             float* __restrict__ kout,
                                             float* __restrict__ vout,
                                             unsigned short* __restrict__ xq,
                                             unsigned short* __restrict__ xb) {
  int idx = blockIdx.x * 256 + threadIdx.x;  // B*N*H*64 = 4,194,304
  int f  = idx & 63;
  int h  = (idx >> 6) & 15;
  int bn = idx >> 10;          // b*2048+n
  int n  = bn & 2047;
  size_t base = (size_t)bn * 2048 + h * 128;
  float inv = exp2f((float)f * (-13.287712379549449f / 64.0f));
  float ang = (float)n * inv;
  float c = cosf(ang), s = sinf(ang);
  float a = x[base + f], b = x[base + f + 64];
  float k1 = a * c - b * s;
  float k2 = b * c + a * s;
  kout[base + f]      = k1;
  kout[base + f + 64] = k2;
  xq[base + f]      = f2bf(k1);
  xq[base + f + 64] = f2bf(k2);
  vout[base + f]      = a;
  vout[base + f + 64] = b;
  xb[base + f]      = f2bf(a);
  xb[base + f + 64] = f2bf(b);
}

// ---- x1b = bf16(rmsnorm(x + ao) * w) ---------------------------------------
__global__ __launch_bounds__(256) void krms1(const float* __restrict__ x,
                                             const float* __restrict__ ao,
                                             const float* __restrict__ w,
                                             unsigned short* __restrict__ x1b) {
  size_t row = blockIdx.x;
  const f32x4* xp = (const f32x4*)(x + row * 2048);
  const f32x4* ap = (const f32x4*)(ao + row * 2048);
  int tid = threadIdx.x;
  f32x4 t0 = xp[tid * 2] + ap[tid * 2];
  f32x4 t1 = xp[tid * 2 + 1] + ap[tid * 2 + 1];
  float ss = 0.f;
#pragma unroll
  for (int i = 0; i < 4; ++i) ss += t0[i] * t0[i] + t1[i] * t1[i];
  ss = waveRedSum(ss);
  __shared__ float red[4];
  int wid = tid >> 6, lane = tid & 63;
  if (!lane) red[wid] = ss;
  __syncthreads();
  ss = red[0] + red[1] + red[2] + red[3];
  float rr = rsqrtf(ss * (1.0f / 2048.0f) + 1e-6f);
  const f32x4* wp = (const f32x4*)w;
  f32x4 w0 = wp[tid * 2], w1 = wp[tid * 2 + 1];
  u16x4 o0, o1;
#pragma unroll
  for (int i = 0; i < 4; ++i) {
    o0[i] = f2bf(t0[i] * rr * w0[i]);
    o1[i] = f2bf(t1[i] * rr * w1[i]);
  }
  u16x4* op = (u16x4*)(x1b + row * 2048);
  op[tid * 2] = o0;
  op[tid * 2 + 1] = o1;
}

// ---- x2 = f32(rmsnorm(x1b + fc) * w) -> d_out ------------------------------
__global__ __launch_bounds__(256) void krms2(const unsigned short* __restrict__ x1b,
                                             const unsigned short* __restrict__ fc,
                                             const float* __restrict__ w,
                                             float* __restrict__ out) {
  size_t row = blockIdx.x;
  const u16x4* xp = (const u16x4*)(x1b + row * 2048);
  const u16x4* fp = (const u16x4*)(fc + row * 2048);
  int tid = threadIdx.x;
  u16x4 a0 = xp[tid * 2], a1 = xp[tid * 2 + 1];
  u16x4 b0 = fp[tid * 2], b1 = fp[tid * 2 + 1];
  f32x4 t0, t1;
#pragma unroll
  for (int i = 0; i < 4; ++i) {
    t0[i] = bf2f(a0[i]) + bf2f(b0[i]);
    t1[i] = bf2f(a1[i]) + bf2f(b1[i]);
  }
  float ss = 0.f;
#pragma unroll
  for (int i = 0; i < 4; ++i) ss += t0[i] * t0[i] + t1[i] * t1[i];
  ss = waveRedSum(ss);
  __shared__ float red[4];
  int wid = tid >> 6, lane = tid & 63;
  if (!lane) red[wid] = ss;
  __syncthreads();
  ss = red[0] + red[1] + red[2] + red[3];
  float rr = rsqrtf(ss * (1.0f / 2048.0f) + 1e-6f);
  const f32x4* wp = (const f32x4*)w;
  f32x4 w0 = wp[tid * 2], w1 = wp[tid * 2 + 1];
  f32x4* op = (f32x4*)(out + row * 2048);
  op[tid * 2]     = t0 * rr * w0;
  op[tid * 2 + 1] = t1 * rr * w1;
}

// ---- 128x128 MFMA GEMM (small shapes: k/v projections) ---------------------
template <bool OUT_BF16, bool TRANS_OUT>
__global__ __launch_bounds__(256, 2) void gemm_bt(
    const unsigned short* __restrict__ A, const unsigned short* __restrict__ Bt,
    void* __restrict__ C_, int K, int lda, int ldb, int ldc, float alpha) {
  __shared__ unsigned short As[128 * 32];
  __shared__ unsigned short Bs[128 * 32];
  const int tid = threadIdx.x;
  const int bm0 = blockIdx.y * 128, bn0 = blockIdx.x * 128;

  f32x4 acc[4][4] = {};

  const int lane = tid & 63, wid = tid >> 6;
  const int wr = wid >> 1, wc = wid & 1;
  const int lr = lane & 15, kq = lane >> 4;
  const int srow = tid >> 2;        // 0..63
  const int scol = (tid & 3) * 8;   // 0,8,16,24
  unsigned short* AsW = As + tid * 8;
  unsigned short* BsW = Bs + tid * 8;

  for (int kt = 0; kt < K; kt += 32) {
    ASYNC16(AsW,        A + (size_t)(bm0 + srow)      * lda + kt + scol);
    ASYNC16(AsW + 2048, A + (size_t)(bm0 + srow + 64) * lda + kt + scol);
    ASYNC16(BsW,        Bt + (size_t)(bn0 + srow)      * ldb + kt + scol);
    ASYNC16(BsW + 2048, Bt + (size_t)(bn0 + srow + 64) * ldb + kt + scol);
    __syncthreads();
    bf16x8 afr[4], bfr[4];
#pragma unroll
    for (int i = 0; i < 4; ++i)
      afr[i] = *(const bf16x8*)&As[(wr * 64 + i * 16 + lr) * 32 + kq * 8];
#pragma unroll
    for (int j = 0; j < 4; ++j)
      bfr[j] = *(const bf16x8*)&Bs[(wc * 64 + j * 16 + lr) * 32 + kq * 8];
#pragma unroll
    for (int i = 0; i < 4; ++i)
#pragma unroll
      for (int j = 0; j < 4; ++j)
        acc[i][j] = __builtin_amdgcn_mfma_f32_16x16x32_bf16(afr[i], bfr[j],
                                                            acc[i][j], 0, 0, 0);
    __syncthreads();
  }

#pragma unroll
  for (int i = 0; i < 4; ++i)
#pragma unroll
    for (int j = 0; j < 4; ++j) {
      int rowb = bm0 + wr * 64 + i * 16 + kq * 4;
      int col = bn0 + wc * 64 + j * 16 + lr;
#pragma unroll
      for (int r = 0; r < 4; ++r) {
        float v = acc[i][j][r] * alpha;
        size_t idx = TRANS_OUT ? ((size_t)col * ldc + (rowb + r))
                               : ((size_t)(rowb + r) * ldc + col);
        if constexpr (OUT_BF16)
          ((unsigned short*)C_)[idx] = f2bf(v);
        else
          ((float*)C_)[idx] = v;
      }
    }
}

// ===========================================================================
// Fused attention v6: scores = counted-vmcnt K staging (unchanged);
// PV = V direct global->register, 4-deep rolling prefetch (no LDS V).
// XCD-locality swizzle: g8 = bid&7 pins each (b,g) slice to one XCD.
// LDS ~66.5KB -> 2 blocks/CU.
// ===========================================================================
__global__ __launch_bounds__(512, 4) void kattn(
    const unsigned short* __restrict__ qh,   // [b][n][h*128+d] ld 2048
    const unsigned short* __restrict__ kh,   // [b][n][g*128+d] ld 512
    const unsigned short* __restrict__ vT,   // [g*128+d][b*2048+key] ld 4096
    float* __restrict__ attn,                // [b][h][q][key]
    unsigned short* __restrict__ ctx) {      // [b][n][h*128+d] ld 2048
  __shared__ __align__(16) char U[65536];    // K dbuf, then P
  __shared__ float redm[128], reds[128];

  const int tid = threadIdx.x;
  const int lane = tid & 63, w = tid >> 6;   // w 0..7
  const int lr = lane & 15, kq = lane >> 4;  // q = lr, quarter = kq
  const int bid = blockIdx.x;
  const int g8 = bid & 7;          // (b,g) slice, 0..7
  const int j  = bid >> 3;         // 0..511
  const int bz = g8 >> 2;          // batch
  const int gz = g8 & 3;           // kv group
  const int hz = gz * 4 + (j & 3); // head (hz>>2 == gz)
  const int q0 = (j >> 2) << 4;    // q-tile * 16
  const int z  = bz * 16 + hz;

  const unsigned short* Aq =
      qh + ((size_t)(bz * 2048 + q0 + lr) * 2048 + hz * 128);
  bf16x8 qfr[4];
#pragma unroll
  for (int kk = 0; kk < 4; ++kk)
    qfr[kk] = *(const bf16x8*)(Aq + kk * 32 + kq * 8);

  // --- scores: wave-private K staging, counted-vmcnt pipeline --------------
  const unsigned short* Kb =
      kh + ((size_t)(bz * 2048) * 512 + gz * 128);
  int krow[4], kcs[4];
#pragma unroll
  for (int R = 0; R < 4; ++R) {
    int idx = R * 64 + lane;
    krow[R] = idx >> 4;
    kcs[R] = (idx & 15) ^ (krow[R] & 7);  // pre-swizzled source chunk
  }
  auto stageK = [&](int buf, int t) {
#pragma unroll
    for (int R = 0; R < 4; ++R)
      ASYNC16(U + buf * 32768 + w * 4096 + (R * 64 + lane) * 16,
              Kb + (size_t)(t * 128 + w * 16 + krow[R]) * 512 + kcs[R] * 8);
  };

  f32x4 acc[16];
#pragma unroll
  for (int t = 0; t < 16; ++t) acc[t] = f32x4{0.f, 0.f, 0.f, 0.f};

  stageK(0, 0);
  stageK(1, 1);
#pragma unroll
  for (int t = 0; t < 16; ++t) {
    if (t < 15) asm volatile("s_waitcnt vmcnt(4)" ::: "memory");
    else        asm volatile("s_waitcnt vmcnt(0)" ::: "memory");
    __builtin_amdgcn_sched_barrier(0);
    const char* Kw = U + (t & 1) * 32768 + w * 4096;
    bf16x8 kfr[4];
#pragma unroll
    for (int kk = 0; kk < 4; ++kk) {
      int cch = (kk * 4 + kq) ^ (lr & 7);
      kfr[kk] = *(const bf16x8*)(Kw + lr * 256 + cch * 16);
    }
    asm volatile("s_waitcnt lgkmcnt(0)" ::: "memory");
    __builtin_amdgcn_sched_barrier(0);
    if (t + 2 < 16) stageK(t & 1, t + 2);  // reuse just-read buffer
#pragma unroll
    for (int kk = 0; kk < 4; ++kk)
      acc[t] = __builtin_amdgcn_mfma_f32_16x16x32_bf16(kfr[kk], qfr[kk],
                                                       acc[t], 0, 0, 0);
  }

  // --- softmax (per-lane q-row = lr) ---------------------------------------
  const float scale = 0.08838834764831845f;
  float mx = -3.4e38f;
#pragma unroll
  for (int t = 0; t < 16; ++t) {
    acc[t] *= scale;
#pragma unroll
    for (int r = 0; r < 4; ++r) mx = fmaxf(mx, acc[t][r]);
  }
  mx = fmaxf(mx, __shfl_xor(mx, 16));
  mx = fmaxf(mx, __shfl_xor(mx, 32));
  if (kq == 0) redm[w * 16 + lr] = mx;
  __syncthreads();  // barrier A
  mx = redm[lr];
#pragma unroll
  for (int ww = 1; ww < 8; ++ww) mx = fmaxf(mx, redm[ww * 16 + lr]);

  float sm = 0.f;
#pragma unroll
  for (int t = 0; t < 16; ++t) {
#pragma unroll
    for (int r = 0; r < 4; ++r) {
      float e = __expf(acc[t][r] - mx);
      acc[t][r] = e;
      sm += e;
    }
  }
  sm += __shfl_xor(sm, 16);
  sm += __shfl_xor(sm, 32);
  if (kq == 0) reds[w * 16 + lr] = sm;
  __syncthreads();  // barrier B
  float smt = reds[lr];
#pragma unroll
  for (int ww = 1; ww < 8; ++ww) smt += reds[ww * 16 + lr];
  float inv = 1.0f / smt;

  // --- write attn f32 + P bf16 into U (swizzled chunks) --------------------
  float* arow = attn + (((size_t)z * 2048 + q0 + lr) * 2048);
#pragma unroll
  for (int t = 0; t < 16; ++t) {
    int key = t * 128 + w * 16 + kq * 4;
    f32x4 p = acc[t] * inv;
    *(f32x4*)(arow + key) = p;
    bf16x4 pb;
#pragma unroll
    for (int r = 0; r < 4; ++r) pb[r] = (short)f2bf(p[r]);
    int c8 = key >> 3;  // 16B chunk index in q-row
    *(bf16x4*)(U + lr * 4096 + ((c8 ^ (lr & 7)) << 4) + ((key & 7) << 1)) = pb;
  }
  __syncthreads();  // barrier C: P ready block-wide

  // --- PV: V direct from global, 4-deep register prefetch ------------------
  // lane reads V[d0+lr][T*32 + kq*8 .. +8] for 32-key tile T (same bytes the
  // old LDS round-trip delivered; involution verified).
  const unsigned short* Bv = vT + (size_t)gz * 524288 + bz * 2048;
  const int d0 = w * 16;
  const unsigned short* Vp = Bv + (size_t)(d0 + lr) * 4096 + kq * 8;
  bf16x8 vr0 = *(const bf16x8*)(Vp);
  bf16x8 vr1 = *(const bf16x8*)(Vp + 32);
  bf16x8 vr2 = *(const bf16x8*)(Vp + 64);
  bf16x8 vr3 = *(const bf16x8*)(Vp + 96);
  f32x4 cfr = {};
#pragma unroll
  for (int tt = 0; tt < 64; tt += 4) {
    {
      bf16x8 p = *(const bf16x8*)(U + lr * 4096 +
                                  (((tt * 4 + kq) ^ (lr & 7)) << 4));
      cfr = __builtin_amdgcn_mfma_f32_16x16x32_bf16(p, vr0, cfr, 0, 0, 0);
      if (tt + 4 < 64) vr0 = *(const bf16x8*)(Vp + (tt + 4) * 32);
    }
    {
      bf16x8 p = *(const bf16x8*)(U + lr * 4096 +
                                  ((((tt + 1) * 4 + kq) ^ (lr & 7)) << 4));
      cfr = __builtin_amdgcn_mfma_f32_16x16x32_bf16(p, vr1, cfr, 0, 0, 0);
      if (tt + 5 < 64) vr1 = *(const bf16x8*)(Vp + (tt + 5) * 32);
    }
    {
      bf16x8 p = *(const bf16x8*)(U + lr * 4096 +
                                  ((((tt + 2) * 4 + kq) ^ (lr & 7)) << 4));
      cfr = __builtin_amdgcn_mfma_f32_16x16x32_bf16(p, vr2, cfr, 0, 0, 0);
      if (tt + 6 < 64) vr2 = *(const bf16x8*)(Vp + (tt + 6) * 32);
    }
    {
      bf16x8 p = *(const bf16x8*)(U + lr * 4096 +
                                  ((((tt + 3) * 4 + kq) ^ (lr & 7)) << 4));
      cfr = __builtin_amdgcn_mfma_f32_16x16x32_bf16(p, vr3, cfr, 0, 0, 0);
      if (tt + 7 < 64) vr3 = *(const bf16x8*)(Vp + (tt + 7) * 32);
    }
  }
#pragma unroll
  for (int r = 0; r < 4; ++r) {
    int q = kq * 4 + r;
    ctx[((size_t)(bz * 2048 + q0 + q) * 2048) + hz * 128 + d0 + lr] =
        f2bf(cfr[r]);
  }
}

// ===========================================================================
// 256x128 8-wave GEMM, BK=64 — R11 depth-2 counted-vmcnt pipeline (reverted
// from R12 depth-3: the 144KB LDS cost a block/CU, net -28us).
// ===========================================================================
template <bool OUT_BF16>
__global__ __launch_bounds__(512, 2) void gemm256(
    const unsigned short* __restrict__ A, const unsigned short* __restrict__ Bt,
    void* __restrict__ C_, int K, int lda, int ldb, int ldc) {
  __shared__ unsigned short As[2][256 * 64];  // 64 KB
  __shared__ unsigned short Bs[2][128 * 64];  // 32 KB
  const int tid = threadIdx.x;
  const int bm0 = blockIdx.y * 256, bn0 = blockIdx.x * 128;
  const int lane = tid & 63, wid = tid >> 6;
  const int wr = wid >> 2, wc = wid & 3;
  const int lr = lane & 15, kq = lane >> 4;

  f32x4 acc[8][2] = {};

  int sArow[4], sAcc[4], sBrow[2], sBcc[2];
#pragma unroll
  for (int R = 0; R < 4; ++R) {
    int c = R * 512 + tid;
    sArow[R] = c >> 3;
    sAcc[R]  = (c & 7) ^ (sArow[R] & 7);
  }
#pragma unroll
  for (int R = 0; R < 2; ++R) {
    int c = R * 512 + tid;
    sBrow[R] = c >> 3;
    sBcc[R]  = (c & 7) ^ (sBrow[R] & 7);
  }

  auto stage = [&](int buf, int k0) {  // 6 loads/thread
#pragma unroll
    for (int R = 0; R < 4; ++R)
      ASYNC16(&As[buf][(R * 512 + tid) * 8],
              A + (size_t)(bm0 + sArow[R]) * lda + k0 + sAcc[R] * 8);
#pragma unroll
    for (int R = 0; R < 2; ++R)
      ASYNC16(&Bs[buf][(R * 512 + tid) * 8],
              Bt + (size_t)(bn0 + sBrow[R]) * ldb + k0 + sBcc[R] * 8);
  };

  const int NT = K >> 6;
  stage(0, 0);
  stage(1, 64);
  int cur = 0;
  for (int t = 0; t < NT; ++t) {
    if (t + 1 < NT) asm volatile("s_waitcnt vmcnt(6)" ::: "memory");
    else            asm volatile("s_waitcnt vmcnt(0)" ::: "memory");
    __builtin_amdgcn_sched_barrier(0);
    __builtin_amdgcn_s_barrier();
    __builtin_amdgcn_sched_barrier(0);
    const unsigned short* Ac = As[cur];
    const unsigned short* Bc = Bs[cur];
    // ---- ks = 0 ----
    bf16x8 afr0[8], bfr0[2];
#pragma unroll
    for (int i = 0; i < 8; ++i) {
      int row = wr * 128 + i * 16 + lr;
      afr0[i] = *(const bf16x8*)&Ac[(row * 8 + (kq ^ (row & 7))) * 8];
    }
#pragma unroll
    for (int j2 = 0; j2 < 2; ++j2) {
      int brow = wc * 32 + j2 * 16 + lr;
      bfr0[j2] = *(const bf16x8*)&Bc[(brow * 8 + (kq ^ (brow & 7))) * 8];
    }
    __builtin_amdgcn_s_setprio(1);
#pragma unroll
    for (int j2 = 0; j2 < 2; ++j2)
#pragma unroll
      for (int i = 0; i < 8; ++i)
        acc[i][j2] = __builtin_amdgcn_mfma_f32_16x16x32_bf16(afr0[i], bfr0[j2],
                                                             acc[i][j2], 0, 0, 0);
    __builtin_amdgcn_s_setprio(0);
    // ---- ks = 1 ----
    bf16x8 afr1[8], bfr1[2];
#pragma unroll
    for (int i = 0; i < 8; ++i) {
      int row = wr * 128 + i * 16 + lr;
      afr1[i] = *(const bf16x8*)&Ac[(row * 8 + ((4 + kq) ^ (row & 7))) * 8];
    }
#pragma unroll
    for (int j2 = 0; j2 < 2; ++j2) {
      int brow = wc * 32 + j2 * 16 + lr;
      bfr1[j2] = *(const bf16x8*)&Bc[(brow * 8 + ((4 + kq) ^ (brow & 7))) * 8];
    }
    asm volatile("s_waitcnt lgkmcnt(0)" ::: "memory");
    __builtin_amdgcn_sched_barrier(0);
    __builtin_amdgcn_s_barrier();   // all waves' reads of buf[cur] done
    __builtin_amdgcn_sched_barrier(0);
    if (t + 2 < NT) stage(cur, (t + 2) << 6);
    __builtin_amdgcn_s_setprio(1);
#pragma unroll
    for (int j2 = 0; j2 < 2; ++j2)
#pragma unroll
      for (int i = 0; i < 8; ++i)
        acc[i][j2] = __builtin_amdgcn_mfma_f32_16x16x32_bf16(afr1[i], bfr1[j2],
                                                             acc[i][j2], 0, 0, 0);
    __builtin_amdgcn_s_setprio(0);
    cur ^= 1;
  }

#pragma unroll
  for (int i = 0; i < 8; ++i)
#pragma unroll
    for (int j = 0; j < 2; ++j) {
      int rowb = bm0 + wr * 128 + i * 16 + kq * 4;
      int col = bn0 + wc * 32 + j * 16 + lr;
#pragma unroll
      for (int r = 0; r < 4; ++r) {
        if constexpr (OUT_BF16)
          ((unsigned short*)C_)[(size_t)(rowb + r) * ldc + col] = f2bf(acc[i][j][r]);
        else
          ((float*)C_)[(size_t)(rowb + r) * ldc + col] = acc[i][j][r];
      }
    }
}

// ---- GeGLU dual GEMM: R11 depth-2 counted-vmcnt schedule (unchanged) -------
__global__ __launch_bounds__(512, 2) void gemm_geglu256(
    const unsigned short* __restrict__ A, const unsigned short* __restrict__ B1,
    const unsigned short* __restrict__ B2, unsigned short* __restrict__ H_,
    int K, int lda, int ldb, int ldc) {
  __shared__ unsigned short As[2][256 * 64];   // 64 KB
  __shared__ unsigned short B1s[2][128 * 64];  // 32 KB
  __shared__ unsigned short B2s[2][128 * 64];  // 32 KB
  const int tid = threadIdx.x;
  const int bm0 = blockIdx.y * 256, bn0 = blockIdx.x * 128;
  const int lane = tid & 63, wid = tid >> 6;
  const int wr = wid >> 2, wc = wid & 3;
  const int lr = lane & 15, kq = lane >> 4;

  f32x4 accu[8][2] = {};
  f32x4 accg[8][2] = {};

  int sArow[4], sAcc[4], sBrow[2], sBcc[2];
#pragma unroll
  for (int R = 0; R < 4; ++R) {
    int c = R * 512 + tid;
    sArow[R] = c >> 3;
    sAcc[R]  = (c & 7) ^ (sArow[R] & 7);
  }
#pragma unroll
  for (int R = 0; R < 2; ++R) {
    int c = R * 512 + tid;
    sBrow[R] = c >> 3;
    sBcc[R]  = (c & 7) ^ (sBrow[R] & 7);
  }

  auto stage = [&](int buf, int k0) {  // 8 loads/thread
#pragma unroll
    for (int R = 0; R < 4; ++R)
      ASYNC16(&As[buf][(R * 512 + tid) * 8],
              A + (size_t)(bm0 + sArow[R]) * lda + k0 + sAcc[R] * 8);
#pragma unroll
    for (int R = 0; R < 2; ++R)
      ASYNC16(&B1s[buf][(R * 512 + tid) * 8],
              B1 + (size_t)(bn0 + sBrow[R]) * ldb + k0 + sBcc[R] * 8);
#pragma unroll
    for (int R = 0; R < 2; ++R)
      ASYNC16(&B2s[buf][(R * 512 + tid) * 8],
              B2 + (size_t)(bn0 + sBrow[R]) * ldb + k0 + sBcc[R] * 8);
  };

  const int NT = K >> 6;
  stage(0, 0);
  stage(1, 64);
  int cur = 0;
  for (int t = 0; t < NT; ++t) {
    if (t + 1 < NT) asm volatile("s_waitcnt vmcnt(8)" ::: "memory");
    else            asm volatile("s_waitcnt vmcnt(0)" ::: "memory");
    __builtin_amdgcn_sched_barrier(0);
    __builtin_amdgcn_s_barrier();
    __builtin_amdgcn_sched_barrier(0);
    const unsigned short* Ac = As[cur];
    const unsigned short* B1c = B1s[cur];
    const unsigned short* B2c = B2s[cur];
    // ---- ks = 0 ----
    bf16x8 afr0[8], b10[2], b20[2];
#pragma unroll
    for (int i = 0; i < 8; ++i) {
      int row = wr * 128 + i * 16 + lr;
      afr0[i] = *(const bf16x8*)&Ac[(row * 8 + (kq ^ (row & 7))) * 8];
    }
#pragma unroll
    for (int j2 = 0; j2 < 2; ++j2) {
      int brow = wc * 32 + j2 * 16 + lr;
      b10[j2] = *(const bf16x8*)&B1c[(brow * 8 + (kq ^ (brow & 7))) * 8];
      b20[j2] = *(const bf16x8*)&B2c[(brow * 8 + (kq ^ (brow & 7))) * 8];
    }
    __builtin_amdgcn_s_setprio(1);
#pragma unroll
    for (int j2 = 0; j2 < 2; ++j2)
#pragma unroll
      for (int i = 0; i < 8; ++i) {
        accu[i][j2] = __builtin_amdgcn_mfma_f32_16x16x32_bf16(afr0[i], b10[j2],
                                                              accu[i][j2], 0, 0, 0);
        accg[i][j2] = __builtin_amdgcn_mfma_f32_16x16x32_bf16(afr0[i], b20[j2],
                                                              accg[i][j2], 0, 0, 0);
      }
    __builtin_amdgcn_s_setprio(0);
    // ---- ks = 1 ----
    bf16x8 afr1[8], b11[2], b21[2];
#pragma unroll
    for (int i = 0; i < 8; ++i) {
      int row = wr * 128 + i * 16 + lr;
      afr1[i] = *(const bf16x8*)&Ac[(row * 8 + ((4 + kq) ^ (row & 7))) * 8];
    }
#pragma unroll
    for (int j2 = 0; j2 < 2; ++j2) {
      int brow = wc * 32 + j2 * 16 + lr;
      b11[j2] = *(const bf16x8*)&B1c[(brow * 8 + ((4 + kq) ^ (brow & 7))) * 8];
      b21[j2] = *(const bf16x8*)&B2c[(brow * 8 + ((4 + kq) ^ (brow & 7))) * 8];
    }
    asm volatile("s_waitcnt lgkmcnt(0)" ::: "memory");
    __builtin_amdgcn_sched_barrier(0);
    __builtin_amdgcn_s_barrier();
    __builtin_amdgcn_sched_barrier(0);
    if (t + 2 < NT) stage(cur, (t + 2) << 6);
    __builtin_amdgcn_s_setprio(1);
#pragma unroll
    for (int j2 = 0; j2 < 2; ++j2)
#pragma unroll
      for (int i = 0; i < 8; ++i) {
        accu[i][j2] = __builtin_amdgcn_mfma_f32_16x16x32_bf16(afr1[i], b11[j2],
                                                              accu[i][j2], 0, 0, 0);
        accg[i][j2] = __builtin_amdgcn_mfma_f32_16x16x32_bf16(afr1[i], b21[j2],
                                                              accg[i][j2], 0, 0, 0);
      }
    __builtin_amdgcn_s_setprio(0);
    cur ^= 1;
  }

#pragma unroll
  for (int i = 0; i < 8; ++i)
#pragma unroll
    for (int j = 0; j < 2; ++j) {
      int rowb = bm0 + wr * 128 + i * 16 + kq * 4;
      int col = bn0 + wc * 32 + j * 16 + lr;
#pragma unroll
      for (int r = 0; r < 4; ++r) {
        float u = accu[i][j][r];
        float g = accg[i][j][r];
        float tv = tanhf(0.7978845608028654f * (g + 0.044715f * g * g * g));
        float hv = u * 0.5f * g * (1.0f + tv);
        H_[(size_t)(rowb + r) * ldc + col] = f2bf(hv);
      }
    }
}

// ---------------------------------------------------------------------------
extern "C" void kernel_launch(void* const* d_in, const int* in_sizes, int n_in,
                              void* d_out, int out_size, void* d_ws, size_t ws_size,
                              hipStream_t stream) {
  const float* x   = (const float*)d_in[0];
  const float* wq  = (const float*)d_in[1];
  const float* wk  = (const float*)d_in[2];
  const float* wv  = (const float*)d_in[3];
  const float* wo  = (const float*)d_in[4];
  const float* w1  = (const float*)d_in[5];
  const float* w2  = (const float*)d_in[6];
  const float* n1w = (const float*)d_in[7];
  const float* n2w = (const float*)d_in[8];

  float* out    = (float*)d_out;
  float* x2_out = out;
  float* k_out  = out + 8388608;
  float* v_out  = out + 16777216;
  float* attn   = out + 25165824;  // 134,217,728 f32

  char* ws = (char*)d_ws;
  unsigned short* wqT  = (unsigned short*)(ws + 0);
  unsigned short* wkT  = (unsigned short*)(ws + 8388608);
  unsigned short* wvT  = (unsigned short*)(ws + 10485760);
  unsigned short* woT  = (unsigned short*)(ws + 12582912);
  unsigned short* w1T  = (unsigned short*)(ws + 20971520);
  unsigned short* w2T  = (unsigned short*)(ws + 88080384);
  unsigned short* qh   = (unsigned short*)(ws + 121634816);
  unsigned short* kh   = (unsigned short*)(ws + 138412032);
  unsigned short* vhT  = (unsigned short*)(ws + 142606336);
  unsigned short* ctx  = (unsigned short*)(ws + 146800640);
  float*          ao   = (float*)(ws + 163577856);
  unsigned short* hbuf = (unsigned short*)(ws + 121634816);  // alias qh..ao (dead)
  unsigned short* x1b  = (unsigned short*)(ws + 197132288);
  unsigned short* fc   = (unsigned short*)(ws + 213909504);
  // ws total: 230,686,720 bytes

  // bf16 scratch inside not-yet-written attn region of d_out
  unsigned short* xb = (unsigned short*)attn;   // bf16(x), 8,388,608 elems
  unsigned short* xq = xb + 8388608;            // bf16(rope(x))

  dim3 blk(256);
  dim3 blk512(512);

  // 1) weight convert+transpose (f32 [K,N] -> bf16 [N,K])
  kconvT<<<dim3(64, 64), blk, 0, stream>>>(wq, wqT, 2048, 2048);
  kconvT<<<dim3(16, 64), blk, 0, stream>>>(wk, wkT, 2048, 512);
  kconvT<<<dim3(16, 64), blk, 0, stream>>>(wv, wvT, 2048, 512);
  kconvT<<<dim3(64, 64), blk, 0, stream>>>(wo, woT, 2048, 2048);
  kconvT<<<dim3(512, 64), blk, 0, stream>>>(w1, w1T, 2048, 16384);
  kconvT<<<dim3(64, 256), blk, 0, stream>>>(w2, w2T, 8192, 2048);

  // 2) k_flat = rope(x), v_flat = x, xq/xb bf16 (fused)
  krope<<<16384, blk, 0, stream>>>(x, k_out, v_out, xq, xb);

  // 3) projections
  gemm256<true><<<dim3(16, 16), blk512, 0, stream>>>(
      xq, wqT, qh, 2048, 2048, 2048, 2048);
  gemm_bt<true, false><<<dim3(4, 32), blk, 0, stream>>>(
      xq, wkT, kh, 2048, 2048, 2048, 512, 1.0f);
  gemm_bt<true, true><<<dim3(4, 32), blk, 0, stream>>>(
      xb, wvT, vhT, 2048, 2048, 2048, 4096, 1.0f);

  // 4) fused scores + softmax + attn write + PV -> ctx (XCD-swizzled 1D grid)
  kattn<<<dim3(4096), blk512, 0, stream>>>(qh, kh, vhT, attn, ctx);

  // 5) attn_out = ctx @ wo (f32)
  gemm256<false><<<dim3(16, 16), blk512, 0, stream>>>(
      ctx, woT, (void*)ao, 2048, 2048, 2048, 2048);
  // 6) x1b = rmsnorm(x + ao) * n1w
  krms1<<<4096, blk, 0, stream>>>(x, ao, n1w, x1b);
  // 7) h = u * gelu(gate)  (fused dual GEMM, uv never materialized)
  gemm_geglu256<<<dim3(64, 16), blk512, 0, stream>>>(
      x1b, w1T, w1T + 16777216, hbuf, 2048, 2048, 2048, 8192);
  // 8) fc = h @ w2
  gemm256<true><<<dim3(16, 16), blk512, 0, stream>>>(
      hbuf, w2T, fc, 8192, 8192, 8192, 2048);
  // 9) x2 = rmsnorm(x1 + fc) * n2w
  krms2<<<4096, blk, 0, stream>>>(x1b, fc, n2w, x2_out);
}

// Round 14
// 983.452 us; speedup vs baseline: 1.1903x; 1.1903x over previous
//
#include <hip/hip_runtime.h>
#include <hip/hip_bf16.h>

// ---------------------------------------------------------------------------
// TransformerBlock: B=2 N=2048 E=2048 H=16 G=4 D=128 HID=8192
// out = [ x2 (8.39M f32) | k_flat (8.39M) | v_flat (8.39M) | attn (134.2M) ]
// R14: REVERT kattn PV to v5 LDS staging (v6's per-lane 8KB-stride V loads
//      were uncoalesced: FETCH 41.6->57MB, kattn 297->408us).
//      NEW: nontemporal stores for stream-once outputs (attn 537MB, k_flat,
//      v_flat, x2) -- stops the write streams evicting the XCD-pinned K/V
//      slices (~1MB/XCD, 128x reuse) from the 4MB L2s.
//      GEMMs = R11 depth-2 counted-vmcnt (best known). krope fusion kept.
// ---------------------------------------------------------------------------

using f32x4  = __attribute__((ext_vector_type(4))) float;
using bf16x8 = __attribute__((ext_vector_type(8))) short;
using bf16x4 = __attribute__((ext_vector_type(4))) short;
using u16x4  = __attribute__((ext_vector_type(4))) unsigned short;

#define DEV __device__ __forceinline__

// async global->LDS, 16B per lane; LDS dest must be wave-uniform base + lane*16
#define ASYNC16(lds, g)                                                        \
  __builtin_amdgcn_global_load_lds(                                           \
      (const __attribute__((address_space(1))) void*)(g),                      \
      (__attribute__((address_space(3))) void*)(lds), 16, 0, 0)

DEV unsigned short f2bf(float f) {
  unsigned int u = __float_as_uint(f);
  return (unsigned short)((u + 0x7fffu + ((u >> 16) & 1u)) >> 16);
}
DEV float bf2f(unsigned short h) {
  return __uint_as_float(((unsigned int)h) << 16);
}

DEV float waveRedSum(float v) {
#pragma unroll
  for (int o = 32; o; o >>= 1) v += __shfl_xor(v, o);
  return v;
}

// ---- transpose+convert: in f32 [K,N] -> out bf16 [N,K] ---------------------
__global__ __launch_bounds__(256) void kconvT(const float* __restrict__ in,
                                              unsigned short* __restrict__ out,
                                              int K, int N) {
  __shared__ float tile[32][33];
  int bx = blockIdx.x * 32;  // N dim
  int by = blockIdx.y * 32;  // K dim
  int tx = threadIdx.x & 31;
  int ty = threadIdx.x >> 5;  // 0..7
#pragma unroll
  for (int i = 0; i < 32; i += 8)
    tile[ty + i][tx] = in[(size_t)(by + ty + i) * N + bx + tx];
  __syncthreads();
#pragma unroll
  for (int i = 0; i < 32; i += 8)
    out[(size_t)(bx + ty + i) * K + by + tx] = f2bf(tile[tx][ty + i]);
}

// ---- RoPE + v_flat copy + bf16 casts (fused); k/v outs nontemporal ---------
__global__ __launch_bounds__(256) void krope(const float* __restrict__ x,
                                             float* __restrict__ kout,
                                             float* __restrict__ vout,
                                             unsigned short* __restrict__ xq,
                                             unsigned short* __restrict__ xb) {
  int idx = blockIdx.x * 256 + threadIdx.x;  // B*N*H*64 = 4,194,304
  int f  = idx & 63;
  int h  = (idx >> 6) & 15;
  int bn = idx >> 10;          // b*2048+n
  int n  = bn & 2047;
  size_t base = (size_t)bn * 2048 + h * 128;
  float inv = exp2f((float)f * (-13.287712379549449f / 64.0f));
  float ang = (float)n * inv;
  float c = cosf(ang), s = sinf(ang);
  float a = x[base + f], b = x[base + f + 64];
  float k1 = a * c - b * s;
  float k2 = b * c + a * s;
  __builtin_nontemporal_store(k1, kout + base + f);
  __builtin_nontemporal_store(k2, kout + base + f + 64);
  xq[base + f]      = f2bf(k1);
  xq[base + f + 64] = f2bf(k2);
  __builtin_nontemporal_store(a, vout + base + f);
  __builtin_nontemporal_store(b, vout + base + f + 64);
  xb[base + f]      = f2bf(a);
  xb[base + f + 64] = f2bf(b);
}

// ---- x1b = bf16(rmsnorm(x + ao) * w) ---------------------------------------
__global__ __launch_bounds__(256) void krms1(const float* __restrict__ x,
                                             const float* __restrict__ ao,
                                             const float* __restrict__ w,
                                             unsigned short* __restrict__ x1b) {
  size_t row = blockIdx.x;
  const f32x4* xp = (const f32x4*)(x + row * 2048);
  const f32x4* ap = (const f32x4*)(ao + row * 2048);
  int tid = threadIdx.x;
  f32x4 t0 = xp[tid * 2] + ap[tid * 2];
  f32x4 t1 = xp[tid * 2 + 1] + ap[tid * 2 + 1];
  float ss = 0.f;
#pragma unroll
  for (int i = 0; i < 4; ++i) ss += t0[i] * t0[i] + t1[i] * t1[i];
  ss = waveRedSum(ss);
  __shared__ float red[4];
  int wid = tid >> 6, lane = tid & 63;
  if (!lane) red[wid] = ss;
  __syncthreads();
  ss = red[0] + red[1] + red[2] + red[3];
  float rr = rsqrtf(ss * (1.0f / 2048.0f) + 1e-6f);
  const f32x4* wp = (const f32x4*)w;
  f32x4 w0 = wp[tid * 2], w1 = wp[tid * 2 + 1];
  u16x4 o0, o1;
#pragma unroll
  for (int i = 0; i < 4; ++i) {
    o0[i] = f2bf(t0[i] * rr * w0[i]);
    o1[i] = f2bf(t1[i] * rr * w1[i]);
  }
  u16x4* op = (u16x4*)(x1b + row * 2048);
  op[tid * 2] = o0;
  op[tid * 2 + 1] = o1;
}

// ---- x2 = f32(rmsnorm(x1b + fc) * w) -> d_out (nontemporal) ----------------
__global__ __launch_bounds__(256) void krms2(const unsigned short* __restrict__ x1b,
                                             const unsigned short* __restrict__ fc,
                                             const float* __restrict__ w,
                                             float* __restrict__ out) {
  size_t row = blockIdx.x;
  const u16x4* xp = (const u16x4*)(x1b + row * 2048);
  const u16x4* fp = (const u16x4*)(fc + row * 2048);
  int tid = threadIdx.x;
  u16x4 a0 = xp[tid * 2], a1 = xp[tid * 2 + 1];
  u16x4 b0 = fp[tid * 2], b1 = fp[tid * 2 + 1];
  f32x4 t0, t1;
#pragma unroll
  for (int i = 0; i < 4; ++i) {
    t0[i] = bf2f(a0[i]) + bf2f(b0[i]);
    t1[i] = bf2f(a1[i]) + bf2f(b1[i]);
  }
  float ss = 0.f;
#pragma unroll
  for (int i = 0; i < 4; ++i) ss += t0[i] * t0[i] + t1[i] * t1[i];
  ss = waveRedSum(ss);
  __shared__ float red[4];
  int wid = tid >> 6, lane = tid & 63;
  if (!lane) red[wid] = ss;
  __syncthreads();
  ss = red[0] + red[1] + red[2] + red[3];
  float rr = rsqrtf(ss * (1.0f / 2048.0f) + 1e-6f);
  const f32x4* wp = (const f32x4*)w;
  f32x4 w0 = wp[tid * 2], w1 = wp[tid * 2 + 1];
  f32x4* op = (f32x4*)(out + row * 2048);
  f32x4 o0 = t0 * rr * w0;
  f32x4 o1 = t1 * rr * w1;
  __builtin_nontemporal_store(o0, op + tid * 2);
  __builtin_nontemporal_store(o1, op + tid * 2 + 1);
}

// ---- 128x128 MFMA GEMM (small shapes: k/v projections) ---------------------
template <bool OUT_BF16, bool TRANS_OUT>
__global__ __launch_bounds__(256, 2) void gemm_bt(
    const unsigned short* __restrict__ A, const unsigned short* __restrict__ Bt,
    void* __restrict__ C_, int K, int lda, int ldb, int ldc, float alpha) {
  __shared__ unsigned short As[128 * 32];
  __shared__ unsigned short Bs[128 * 32];
  const int tid = threadIdx.x;
  const int bm0 = blockIdx.y * 128, bn0 = blockIdx.x * 128;

  f32x4 acc[4][4] = {};

  const int lane = tid & 63, wid = tid >> 6;
  const int wr = wid >> 1, wc = wid & 1;
  const int lr = lane & 15, kq = lane >> 4;
  const int srow = tid >> 2;        // 0..63
  const int scol = (tid & 3) * 8;   // 0,8,16,24
  unsigned short* AsW = As + tid * 8;
  unsigned short* BsW = Bs + tid * 8;

  for (int kt = 0; kt < K; kt += 32) {
    ASYNC16(AsW,        A + (size_t)(bm0 + srow)      * lda + kt + scol);
    ASYNC16(AsW + 2048, A + (size_t)(bm0 + srow + 64) * lda + kt + scol);
    ASYNC16(BsW,        Bt + (size_t)(bn0 + srow)      * ldb + kt + scol);
    ASYNC16(BsW + 2048, Bt + (size_t)(bn0 + srow + 64) * ldb + kt + scol);
    __syncthreads();
    bf16x8 afr[4], bfr[4];
#pragma unroll
    for (int i = 0; i < 4; ++i)
      afr[i] = *(const bf16x8*)&As[(wr * 64 + i * 16 + lr) * 32 + kq * 8];
#pragma unroll
    for (int j = 0; j < 4; ++j)
      bfr[j] = *(const bf16x8*)&Bs[(wc * 64 + j * 16 + lr) * 32 + kq * 8];
#pragma unroll
    for (int i = 0; i < 4; ++i)
#pragma unroll
      for (int j = 0; j < 4; ++j)
        acc[i][j] = __builtin_amdgcn_mfma_f32_16x16x32_bf16(afr[i], bfr[j],
                                                            acc[i][j], 0, 0, 0);
    __syncthreads();
  }

#pragma unroll
  for (int i = 0; i < 4; ++i)
#pragma unroll
    for (int j = 0; j < 4; ++j) {
      int rowb = bm0 + wr * 64 + i * 16 + kq * 4;
      int col = bn0 + wc * 64 + j * 16 + lr;
#pragma unroll
      for (int r = 0; r < 4; ++r) {
        float v = acc[i][j][r] * alpha;
        size_t idx = TRANS_OUT ? ((size_t)col * ldc + (rowb + r))
                               : ((size_t)(rowb + r) * ldc + col);
        if constexpr (OUT_BF16)
          ((unsigned short*)C_)[idx] = f2bf(v);
        else
          ((float*)C_)[idx] = v;
      }
    }
}

// ===========================================================================
// Fused attention v7 = v5 (proven 297us) + nontemporal attn stores.
// scores: wave-private K staging, counted vmcnt(4); PV: LDS V dbuf,
// counted vmcnt(1) (coalesced 4-lanes/64B source). XCD swizzle g8 = bid&7.
// LDS 80KB -> 2 blocks/CU.
// ===========================================================================
__global__ __launch_bounds__(512, 4) void kattn(
    const unsigned short* __restrict__ qh,   // [b][n][h*128+d] ld 2048
    const unsigned short* __restrict__ kh,   // [b][n][g*128+d] ld 512
    const unsigned short* __restrict__ vT,   // [g*128+d][b*2048+key] ld 4096
    float* __restrict__ attn,                // [b][h][q][key]
    unsigned short* __restrict__ ctx) {      // [b][n][h*128+d] ld 2048
  __shared__ __align__(16) char U[65536];
  __shared__ __align__(16) char Vb[16384];
  float* redm = (float*)Vb;         // [8][16]
  float* reds = redm + 128;         // [8][16]

  const int tid = threadIdx.x;
  const int lane = tid & 63, w = tid >> 6;   // w 0..7
  const int lr = lane & 15, kq = lane >> 4;  // q = lr, quarter = kq
  const int bid = blockIdx.x;
  const int g8 = bid & 7;          // (b,g) slice, 0..7
  const int j  = bid >> 3;         // 0..511
  const int bz = g8 >> 2;          // batch
  const int gz = g8 & 3;           // kv group
  const int hz = gz * 4 + (j & 3); // head (hz>>2 == gz)
  const int q0 = (j >> 2) << 4;    // q-tile * 16
  const int z  = bz * 16 + hz;

  const unsigned short* Aq =
      qh + ((size_t)(bz * 2048 + q0 + lr) * 2048 + hz * 128);
  bf16x8 qfr[4];
#pragma unroll
  for (int kk = 0; kk < 4; ++kk)
    qfr[kk] = *(const bf16x8*)(Aq + kk * 32 + kq * 8);

  // --- scores: wave-private K staging, counted-vmcnt pipeline --------------
  const unsigned short* Kb =
      kh + ((size_t)(bz * 2048) * 512 + gz * 128);
  int krow[4], kcs[4];
#pragma unroll
  for (int R = 0; R < 4; ++R) {
    int idx = R * 64 + lane;
    krow[R] = idx >> 4;
    kcs[R] = (idx & 15) ^ (krow[R] & 7);  // pre-swizzled source chunk
  }
  auto stageK = [&](int buf, int t) {
#pragma unroll
    for (int R = 0; R < 4; ++R)
      ASYNC16(U + buf * 32768 + w * 4096 + (R * 64 + lane) * 16,
              Kb + (size_t)(t * 128 + w * 16 + krow[R]) * 512 + kcs[R] * 8);
  };

  f32x4 acc[16];
#pragma unroll
  for (int t = 0; t < 16; ++t) acc[t] = f32x4{0.f, 0.f, 0.f, 0.f};

  stageK(0, 0);
  stageK(1, 1);
#pragma unroll
  for (int t = 0; t < 16; ++t) {
    if (t < 15) asm volatile("s_waitcnt vmcnt(4)" ::: "memory");
    else        asm volatile("s_waitcnt vmcnt(0)" ::: "memory");
    __builtin_amdgcn_sched_barrier(0);
    const char* Kw = U + (t & 1) * 32768 + w * 4096;
    bf16x8 kfr[4];
#pragma unroll
    for (int kk = 0; kk < 4; ++kk) {
      int cch = (kk * 4 + kq) ^ (lr & 7);
      kfr[kk] = *(const bf16x8*)(Kw + lr * 256 + cch * 16);
    }
    asm volatile("s_waitcnt lgkmcnt(0)" ::: "memory");
    __builtin_amdgcn_sched_barrier(0);
    if (t + 2 < 16) stageK(t & 1, t + 2);  // reuse just-read buffer
#pragma unroll
    for (int kk = 0; kk < 4; ++kk)
      acc[t] = __builtin_amdgcn_mfma_f32_16x16x32_bf16(kfr[kk], qfr[kk],
                                                       acc[t], 0, 0, 0);
  }

  // --- softmax (per-lane q-row = lr) ---------------------------------------
  const float scale = 0.08838834764831845f;
  float mx = -3.4e38f;
#pragma unroll
  for (int t = 0; t < 16; ++t) {
    acc[t] *= scale;
#pragma unroll
    for (int r = 0; r < 4; ++r) mx = fmaxf(mx, acc[t][r]);
  }
  mx = fmaxf(mx, __shfl_xor(mx, 16));
  mx = fmaxf(mx, __shfl_xor(mx, 32));
  if (kq == 0) redm[w * 16 + lr] = mx;
  __syncthreads();  // barrier A
  mx = redm[lr];
#pragma unroll
  for (int ww = 1; ww < 8; ++ww) mx = fmaxf(mx, redm[ww * 16 + lr]);

  float sm = 0.f;
#pragma unroll
  for (int t = 0; t < 16; ++t) {
#pragma unroll
    for (int r = 0; r < 4; ++r) {
      float e = __expf(acc[t][r] - mx);
      acc[t][r] = e;
      sm += e;
    }
  }
  sm += __shfl_xor(sm, 16);
  sm += __shfl_xor(sm, 32);
  if (kq == 0) reds[w * 16 + lr] = sm;
  __syncthreads();  // barrier B
  float smt = reds[lr];
#pragma unroll
  for (int ww = 1; ww < 8; ++ww) smt += reds[ww * 16 + lr];
  float inv = 1.0f / smt;

  // --- write attn f32 (NT) + P bf16 into U (swizzled chunks) ---------------
  float* arow = attn + (((size_t)z * 2048 + q0 + lr) * 2048);
#pragma unroll
  for (int t = 0; t < 16; ++t) {
    int key = t * 128 + w * 16 + kq * 4;
    f32x4 p = acc[t] * inv;
    __builtin_nontemporal_store(p, (f32x4*)(arow + key));
    bf16x4 pb;
#pragma unroll
    for (int r = 0; r < 4; ++r) pb[r] = (short)f2bf(p[r]);
    int c8 = key >> 3;  // 16B chunk index in q-row
    *(bf16x4*)(U + lr * 4096 + ((c8 ^ (lr & 7)) << 4) + ((key & 7) << 1)) = pb;
  }
  __syncthreads();  // barrier C: P ready, red reads done, stores drained

  // --- PV: wave-private V staging, counted-vmcnt pipeline ------------------
  const unsigned short* Bv = vT + (size_t)gz * 524288 + bz * 2048;
  const int d0 = w * 16;
  const int vd = lane >> 2;                 // 0..15 local d-row
  const int vcs = (lane & 3) ^ (vd & 3);    // pre-swizzled source chunk
  auto stageV = [&](int buf, int t) {
    ASYNC16(Vb + buf * 8192 + w * 1024 + lane * 16,
            Bv + (size_t)(d0 + vd) * 4096 + t * 32 + vcs * 8);
  };

  f32x4 cfr = {};
  stageV(0, 0);
  stageV(1, 1);
#pragma unroll
  for (int t = 0; t < 64; ++t) {
    if (t < 63) asm volatile("s_waitcnt vmcnt(1)" ::: "memory");
    else        asm volatile("s_waitcnt vmcnt(0)" ::: "memory");
    __builtin_amdgcn_sched_barrier(0);
    int c8 = t * 4 + kq;
    bf16x8 pfr = *(const bf16x8*)(U + lr * 4096 + ((c8 ^ (lr & 7)) << 4));
    const char* Vw = Vb + (t & 1) * 8192 + w * 1024;
    bf16x8 vfr = *(const bf16x8*)(Vw + lr * 64 + ((kq ^ (lr & 3)) << 4));
    asm volatile("s_waitcnt lgkmcnt(0)" ::: "memory");
    __builtin_amdgcn_sched_barrier(0);
    if (t + 2 < 64) stageV(t & 1, t + 2);  // reuse just-read buffer
    cfr = __builtin_amdgcn_mfma_f32_16x16x32_bf16(pfr, vfr, cfr, 0, 0, 0);
  }
#pragma unroll
  for (int r = 0; r < 4; ++r) {
    int q = kq * 4 + r;
    ctx[((size_t)(bz * 2048 + q0 + q) * 2048) + hz * 128 + d0 + lr] =
        f2bf(cfr[r]);
  }
}

// ===========================================================================
// 256x128 8-wave GEMM, BK=64 — R11 depth-2 counted-vmcnt pipeline.
// ===========================================================================
template <bool OUT_BF16>
__global__ __launch_bounds__(512, 2) void gemm256(
    const unsigned short* __restrict__ A, const unsigned short* __restrict__ Bt,
    void* __restrict__ C_, int K, int lda, int ldb, int ldc) {
  __shared__ unsigned short As[2][256 * 64];  // 64 KB
  __shared__ unsigned short Bs[2][128 * 64];  // 32 KB
  const int tid = threadIdx.x;
  const int bm0 = blockIdx.y * 256, bn0 = blockIdx.x * 128;
  const int lane = tid & 63, wid = tid >> 6;
  const int wr = wid >> 2, wc = wid & 3;
  const int lr = lane & 15, kq = lane >> 4;

  f32x4 acc[8][2] = {};

  int sArow[4], sAcc[4], sBrow[2], sBcc[2];
#pragma unroll
  for (int R = 0; R < 4; ++R) {
    int c = R * 512 + tid;
    sArow[R] = c >> 3;
    sAcc[R]  = (c & 7) ^ (sArow[R] & 7);
  }
#pragma unroll
  for (int R = 0; R < 2; ++R) {
    int c = R * 512 + tid;
    sBrow[R] = c >> 3;
    sBcc[R]  = (c & 7) ^ (sBrow[R] & 7);
  }

  auto stage = [&](int buf, int k0) {  // 6 loads/thread
#pragma unroll
    for (int R = 0; R < 4; ++R)
      ASYNC16(&As[buf][(R * 512 + tid) * 8],
              A + (size_t)(bm0 + sArow[R]) * lda + k0 + sAcc[R] * 8);
#pragma unroll
    for (int R = 0; R < 2; ++R)
      ASYNC16(&Bs[buf][(R * 512 + tid) * 8],
              Bt + (size_t)(bn0 + sBrow[R]) * ldb + k0 + sBcc[R] * 8);
  };

  const int NT = K >> 6;
  stage(0, 0);
  stage(1, 64);
  int cur = 0;
  for (int t = 0; t < NT; ++t) {
    if (t + 1 < NT) asm volatile("s_waitcnt vmcnt(6)" ::: "memory");
    else            asm volatile("s_waitcnt vmcnt(0)" ::: "memory");
    __builtin_amdgcn_sched_barrier(0);
    __builtin_amdgcn_s_barrier();
    __builtin_amdgcn_sched_barrier(0);
    const unsigned short* Ac = As[cur];
    const unsigned short* Bc = Bs[cur];
    // ---- ks = 0 ----
    bf16x8 afr0[8], bfr0[2];
#pragma unroll
    for (int i = 0; i < 8; ++i) {
      int row = wr * 128 + i * 16 + lr;
      afr0[i] = *(const bf16x8*)&Ac[(row * 8 + (kq ^ (row & 7))) * 8];
    }
#pragma unroll
    for (int j2 = 0; j2 < 2; ++j2) {
      int brow = wc * 32 + j2 * 16 + lr;
      bfr0[j2] = *(const bf16x8*)&Bc[(brow * 8 + (kq ^ (brow & 7))) * 8];
    }
    __builtin_amdgcn_s_setprio(1);
#pragma unroll
    for (int j2 = 0; j2 < 2; ++j2)
#pragma unroll
      for (int i = 0; i < 8; ++i)
        acc[i][j2] = __builtin_amdgcn_mfma_f32_16x16x32_bf16(afr0[i], bfr0[j2],
                                                             acc[i][j2], 0, 0, 0);
    __builtin_amdgcn_s_setprio(0);
    // ---- ks = 1 ----
    bf16x8 afr1[8], bfr1[2];
#pragma unroll
    for (int i = 0; i < 8; ++i) {
      int row = wr * 128 + i * 16 + lr;
      afr1[i] = *(const bf16x8*)&Ac[(row * 8 + ((4 + kq) ^ (row & 7))) * 8];
    }
#pragma unroll
    for (int j2 = 0; j2 < 2; ++j2) {
      int brow = wc * 32 + j2 * 16 + lr;
      bfr1[j2] = *(const bf16x8*)&Bc[(brow * 8 + ((4 + kq) ^ (brow & 7))) * 8];
    }
    asm volatile("s_waitcnt lgkmcnt(0)" ::: "memory");
    __builtin_amdgcn_sched_barrier(0);
    __builtin_amdgcn_s_barrier();   // all waves' reads of buf[cur] done
    __builtin_amdgcn_sched_barrier(0);
    if (t + 2 < NT) stage(cur, (t + 2) << 6);
    __builtin_amdgcn_s_setprio(1);
#pragma unroll
    for (int j2 = 0; j2 < 2; ++j2)
#pragma unroll
      for (int i = 0; i < 8; ++i)
        acc[i][j2] = __builtin_amdgcn_mfma_f32_16x16x32_bf16(afr1[i], bfr1[j2],
                                                             acc[i][j2], 0, 0, 0);
    __builtin_amdgcn_s_setprio(0);
    cur ^= 1;
  }

#pragma unroll
  for (int i = 0; i < 8; ++i)
#pragma unroll
    for (int j = 0; j < 2; ++j) {
      int rowb = bm0 + wr * 128 + i * 16 + kq * 4;
      int col = bn0 + wc * 32 + j * 16 + lr;
#pragma unroll
      for (int r = 0; r < 4; ++r) {
        if constexpr (OUT_BF16)
          ((unsigned short*)C_)[(size_t)(rowb + r) * ldc + col] = f2bf(acc[i][j][r]);
        else
          ((float*)C_)[(size_t)(rowb + r) * ldc + col] = acc[i][j][r];
      }
    }
}

// ---- GeGLU dual GEMM: R11 depth-2 counted-vmcnt schedule -------------------
__global__ __launch_bounds__(512, 2) void gemm_geglu256(
    const unsigned short* __restrict__ A, const unsigned short* __restrict__ B1,
    const unsigned short* __restrict__ B2, unsigned short* __restrict__ H_,
    int K, int lda, int ldb, int ldc) {
  __shared__ unsigned short As[2][256 * 64];   // 64 KB
  __shared__ unsigned short B1s[2][128 * 64];  // 32 KB
  __shared__ unsigned short B2s[2][128 * 64];  // 32 KB
  const int tid = threadIdx.x;
  const int bm0 = blockIdx.y * 256, bn0 = blockIdx.x * 128;
  const int lane = tid & 63, wid = tid >> 6;
  const int wr = wid >> 2, wc = wid & 3;
  const int lr = lane & 15, kq = lane >> 4;

  f32x4 accu[8][2] = {};
  f32x4 accg[8][2] = {};

  int sArow[4], sAcc[4], sBrow[2], sBcc[2];
#pragma unroll
  for (int R = 0; R < 4; ++R) {
    int c = R * 512 + tid;
    sArow[R] = c >> 3;
    sAcc[R]  = (c & 7) ^ (sArow[R] & 7);
  }
#pragma unroll
  for (int R = 0; R < 2; ++R) {
    int c = R * 512 + tid;
    sBrow[R] = c >> 3;
    sBcc[R]  = (c & 7) ^ (sBrow[R] & 7);
  }

  auto stage = [&](int buf, int k0) {  // 8 loads/thread
#pragma unroll
    for (int R = 0; R < 4; ++R)
      ASYNC16(&As[buf][(R * 512 + tid) * 8],
              A + (size_t)(bm0 + sArow[R]) * lda + k0 + sAcc[R] * 8);
#pragma unroll
    for (int R = 0; R < 2; ++R)
      ASYNC16(&B1s[buf][(R * 512 + tid) * 8],
              B1 + (size_t)(bn0 + sBrow[R]) * ldb + k0 + sBcc[R] * 8);
#pragma unroll
    for (int R = 0; R < 2; ++R)
      ASYNC16(&B2s[buf][(R * 512 + tid) * 8],
              B2 + (size_t)(bn0 + sBrow[R]) * ldb + k0 + sBcc[R] * 8);
  };

  const int NT = K >> 6;
  stage(0, 0);
  stage(1, 64);
  int cur = 0;
  for (int t = 0; t < NT; ++t) {
    if (t + 1 < NT) asm volatile("s_waitcnt vmcnt(8)" ::: "memory");
    else            asm volatile("s_waitcnt vmcnt(0)" ::: "memory");
    __builtin_amdgcn_sched_barrier(0);
    __builtin_amdgcn_s_barrier();
    __builtin_amdgcn_sched_barrier(0);
    const unsigned short* Ac = As[cur];
    const unsigned short* B1c = B1s[cur];
    const unsigned short* B2c = B2s[cur];
    // ---- ks = 0 ----
    bf16x8 afr0[8], b10[2], b20[2];
#pragma unroll
    for (int i = 0; i < 8; ++i) {
      int row = wr * 128 + i * 16 + lr;
      afr0[i] = *(const bf16x8*)&Ac[(row * 8 + (kq ^ (row & 7))) * 8];
    }
#pragma unroll
    for (int j2 = 0; j2 < 2; ++j2) {
      int brow = wc * 32 + j2 * 16 + lr;
      b10[j2] = *(const bf16x8*)&B1c[(brow * 8 + (kq ^ (brow & 7))) * 8];
      b20[j2] = *(const bf16x8*)&B2c[(brow * 8 + (kq ^ (brow & 7))) * 8];
    }
    __builtin_amdgcn_s_setprio(1);
#pragma unroll
    for (int j2 = 0; j2 < 2; ++j2)
#pragma unroll
      for (int i = 0; i < 8; ++i) {
        accu[i][j2] = __builtin_amdgcn_mfma_f32_16x16x32_bf16(afr0[i], b10[j2],
                                                              accu[i][j2], 0, 0, 0);
        accg[i][j2] = __builtin_amdgcn_mfma_f32_16x16x32_bf16(afr0[i], b20[j2],
                                                              accg[i][j2], 0, 0, 0);
      }
    __builtin_amdgcn_s_setprio(0);
    // ---- ks = 1 ----
    bf16x8 afr1[8], b11[2], b21[2];
#pragma unroll
    for (int i = 0; i < 8; ++i) {
      int row = wr * 128 + i * 16 + lr;
      afr1[i] = *(const bf16x8*)&Ac[(row * 8 + ((4 + kq) ^ (row & 7))) * 8];
    }
#pragma unroll
    for (int j2 = 0; j2 < 2; ++j2) {
      int brow = wc * 32 + j2 * 16 + lr;
      b11[j2] = *(const bf16x8*)&B1c[(brow * 8 + ((4 + kq) ^ (brow & 7))) * 8];
      b21[j2] = *(const bf16x8*)&B2c[(brow * 8 + ((4 + kq) ^ (brow & 7))) * 8];
    }
    asm volatile("s_waitcnt lgkmcnt(0)" ::: "memory");
    __builtin_amdgcn_sched_barrier(0);
    __builtin_amdgcn_s_barrier();
    __builtin_amdgcn_sched_barrier(0);
    if (t + 2 < NT) stage(cur, (t + 2) << 6);
    __builtin_amdgcn_s_setprio(1);
#pragma unroll
    for (int j2 = 0; j2 < 2; ++j2)
#pragma unroll
      for (int i = 0; i < 8; ++i) {
        accu[i][j2] = __builtin_amdgcn_mfma_f32_16x16x32_bf16(afr1[i], b11[j2],
                                                              accu[i][j2], 0, 0, 0);
        accg[i][j2] = __builtin_amdgcn_mfma_f32_16x16x32_bf16(afr1[i], b21[j2],
                                                              accg[i][j2], 0, 0, 0);
      }
    __builtin_amdgcn_s_setprio(0);
    cur ^= 1;
  }

#pragma unroll
  for (int i = 0; i < 8; ++i)
#pragma unroll
    for (int j = 0; j < 2; ++j) {
      int rowb = bm0 + wr * 128 + i * 16 + kq * 4;
      int col = bn0 + wc * 32 + j * 16 + lr;
#pragma unroll
      for (int r = 0; r < 4; ++r) {
        float u = accu[i][j][r];
        float g = accg[i][j][r];
        float tv = tanhf(0.7978845608028654f * (g + 0.044715f * g * g * g));
        float hv = u * 0.5f * g * (1.0f + tv);
        H_[(size_t)(rowb + r) * ldc + col] = f2bf(hv);
      }
    }
}

// ---------------------------------------------------------------------------
extern "C" void kernel_launch(void* const* d_in, const int* in_sizes, int n_in,
                              void* d_out, int out_size, void* d_ws, size_t ws_size,
                              hipStream_t stream) {
  const float* x   = (const float*)d_in[0];
  const float* wq  = (const float*)d_in[1];
  const float* wk  = (const float*)d_in[2];
  const float* wv  = (const float*)d_in[3];
  const float* wo  = (const float*)d_in[4];
  const float* w1  = (const float*)d_in[5];
  const float* w2  = (const float*)d_in[6];
  const float* n1w = (const float*)d_in[7];
  const float* n2w = (const float*)d_in[8];

  float* out    = (float*)d_out;
  float* x2_out = out;
  float* k_out  = out + 8388608;
  float* v_out  = out + 16777216;
  float* attn   = out + 25165824;  // 134,217,728 f32

  char* ws = (char*)d_ws;
  unsigned short* wqT  = (unsigned short*)(ws + 0);
  unsigned short* wkT  = (unsigned short*)(ws + 8388608);
  unsigned short* wvT  = (unsigned short*)(ws + 10485760);
  unsigned short* woT  = (unsigned short*)(ws + 12582912);
  unsigned short* w1T  = (unsigned short*)(ws + 20971520);
  unsigned short* w2T  = (unsigned short*)(ws + 88080384);
  unsigned short* qh   = (unsigned short*)(ws + 121634816);
  unsigned short* kh   = (unsigned short*)(ws + 138412032);
  unsigned short* vhT  = (unsigned short*)(ws + 142606336);
  unsigned short* ctx  = (unsigned short*)(ws + 146800640);
  float*          ao   = (float*)(ws + 163577856);
  unsigned short* hbuf = (unsigned short*)(ws + 121634816);  // alias qh..ao (dead)
  unsigned short* x1b  = (unsigned short*)(ws + 197132288);
  unsigned short* fc   = (unsigned short*)(ws + 213909504);
  // ws total: 230,686,720 bytes

  // bf16 scratch inside not-yet-written attn region of d_out
  unsigned short* xb = (unsigned short*)attn;   // bf16(x), 8,388,608 elems
  unsigned short* xq = xb + 8388608;            // bf16(rope(x))

  dim3 blk(256);
  dim3 blk512(512);

  // 1) weight convert+transpose (f32 [K,N] -> bf16 [N,K])
  kconvT<<<dim3(64, 64), blk, 0, stream>>>(wq, wqT, 2048, 2048);
  kconvT<<<dim3(16, 64), blk, 0, stream>>>(wk, wkT, 2048, 512);
  kconvT<<<dim3(16, 64), blk, 0, stream>>>(wv, wvT, 2048, 512);
  kconvT<<<dim3(64, 64), blk, 0, stream>>>(wo, woT, 2048, 2048);
  kconvT<<<dim3(512, 64), blk, 0, stream>>>(w1, w1T, 2048, 16384);
  kconvT<<<dim3(64, 256), blk, 0, stream>>>(w2, w2T, 8192, 2048);

  // 2) k_flat = rope(x), v_flat = x, xq/xb bf16 (fused)
  krope<<<16384, blk, 0, stream>>>(x, k_out, v_out, xq, xb);

  // 3) projections
  gemm256<true><<<dim3(16, 16), blk512, 0, stream>>>(
      xq, wqT, qh, 2048, 2048, 2048, 2048);
  gemm_bt<true, false><<<dim3(4, 32), blk, 0, stream>>>(
      xq, wkT, kh, 2048, 2048, 2048, 512, 1.0f);
  gemm_bt<true, true><<<dim3(4, 32), blk, 0, stream>>>(
      xb, wvT, vhT, 2048, 2048, 2048, 4096, 1.0f);

  // 4) fused scores + softmax + attn write + PV -> ctx (XCD-swizzled 1D grid)
  kattn<<<dim3(4096), blk512, 0, stream>>>(qh, kh, vhT, attn, ctx);

  // 5) attn_out = ctx @ wo (f32)
  gemm256<false><<<dim3(16, 16), blk512, 0, stream>>>(
      ctx, woT, (void*)ao, 2048, 2048, 2048, 2048);
  // 6) x1b = rmsnorm(x + ao) * n1w
  krms1<<<4096, blk, 0, stream>>>(x, ao, n1w, x1b);
  // 7) h = u * gelu(gate)  (fused dual GEMM, uv never materialized)
  gemm_geglu256<<<dim3(64, 16), blk512, 0, stream>>>(
      x1b, w1T, w1T + 16777216, hbuf, 2048, 2048, 2048, 8192);
  // 8) fc = h @ w2
  gemm256<true><<<dim3(16, 16), blk512, 0, stream>>>(
      hbuf, w2T, fc, 8192, 8192, 8192, 2048);
  // 9) x2 = rmsnorm(x1 + fc) * n2w
  krms2<<<4096, blk, 0, stream>>>(x1b, fc, n2w, x2_out);
}

// Round 15
// 940.732 us; speedup vs baseline: 1.2444x; 1.0454x over previous
//
#include <hip/hip_runtime.h>
#include <hip/hip_bf16.h>

// ---------------------------------------------------------------------------
// TransformerBlock: B=2 N=2048 E=2048 H=16 G=4 D=128 HID=8192
// out = [ x2 (8.39M f32) | k_flat (8.39M) | v_flat (8.39M) | attn (134.2M) ]
// R15: q/wo/fc -> gemm128 (BM=BN=128, 8 waves, R11 depth-2 counted-vmcnt):
//      grids 512 blocks = 2 blocks/CU (was 256 = 1/CU, no cross-block
//      overlap -- the m114 TLP that makes GeGLU the best GEMM in the stack).
//      kattn v7 (v5+NT stores, 250us) / GeGLU R11 / krope fusion unchanged.
// ---------------------------------------------------------------------------

using f32x4  = __attribute__((ext_vector_type(4))) float;
using bf16x8 = __attribute__((ext_vector_type(8))) short;
using bf16x4 = __attribute__((ext_vector_type(4))) short;
using u16x4  = __attribute__((ext_vector_type(4))) unsigned short;

#define DEV __device__ __forceinline__

// async global->LDS, 16B per lane; LDS dest must be wave-uniform base + lane*16
#define ASYNC16(lds, g)                                                        \
  __builtin_amdgcn_global_load_lds(                                           \
      (const __attribute__((address_space(1))) void*)(g),                      \
      (__attribute__((address_space(3))) void*)(lds), 16, 0, 0)

DEV unsigned short f2bf(float f) {
  unsigned int u = __float_as_uint(f);
  return (unsigned short)((u + 0x7fffu + ((u >> 16) & 1u)) >> 16);
}
DEV float bf2f(unsigned short h) {
  return __uint_as_float(((unsigned int)h) << 16);
}

DEV float waveRedSum(float v) {
#pragma unroll
  for (int o = 32; o; o >>= 1) v += __shfl_xor(v, o);
  return v;
}

// ---- transpose+convert: in f32 [K,N] -> out bf16 [N,K] ---------------------
__global__ __launch_bounds__(256) void kconvT(const float* __restrict__ in,
                                              unsigned short* __restrict__ out,
                                              int K, int N) {
  __shared__ float tile[32][33];
  int bx = blockIdx.x * 32;  // N dim
  int by = blockIdx.y * 32;  // K dim
  int tx = threadIdx.x & 31;
  int ty = threadIdx.x >> 5;  // 0..7
#pragma unroll
  for (int i = 0; i < 32; i += 8)
    tile[ty + i][tx] = in[(size_t)(by + ty + i) * N + bx + tx];
  __syncthreads();
#pragma unroll
  for (int i = 0; i < 32; i += 8)
    out[(size_t)(bx + ty + i) * K + by + tx] = f2bf(tile[tx][ty + i]);
}

// ---- RoPE + v_flat copy + bf16 casts (fused); k/v outs nontemporal ---------
__global__ __launch_bounds__(256) void krope(const float* __restrict__ x,
                                             float* __restrict__ kout,
                                             float* __restrict__ vout,
                                             unsigned short* __restrict__ xq,
                                             unsigned short* __restrict__ xb) {
  int idx = blockIdx.x * 256 + threadIdx.x;  // B*N*H*64 = 4,194,304
  int f  = idx & 63;
  int h  = (idx >> 6) & 15;
  int bn = idx >> 10;          // b*2048+n
  int n  = bn & 2047;
  size_t base = (size_t)bn * 2048 + h * 128;
  float inv = exp2f((float)f * (-13.287712379549449f / 64.0f));
  float ang = (float)n * inv;
  float c = cosf(ang), s = sinf(ang);
  float a = x[base + f], b = x[base + f + 64];
  float k1 = a * c - b * s;
  float k2 = b * c + a * s;
  __builtin_nontemporal_store(k1, kout + base + f);
  __builtin_nontemporal_store(k2, kout + base + f + 64);
  xq[base + f]      = f2bf(k1);
  xq[base + f + 64] = f2bf(k2);
  __builtin_nontemporal_store(a, vout + base + f);
  __builtin_nontemporal_store(b, vout + base + f + 64);
  xb[base + f]      = f2bf(a);
  xb[base + f + 64] = f2bf(b);
}

// ---- x1b = bf16(rmsnorm(x + ao) * w) ---------------------------------------
__global__ __launch_bounds__(256) void krms1(const float* __restrict__ x,
                                             const float* __restrict__ ao,
                                             const float* __restrict__ w,
                                             unsigned short* __restrict__ x1b) {
  size_t row = blockIdx.x;
  const f32x4* xp = (const f32x4*)(x + row * 2048);
  const f32x4* ap = (const f32x4*)(ao + row * 2048);
  int tid = threadIdx.x;
  f32x4 t0 = xp[tid * 2] + ap[tid * 2];
  f32x4 t1 = xp[tid * 2 + 1] + ap[tid * 2 + 1];
  float ss = 0.f;
#pragma unroll
  for (int i = 0; i < 4; ++i) ss += t0[i] * t0[i] + t1[i] * t1[i];
  ss = waveRedSum(ss);
  __shared__ float red[4];
  int wid = tid >> 6, lane = tid & 63;
  if (!lane) red[wid] = ss;
  __syncthreads();
  ss = red[0] + red[1] + red[2] + red[3];
  float rr = rsqrtf(ss * (1.0f / 2048.0f) + 1e-6f);
  const f32x4* wp = (const f32x4*)w;
  f32x4 w0 = wp[tid * 2], w1 = wp[tid * 2 + 1];
  u16x4 o0, o1;
#pragma unroll
  for (int i = 0; i < 4; ++i) {
    o0[i] = f2bf(t0[i] * rr * w0[i]);
    o1[i] = f2bf(t1[i] * rr * w1[i]);
  }
  u16x4* op = (u16x4*)(x1b + row * 2048);
  op[tid * 2] = o0;
  op[tid * 2 + 1] = o1;
}

// ---- x2 = f32(rmsnorm(x1b + fc) * w) -> d_out (nontemporal) ----------------
__global__ __launch_bounds__(256) void krms2(const unsigned short* __restrict__ x1b,
                                             const unsigned short* __restrict__ fc,
                                             const float* __restrict__ w,
                                             float* __restrict__ out) {
  size_t row = blockIdx.x;
  const u16x4* xp = (const u16x4*)(x1b + row * 2048);
  const u16x4* fp = (const u16x4*)(fc + row * 2048);
  int tid = threadIdx.x;
  u16x4 a0 = xp[tid * 2], a1 = xp[tid * 2 + 1];
  u16x4 b0 = fp[tid * 2], b1 = fp[tid * 2 + 1];
  f32x4 t0, t1;
#pragma unroll
  for (int i = 0; i < 4; ++i) {
    t0[i] = bf2f(a0[i]) + bf2f(b0[i]);
    t1[i] = bf2f(a1[i]) + bf2f(b1[i]);
  }
  float ss = 0.f;
#pragma unroll
  for (int i = 0; i < 4; ++i) ss += t0[i] * t0[i] + t1[i] * t1[i];
  ss = waveRedSum(ss);
  __shared__ float red[4];
  int wid = tid >> 6, lane = tid & 63;
  if (!lane) red[wid] = ss;
  __syncthreads();
  ss = red[0] + red[1] + red[2] + red[3];
  float rr = rsqrtf(ss * (1.0f / 2048.0f) + 1e-6f);
  const f32x4* wp = (const f32x4*)w;
  f32x4 w0 = wp[tid * 2], w1 = wp[tid * 2 + 1];
  f32x4* op = (f32x4*)(out + row * 2048);
  f32x4 o0 = t0 * rr * w0;
  f32x4 o1 = t1 * rr * w1;
  __builtin_nontemporal_store(o0, op + tid * 2);
  __builtin_nontemporal_store(o1, op + tid * 2 + 1);
}

// ---- 128x128 MFMA GEMM, 256 thr (small shapes: k/v projections) ------------
template <bool OUT_BF16, bool TRANS_OUT>
__global__ __launch_bounds__(256, 2) void gemm_bt(
    const unsigned short* __restrict__ A, const unsigned short* __restrict__ Bt,
    void* __restrict__ C_, int K, int lda, int ldb, int ldc, float alpha) {
  __shared__ unsigned short As[128 * 32];
  __shared__ unsigned short Bs[128 * 32];
  const int tid = threadIdx.x;
  const int bm0 = blockIdx.y * 128, bn0 = blockIdx.x * 128;

  f32x4 acc[4][4] = {};

  const int lane = tid & 63, wid = tid >> 6;
  const int wr = wid >> 1, wc = wid & 1;
  const int lr = lane & 15, kq = lane >> 4;
  const int srow = tid >> 2;        // 0..63
  const int scol = (tid & 3) * 8;   // 0,8,16,24
  unsigned short* AsW = As + tid * 8;
  unsigned short* BsW = Bs + tid * 8;

  for (int kt = 0; kt < K; kt += 32) {
    ASYNC16(AsW,        A + (size_t)(bm0 + srow)      * lda + kt + scol);
    ASYNC16(AsW + 2048, A + (size_t)(bm0 + srow + 64) * lda + kt + scol);
    ASYNC16(BsW,        Bt + (size_t)(bn0 + srow)      * ldb + kt + scol);
    ASYNC16(BsW + 2048, Bt + (size_t)(bn0 + srow + 64) * ldb + kt + scol);
    __syncthreads();
    bf16x8 afr[4], bfr[4];
#pragma unroll
    for (int i = 0; i < 4; ++i)
      afr[i] = *(const bf16x8*)&As[(wr * 64 + i * 16 + lr) * 32 + kq * 8];
#pragma unroll
    for (int j = 0; j < 4; ++j)
      bfr[j] = *(const bf16x8*)&Bs[(wc * 64 + j * 16 + lr) * 32 + kq * 8];
#pragma unroll
    for (int i = 0; i < 4; ++i)
#pragma unroll
      for (int j = 0; j < 4; ++j)
        acc[i][j] = __builtin_amdgcn_mfma_f32_16x16x32_bf16(afr[i], bfr[j],
                                                            acc[i][j], 0, 0, 0);
    __syncthreads();
  }

#pragma unroll
  for (int i = 0; i < 4; ++i)
#pragma unroll
    for (int j = 0; j < 4; ++j) {
      int rowb = bm0 + wr * 64 + i * 16 + kq * 4;
      int col = bn0 + wc * 64 + j * 16 + lr;
#pragma unroll
      for (int r = 0; r < 4; ++r) {
        float v = acc[i][j][r] * alpha;
        size_t idx = TRANS_OUT ? ((size_t)col * ldc + (rowb + r))
                               : ((size_t)(rowb + r) * ldc + col);
        if constexpr (OUT_BF16)
          ((unsigned short*)C_)[idx] = f2bf(v);
        else
          ((float*)C_)[idx] = v;
      }
    }
}

// ===========================================================================
// Fused attention v7: v5 pipeline + NT attn stores + XCD swizzle (g8=bid&7).
// LDS 80KB -> 2 blocks/CU.
// ===========================================================================
__global__ __launch_bounds__(512, 4) void kattn(
    const unsigned short* __restrict__ qh,   // [b][n][h*128+d] ld 2048
    const unsigned short* __restrict__ kh,   // [b][n][g*128+d] ld 512
    const unsigned short* __restrict__ vT,   // [g*128+d][b*2048+key] ld 4096
    float* __restrict__ attn,                // [b][h][q][key]
    unsigned short* __restrict__ ctx) {      // [b][n][h*128+d] ld 2048
  __shared__ __align__(16) char U[65536];
  __shared__ __align__(16) char Vb[16384];
  float* redm = (float*)Vb;         // [8][16]
  float* reds = redm + 128;         // [8][16]

  const int tid = threadIdx.x;
  const int lane = tid & 63, w = tid >> 6;   // w 0..7
  const int lr = lane & 15, kq = lane >> 4;  // q = lr, quarter = kq
  const int bid = blockIdx.x;
  const int g8 = bid & 7;          // (b,g) slice, 0..7
  const int j  = bid >> 3;         // 0..511
  const int bz = g8 >> 2;          // batch
  const int gz = g8 & 3;           // kv group
  const int hz = gz * 4 + (j & 3); // head (hz>>2 == gz)
  const int q0 = (j >> 2) << 4;    // q-tile * 16
  const int z  = bz * 16 + hz;

  const unsigned short* Aq =
      qh + ((size_t)(bz * 2048 + q0 + lr) * 2048 + hz * 128);
  bf16x8 qfr[4];
#pragma unroll
  for (int kk = 0; kk < 4; ++kk)
    qfr[kk] = *(const bf16x8*)(Aq + kk * 32 + kq * 8);

  // --- scores: wave-private K staging, counted-vmcnt pipeline --------------
  const unsigned short* Kb =
      kh + ((size_t)(bz * 2048) * 512 + gz * 128);
  int krow[4], kcs[4];
#pragma unroll
  for (int R = 0; R < 4; ++R) {
    int idx = R * 64 + lane;
    krow[R] = idx >> 4;
    kcs[R] = (idx & 15) ^ (krow[R] & 7);  // pre-swizzled source chunk
  }
  auto stageK = [&](int buf, int t) {
#pragma unroll
    for (int R = 0; R < 4; ++R)
      ASYNC16(U + buf * 32768 + w * 4096 + (R * 64 + lane) * 16,
              Kb + (size_t)(t * 128 + w * 16 + krow[R]) * 512 + kcs[R] * 8);
  };

  f32x4 acc[16];
#pragma unroll
  for (int t = 0; t < 16; ++t) acc[t] = f32x4{0.f, 0.f, 0.f, 0.f};

  stageK(0, 0);
  stageK(1, 1);
#pragma unroll
  for (int t = 0; t < 16; ++t) {
    if (t < 15) asm volatile("s_waitcnt vmcnt(4)" ::: "memory");
    else        asm volatile("s_waitcnt vmcnt(0)" ::: "memory");
    __builtin_amdgcn_sched_barrier(0);
    const char* Kw = U + (t & 1) * 32768 + w * 4096;
    bf16x8 kfr[4];
#pragma unroll
    for (int kk = 0; kk < 4; ++kk) {
      int cch = (kk * 4 + kq) ^ (lr & 7);
      kfr[kk] = *(const bf16x8*)(Kw + lr * 256 + cch * 16);
    }
    asm volatile("s_waitcnt lgkmcnt(0)" ::: "memory");
    __builtin_amdgcn_sched_barrier(0);
    if (t + 2 < 16) stageK(t & 1, t + 2);  // reuse just-read buffer
#pragma unroll
    for (int kk = 0; kk < 4; ++kk)
      acc[t] = __builtin_amdgcn_mfma_f32_16x16x32_bf16(kfr[kk], qfr[kk],
                                                       acc[t], 0, 0, 0);
  }

  // --- softmax (per-lane q-row = lr) ---------------------------------------
  const float scale = 0.08838834764831845f;
  float mx = -3.4e38f;
#pragma unroll
  for (int t = 0; t < 16; ++t) {
    acc[t] *= scale;
#pragma unroll
    for (int r = 0; r < 4; ++r) mx = fmaxf(mx, acc[t][r]);
  }
  mx = fmaxf(mx, __shfl_xor(mx, 16));
  mx = fmaxf(mx, __shfl_xor(mx, 32));
  if (kq == 0) redm[w * 16 + lr] = mx;
  __syncthreads();  // barrier A
  mx = redm[lr];
#pragma unroll
  for (int ww = 1; ww < 8; ++ww) mx = fmaxf(mx, redm[ww * 16 + lr]);

  float sm = 0.f;
#pragma unroll
  for (int t = 0; t < 16; ++t) {
#pragma unroll
    for (int r = 0; r < 4; ++r) {
      float e = __expf(acc[t][r] - mx);
      acc[t][r] = e;
      sm += e;
    }
  }
  sm += __shfl_xor(sm, 16);
  sm += __shfl_xor(sm, 32);
  if (kq == 0) reds[w * 16 + lr] = sm;
  __syncthreads();  // barrier B
  float smt = reds[lr];
#pragma unroll
  for (int ww = 1; ww < 8; ++ww) smt += reds[ww * 16 + lr];
  float inv = 1.0f / smt;

  // --- write attn f32 (NT) + P bf16 into U (swizzled chunks) ---------------
  float* arow = attn + (((size_t)z * 2048 + q0 + lr) * 2048);
#pragma unroll
  for (int t = 0; t < 16; ++t) {
    int key = t * 128 + w * 16 + kq * 4;
    f32x4 p = acc[t] * inv;
    __builtin_nontemporal_store(p, (f32x4*)(arow + key));
    bf16x4 pb;
#pragma unroll
    for (int r = 0; r < 4; ++r) pb[r] = (short)f2bf(p[r]);
    int c8 = key >> 3;  // 16B chunk index in q-row
    *(bf16x4*)(U + lr * 4096 + ((c8 ^ (lr & 7)) << 4) + ((key & 7) << 1)) = pb;
  }
  __syncthreads();  // barrier C: P ready, red reads done, stores drained

  // --- PV: wave-private V staging, counted-vmcnt pipeline ------------------
  const unsigned short* Bv = vT + (size_t)gz * 524288 + bz * 2048;
  const int d0 = w * 16;
  const int vd = lane >> 2;                 // 0..15 local d-row
  const int vcs = (lane & 3) ^ (vd & 3);    // pre-swizzled source chunk
  auto stageV = [&](int buf, int t) {
    ASYNC16(Vb + buf * 8192 + w * 1024 + lane * 16,
            Bv + (size_t)(d0 + vd) * 4096 + t * 32 + vcs * 8);
  };

  f32x4 cfr = {};
  stageV(0, 0);
  stageV(1, 1);
#pragma unroll
  for (int t = 0; t < 64; ++t) {
    if (t < 63) asm volatile("s_waitcnt vmcnt(1)" ::: "memory");
    else        asm volatile("s_waitcnt vmcnt(0)" ::: "memory");
    __builtin_amdgcn_sched_barrier(0);
    int c8 = t * 4 + kq;
    bf16x8 pfr = *(const bf16x8*)(U + lr * 4096 + ((c8 ^ (lr & 7)) << 4));
    const char* Vw = Vb + (t & 1) * 8192 + w * 1024;
    bf16x8 vfr = *(const bf16x8*)(Vw + lr * 64 + ((kq ^ (lr & 3)) << 4));
    asm volatile("s_waitcnt lgkmcnt(0)" ::: "memory");
    __builtin_amdgcn_sched_barrier(0);
    if (t + 2 < 64) stageV(t & 1, t + 2);  // reuse just-read buffer
    cfr = __builtin_amdgcn_mfma_f32_16x16x32_bf16(pfr, vfr, cfr, 0, 0, 0);
  }
#pragma unroll
  for (int r = 0; r < 4; ++r) {
    int q = kq * 4 + r;
    ctx[((size_t)(bz * 2048 + q0 + q) * 2048) + hz * 128 + d0 + lr] =
        f2bf(cfr[r]);
  }
}

// ===========================================================================
// 128x128 8-wave GEMM, BK=64 — R11 depth-2 counted-vmcnt schedule, sized so
// M=4096/N=2048 grids give 512 blocks = 2 blocks/CU (cross-block overlap).
// 8 waves = 2M x 4N; per-wave 64x32 (frags 4x2). LDS 64KB. 4 loads/thr/tile.
// ===========================================================================
template <bool OUT_BF16>
__global__ __launch_bounds__(512, 2) void gemm128(
    const unsigned short* __restrict__ A, const unsigned short* __restrict__ Bt,
    void* __restrict__ C_, int K, int lda, int ldb, int ldc) {
  __shared__ unsigned short As[2][128 * 64];  // 32 KB
  __shared__ unsigned short Bs[2][128 * 64];  // 32 KB
  const int tid = threadIdx.x;
  const int bm0 = blockIdx.y * 128, bn0 = blockIdx.x * 128;
  const int lane = tid & 63, wid = tid >> 6;
  const int wr = wid >> 2, wc = wid & 3;      // 2M x 4N
  const int lr = lane & 15, kq = lane >> 4;

  f32x4 acc[4][2] = {};

  int sArow[2], sAcc[2];
#pragma unroll
  for (int R = 0; R < 2; ++R) {
    int c = R * 512 + tid;                    // 0..1023
    sArow[R] = c >> 3;
    sAcc[R]  = (c & 7) ^ (sArow[R] & 7);
  }

  auto stage = [&](int buf, int k0) {  // 4 loads/thread
#pragma unroll
    for (int R = 0; R < 2; ++R)
      ASYNC16(&As[buf][(R * 512 + tid) * 8],
              A + (size_t)(bm0 + sArow[R]) * lda + k0 + sAcc[R] * 8);
#pragma unroll
    for (int R = 0; R < 2; ++R)
      ASYNC16(&Bs[buf][(R * 512 + tid) * 8],
              Bt + (size_t)(bn0 + sArow[R]) * ldb + k0 + sAcc[R] * 8);
  };

  const int NT = K >> 6;
  stage(0, 0);
  stage(1, 64);
  int cur = 0;
  for (int t = 0; t < NT; ++t) {
    if (t + 1 < NT) asm volatile("s_waitcnt vmcnt(4)" ::: "memory");
    else            asm volatile("s_waitcnt vmcnt(0)" ::: "memory");
    __builtin_amdgcn_sched_barrier(0);
    __builtin_amdgcn_s_barrier();
    __builtin_amdgcn_sched_barrier(0);
    const unsigned short* Ac = As[cur];
    const unsigned short* Bc = Bs[cur];
    // ---- ks = 0 ----
    bf16x8 afr0[4], bfr0[2];
#pragma unroll
    for (int i = 0; i < 4; ++i) {
      int row = wr * 64 + i * 16 + lr;
      afr0[i] = *(const bf16x8*)&Ac[(row * 8 + (kq ^ (row & 7))) * 8];
    }
#pragma unroll
    for (int j2 = 0; j2 < 2; ++j2) {
      int brow = wc * 32 + j2 * 16 + lr;
      bfr0[j2] = *(const bf16x8*)&Bc[(brow * 8 + (kq ^ (brow & 7))) * 8];
    }
    __builtin_amdgcn_s_setprio(1);
#pragma unroll
    for (int j2 = 0; j2 < 2; ++j2)
#pragma unroll
      for (int i = 0; i < 4; ++i)
        acc[i][j2] = __builtin_amdgcn_mfma_f32_16x16x32_bf16(afr0[i], bfr0[j2],
                                                             acc[i][j2], 0, 0, 0);
    __builtin_amdgcn_s_setprio(0);
    // ---- ks = 1 ----
    bf16x8 afr1[4], bfr1[2];
#pragma unroll
    for (int i = 0; i < 4; ++i) {
      int row = wr * 64 + i * 16 + lr;
      afr1[i] = *(const bf16x8*)&Ac[(row * 8 + ((4 + kq) ^ (row & 7))) * 8];
    }
#pragma unroll
    for (int j2 = 0; j2 < 2; ++j2) {
      int brow = wc * 32 + j2 * 16 + lr;
      bfr1[j2] = *(const bf16x8*)&Bc[(brow * 8 + ((4 + kq) ^ (brow & 7))) * 8];
    }
    asm volatile("s_waitcnt lgkmcnt(0)" ::: "memory");
    __builtin_amdgcn_sched_barrier(0);
    __builtin_amdgcn_s_barrier();   // all waves' reads of buf[cur] done
    __builtin_amdgcn_sched_barrier(0);
    if (t + 2 < NT) stage(cur, (t + 2) << 6);
    __builtin_amdgcn_s_setprio(1);
#pragma unroll
    for (int j2 = 0; j2 < 2; ++j2)
#pragma unroll
      for (int i = 0; i < 4; ++i)
        acc[i][j2] = __builtin_amdgcn_mfma_f32_16x16x32_bf16(afr1[i], bfr1[j2],
                                                             acc[i][j2], 0, 0, 0);
    __builtin_amdgcn_s_setprio(0);
    cur ^= 1;
  }

#pragma unroll
  for (int i = 0; i < 4; ++i)
#pragma unroll
    for (int j = 0; j < 2; ++j) {
      int rowb = bm0 + wr * 64 + i * 16 + kq * 4;
      int col = bn0 + wc * 32 + j * 16 + lr;
#pragma unroll
      for (int r = 0; r < 4; ++r) {
        if constexpr (OUT_BF16)
          ((unsigned short*)C_)[(size_t)(rowb + r) * ldc + col] = f2bf(acc[i][j][r]);
        else
          ((float*)C_)[(size_t)(rowb + r) * ldc + col] = acc[i][j][r];
      }
    }
}

// ---- GeGLU dual GEMM: R11 depth-2 counted-vmcnt schedule -------------------
__global__ __launch_bounds__(512, 2) void gemm_geglu256(
    const unsigned short* __restrict__ A, const unsigned short* __restrict__ B1,
    const unsigned short* __restrict__ B2, unsigned short* __restrict__ H_,
    int K, int lda, int ldb, int ldc) {
  __shared__ unsigned short As[2][256 * 64];   // 64 KB
  __shared__ unsigned short B1s[2][128 * 64];  // 32 KB
  __shared__ unsigned short B2s[2][128 * 64];  // 32 KB
  const int tid = threadIdx.x;
  const int bm0 = blockIdx.y * 256, bn0 = blockIdx.x * 128;
  const int lane = tid & 63, wid = tid >> 6;
  const int wr = wid >> 2, wc = wid & 3;
  const int lr = lane & 15, kq = lane >> 4;

  f32x4 accu[8][2] = {};
  f32x4 accg[8][2] = {};

  int sArow[4], sAcc[4], sBrow[2], sBcc[2];
#pragma unroll
  for (int R = 0; R < 4; ++R) {
    int c = R * 512 + tid;
    sArow[R] = c >> 3;
    sAcc[R]  = (c & 7) ^ (sArow[R] & 7);
  }
#pragma unroll
  for (int R = 0; R < 2; ++R) {
    int c = R * 512 + tid;
    sBrow[R] = c >> 3;
    sBcc[R]  = (c & 7) ^ (sBrow[R] & 7);
  }

  auto stage = [&](int buf, int k0) {  // 8 loads/thread
#pragma unroll
    for (int R = 0; R < 4; ++R)
      ASYNC16(&As[buf][(R * 512 + tid) * 8],
              A + (size_t)(bm0 + sArow[R]) * lda + k0 + sAcc[R] * 8);
#pragma unroll
    for (int R = 0; R < 2; ++R)
      ASYNC16(&B1s[buf][(R * 512 + tid) * 8],
              B1 + (size_t)(bn0 + sBrow[R]) * ldb + k0 + sBcc[R] * 8);
#pragma unroll
    for (int R = 0; R < 2; ++R)
      ASYNC16(&B2s[buf][(R * 512 + tid) * 8],
              B2 + (size_t)(bn0 + sBrow[R]) * ldb + k0 + sBcc[R] * 8);
  };

  const int NT = K >> 6;
  stage(0, 0);
  stage(1, 64);
  int cur = 0;
  for (int t = 0; t < NT; ++t) {
    if (t + 1 < NT) asm volatile("s_waitcnt vmcnt(8)" ::: "memory");
    else            asm volatile("s_waitcnt vmcnt(0)" ::: "memory");
    __builtin_amdgcn_sched_barrier(0);
    __builtin_amdgcn_s_barrier();
    __builtin_amdgcn_sched_barrier(0);
    const unsigned short* Ac = As[cur];
    const unsigned short* B1c = B1s[cur];
    const unsigned short* B2c = B2s[cur];
    // ---- ks = 0 ----
    bf16x8 afr0[8], b10[2], b20[2];
#pragma unroll
    for (int i = 0; i < 8; ++i) {
      int row = wr * 128 + i * 16 + lr;
      afr0[i] = *(const bf16x8*)&Ac[(row * 8 + (kq ^ (row & 7))) * 8];
    }
#pragma unroll
    for (int j2 = 0; j2 < 2; ++j2) {
      int brow = wc * 32 + j2 * 16 + lr;
      b10[j2] = *(const bf16x8*)&B1c[(brow * 8 + (kq ^ (brow & 7))) * 8];
      b20[j2] = *(const bf16x8*)&B2c[(brow * 8 + (kq ^ (brow & 7))) * 8];
    }
    __builtin_amdgcn_s_setprio(1);
#pragma unroll
    for (int j2 = 0; j2 < 2; ++j2)
#pragma unroll
      for (int i = 0; i < 8; ++i) {
        accu[i][j2] = __builtin_amdgcn_mfma_f32_16x16x32_bf16(afr0[i], b10[j2],
                                                              accu[i][j2], 0, 0, 0);
        accg[i][j2] = __builtin_amdgcn_mfma_f32_16x16x32_bf16(afr0[i], b20[j2],
                                                              accg[i][j2], 0, 0, 0);
      }
    __builtin_amdgcn_s_setprio(0);
    // ---- ks = 1 ----
    bf16x8 afr1[8], b11[2], b21[2];
#pragma unroll
    for (int i = 0; i < 8; ++i) {
      int row = wr * 128 + i * 16 + lr;
      afr1[i] = *(const bf16x8*)&Ac[(row * 8 + ((4 + kq) ^ (row & 7))) * 8];
    }
#pragma unroll
    for (int j2 = 0; j2 < 2; ++j2) {
      int brow = wc * 32 + j2 * 16 + lr;
      b11[j2] = *(const bf16x8*)&B1c[(brow * 8 + ((4 + kq) ^ (brow & 7))) * 8];
      b21[j2] = *(const bf16x8*)&B2c[(brow * 8 + ((4 + kq) ^ (brow & 7))) * 8];
    }
    asm volatile("s_waitcnt lgkmcnt(0)" ::: "memory");
    __builtin_amdgcn_sched_barrier(0);
    __builtin_amdgcn_s_barrier();
    __builtin_amdgcn_sched_barrier(0);
    if (t + 2 < NT) stage(cur, (t + 2) << 6);
    __builtin_amdgcn_s_setprio(1);
#pragma unroll
    for (int j2 = 0; j2 < 2; ++j2)
#pragma unroll
      for (int i = 0; i < 8; ++i) {
        accu[i][j2] = __builtin_amdgcn_mfma_f32_16x16x32_bf16(afr1[i], b11[j2],
                                                              accu[i][j2], 0, 0, 0);
        accg[i][j2] = __builtin_amdgcn_mfma_f32_16x16x32_bf16(afr1[i], b21[j2],
                                                              accg[i][j2], 0, 0, 0);
      }
    __builtin_amdgcn_s_setprio(0);
    cur ^= 1;
  }

#pragma unroll
  for (int i = 0; i < 8; ++i)
#pragma unroll
    for (int j = 0; j < 2; ++j) {
      int rowb = bm0 + wr * 128 + i * 16 + kq * 4;
      int col = bn0 + wc * 32 + j * 16 + lr;
#pragma unroll
      for (int r = 0; r < 4; ++r) {
        float u = accu[i][j][r];
        float g = accg[i][j][r];
        float tv = tanhf(0.7978845608028654f * (g + 0.044715f * g * g * g));
        float hv = u * 0.5f * g * (1.0f + tv);
        H_[(size_t)(rowb + r) * ldc + col] = f2bf(hv);
      }
    }
}

// ---------------------------------------------------------------------------
extern "C" void kernel_launch(void* const* d_in, const int* in_sizes, int n_in,
                              void* d_out, int out_size, void* d_ws, size_t ws_size,
                              hipStream_t stream) {
  const float* x   = (const float*)d_in[0];
  const float* wq  = (const float*)d_in[1];
  const float* wk  = (const float*)d_in[2];
  const float* wv  = (const float*)d_in[3];
  const float* wo  = (const float*)d_in[4];
  const float* w1  = (const float*)d_in[5];
  const float* w2  = (const float*)d_in[6];
  const float* n1w = (const float*)d_in[7];
  const float* n2w = (const float*)d_in[8];

  float* out    = (float*)d_out;
  float* x2_out = out;
  float* k_out  = out + 8388608;
  float* v_out  = out + 16777216;
  float* attn   = out + 25165824;  // 134,217,728 f32

  char* ws = (char*)d_ws;
  unsigned short* wqT  = (unsigned short*)(ws + 0);
  unsigned short* wkT  = (unsigned short*)(ws + 8388608);
  unsigned short* wvT  = (unsigned short*)(ws + 10485760);
  unsigned short* woT  = (unsigned short*)(ws + 12582912);
  unsigned short* w1T  = (unsigned short*)(ws + 20971520);
  unsigned short* w2T  = (unsigned short*)(ws + 88080384);
  unsigned short* qh   = (unsigned short*)(ws + 121634816);
  unsigned short* kh   = (unsigned short*)(ws + 138412032);
  unsigned short* vhT  = (unsigned short*)(ws + 142606336);
  unsigned short* ctx  = (unsigned short*)(ws + 146800640);
  float*          ao   = (float*)(ws + 163577856);
  unsigned short* hbuf = (unsigned short*)(ws + 121634816);  // alias qh..ao (dead)
  unsigned short* x1b  = (unsigned short*)(ws + 197132288);
  unsigned short* fc   = (unsigned short*)(ws + 213909504);
  // ws total: 230,686,720 bytes

  // bf16 scratch inside not-yet-written attn region of d_out
  unsigned short* xb = (unsigned short*)attn;   // bf16(x), 8,388,608 elems
  unsigned short* xq = xb + 8388608;            // bf16(rope(x))

  dim3 blk(256);
  dim3 blk512(512);

  // 1) weight convert+transpose (f32 [K,N] -> bf16 [N,K])
  kconvT<<<dim3(64, 64), blk, 0, stream>>>(wq, wqT, 2048, 2048);
  kconvT<<<dim3(16, 64), blk, 0, stream>>>(wk, wkT, 2048, 512);
  kconvT<<<dim3(16, 64), blk, 0, stream>>>(wv, wvT, 2048, 512);
  kconvT<<<dim3(64, 64), blk, 0, stream>>>(wo, woT, 2048, 2048);
  kconvT<<<dim3(512, 64), blk, 0, stream>>>(w1, w1T, 2048, 16384);
  kconvT<<<dim3(64, 256), blk, 0, stream>>>(w2, w2T, 8192, 2048);

  // 2) k_flat = rope(x), v_flat = x, xq/xb bf16 (fused)
  krope<<<16384, blk, 0, stream>>>(x, k_out, v_out, xq, xb);

  // 3) projections (q: 512 blocks = 2/CU)
  gemm128<true><<<dim3(16, 32), blk512, 0, stream>>>(
      xq, wqT, qh, 2048, 2048, 2048, 2048);
  gemm_bt<true, false><<<dim3(4, 32), blk, 0, stream>>>(
      xq, wkT, kh, 2048, 2048, 2048, 512, 1.0f);
  gemm_bt<true, true><<<dim3(4, 32), blk, 0, stream>>>(
      xb, wvT, vhT, 2048, 2048, 2048, 4096, 1.0f);

  // 4) fused scores + softmax + attn write + PV -> ctx (XCD-swizzled 1D grid)
  kattn<<<dim3(4096), blk512, 0, stream>>>(qh, kh, vhT, attn, ctx);

  // 5) attn_out = ctx @ wo (f32)
  gemm128<false><<<dim3(16, 32), blk512, 0, stream>>>(
      ctx, woT, (void*)ao, 2048, 2048, 2048, 2048);
  // 6) x1b = rmsnorm(x + ao) * n1w
  krms1<<<4096, blk, 0, stream>>>(x, ao, n1w, x1b);
  // 7) h = u * gelu(gate)  (fused dual GEMM, uv never materialized)
  gemm_geglu256<<<dim3(64, 16), blk512, 0, stream>>>(
      x1b, w1T, w1T + 16777216, hbuf, 2048, 2048, 2048, 8192);
  // 8) fc = h @ w2
  gemm128<true><<<dim3(16, 32), blk512, 0, stream>>>(
      hbuf, w2T, fc, 8192, 8192, 8192, 2048);
  // 9) x2 = rmsnorm(x1 + fc) * n2w
  krms2<<<4096, blk, 0, stream>>>(x1b, fc, n2w, x2_out);
}

// Round 16
// 915.150 us; speedup vs baseline: 1.2792x; 1.0280x over previous
//
#include <hip/hip_runtime.h>
#include <hip/hip_bf16.h>

// ---------------------------------------------------------------------------
// TransformerBlock: B=2 N=2048 E=2048 H=16 G=4 D=128 HID=8192
// out = [ x2 (8.39M f32) | k_flat (8.39M) | v_flat (8.39M) | attn (134.2M) ]
// R16: launch consolidation + T5 on kattn.
//  - kconvAll: wq/wk/wv/wo/w1 (all K=2048) converted in ONE launch; their
//    dests are contiguous in ws (verified offsets) => single [21504][2048]
//    bf16 output with uniform per-block source-segment lookup. w2 separate.
//  - kvproj: k & v projections in one launch (blockIdx.z selects operands).
//  - kattn: s_setprio(1) around scores/PV MFMA clusters (T5, attn-positive).
//  14 -> 11 launches. gemm128/gemm_geglu256/kattn-v7 pipelines unchanged.
// ---------------------------------------------------------------------------

using f32x4  = __attribute__((ext_vector_type(4))) float;
using bf16x8 = __attribute__((ext_vector_type(8))) short;
using bf16x4 = __attribute__((ext_vector_type(4))) short;
using u16x4  = __attribute__((ext_vector_type(4))) unsigned short;

#define DEV __device__ __forceinline__

// async global->LDS, 16B per lane; LDS dest must be wave-uniform base + lane*16
#define ASYNC16(lds, g)                                                        \
  __builtin_amdgcn_global_load_lds(                                           \
      (const __attribute__((address_space(1))) void*)(g),                      \
      (__attribute__((address_space(3))) void*)(lds), 16, 0, 0)

DEV unsigned short f2bf(float f) {
  unsigned int u = __float_as_uint(f);
  return (unsigned short)((u + 0x7fffu + ((u >> 16) & 1u)) >> 16);
}
DEV float bf2f(unsigned short h) {
  return __uint_as_float(((unsigned int)h) << 16);
}

DEV float waveRedSum(float v) {
#pragma unroll
  for (int o = 32; o; o >>= 1) v += __shfl_xor(v, o);
  return v;
}

// ---- merged transpose+convert for the five K=2048 weights ------------------
// dst = contiguous [21504][2048] bf16: wqT|wkT|wvT|woT|w1T (offsets verified)
__global__ __launch_bounds__(256) void kconvAll(
    const float* __restrict__ wq, const float* __restrict__ wk,
    const float* __restrict__ wv, const float* __restrict__ wo,
    const float* __restrict__ w1, unsigned short* __restrict__ dst) {
  __shared__ float tile[32][33];
  int bx = blockIdx.x * 32;  // global out-row (= src col) 0..21503
  int by = blockIdx.y * 32;  // K dim 0..2047
  const float* src; int nsrc, c0;
  if (bx < 2048)      { src = wq; nsrc = 2048;  c0 = bx; }
  else if (bx < 2560) { src = wk; nsrc = 512;   c0 = bx - 2048; }
  else if (bx < 3072) { src = wv; nsrc = 512;   c0 = bx - 2560; }
  else if (bx < 5120) { src = wo; nsrc = 2048;  c0 = bx - 3072; }
  else                { src = w1; nsrc = 16384; c0 = bx - 5120; }
  int tx = threadIdx.x & 31;
  int ty = threadIdx.x >> 5;  // 0..7
#pragma unroll
  for (int i = 0; i < 32; i += 8)
    tile[ty + i][tx] = src[(size_t)(by + ty + i) * nsrc + c0 + tx];
  __syncthreads();
#pragma unroll
  for (int i = 0; i < 32; i += 8)
    dst[(size_t)(bx + ty + i) * 2048 + by + tx] = f2bf(tile[tx][ty + i]);
}

// ---- transpose+convert: in f32 [K,N] -> out bf16 [N,K] (w2) ----------------
__global__ __launch_bounds__(256) void kconvT(const float* __restrict__ in,
                                              unsigned short* __restrict__ out,
                                              int K, int N) {
  __shared__ float tile[32][33];
  int bx = blockIdx.x * 32;  // N dim
  int by = blockIdx.y * 32;  // K dim
  int tx = threadIdx.x & 31;
  int ty = threadIdx.x >> 5;  // 0..7
#pragma unroll
  for (int i = 0; i < 32; i += 8)
    tile[ty + i][tx] = in[(size_t)(by + ty + i) * N + bx + tx];
  __syncthreads();
#pragma unroll
  for (int i = 0; i < 32; i += 8)
    out[(size_t)(bx + ty + i) * K + by + tx] = f2bf(tile[tx][ty + i]);
}

// ---- RoPE + v_flat copy + bf16 casts (fused); k/v outs nontemporal ---------
__global__ __launch_bounds__(256) void krope(const float* __restrict__ x,
                                             float* __restrict__ kout,
                                             float* __restrict__ vout,
                                             unsigned short* __restrict__ xq,
                                             unsigned short* __restrict__ xb) {
  int idx = blockIdx.x * 256 + threadIdx.x;  // B*N*H*64 = 4,194,304
  int f  = idx & 63;
  int h  = (idx >> 6) & 15;
  int bn = idx >> 10;          // b*2048+n
  int n  = bn & 2047;
  size_t base = (size_t)bn * 2048 + h * 128;
  float inv = exp2f((float)f * (-13.287712379549449f / 64.0f));
  float ang = (float)n * inv;
  float c = cosf(ang), s = sinf(ang);
  float a = x[base + f], b = x[base + f + 64];
  float k1 = a * c - b * s;
  float k2 = b * c + a * s;
  __builtin_nontemporal_store(k1, kout + base + f);
  __builtin_nontemporal_store(k2, kout + base + f + 64);
  xq[base + f]      = f2bf(k1);
  xq[base + f + 64] = f2bf(k2);
  __builtin_nontemporal_store(a, vout + base + f);
  __builtin_nontemporal_store(b, vout + base + f + 64);
  xb[base + f]      = f2bf(a);
  xb[base + f + 64] = f2bf(b);
}

// ---- x1b = bf16(rmsnorm(x + ao) * w) ---------------------------------------
__global__ __launch_bounds__(256) void krms1(const float* __restrict__ x,
                                             const float* __restrict__ ao,
                                             const float* __restrict__ w,
                                             unsigned short* __restrict__ x1b) {
  size_t row = blockIdx.x;
  const f32x4* xp = (const f32x4*)(x + row * 2048);
  const f32x4* ap = (const f32x4*)(ao + row * 2048);
  int tid = threadIdx.x;
  f32x4 t0 = xp[tid * 2] + ap[tid * 2];
  f32x4 t1 = xp[tid * 2 + 1] + ap[tid * 2 + 1];
  float ss = 0.f;
#pragma unroll
  for (int i = 0; i < 4; ++i) ss += t0[i] * t0[i] + t1[i] * t1[i];
  ss = waveRedSum(ss);
  __shared__ float red[4];
  int wid = tid >> 6, lane = tid & 63;
  if (!lane) red[wid] = ss;
  __syncthreads();
  ss = red[0] + red[1] + red[2] + red[3];
  float rr = rsqrtf(ss * (1.0f / 2048.0f) + 1e-6f);
  const f32x4* wp = (const f32x4*)w;
  f32x4 w0 = wp[tid * 2], w1 = wp[tid * 2 + 1];
  u16x4 o0, o1;
#pragma unroll
  for (int i = 0; i < 4; ++i) {
    o0[i] = f2bf(t0[i] * rr * w0[i]);
    o1[i] = f2bf(t1[i] * rr * w1[i]);
  }
  u16x4* op = (u16x4*)(x1b + row * 2048);
  op[tid * 2] = o0;
  op[tid * 2 + 1] = o1;
}

// ---- x2 = f32(rmsnorm(x1b + fc) * w) -> d_out (nontemporal) ----------------
__global__ __launch_bounds__(256) void krms2(const unsigned short* __restrict__ x1b,
                                             const unsigned short* __restrict__ fc,
                                             const float* __restrict__ w,
                                             float* __restrict__ out) {
  size_t row = blockIdx.x;
  const u16x4* xp = (const u16x4*)(x1b + row * 2048);
  const u16x4* fp = (const u16x4*)(fc + row * 2048);
  int tid = threadIdx.x;
  u16x4 a0 = xp[tid * 2], a1 = xp[tid * 2 + 1];
  u16x4 b0 = fp[tid * 2], b1 = fp[tid * 2 + 1];
  f32x4 t0, t1;
#pragma unroll
  for (int i = 0; i < 4; ++i) {
    t0[i] = bf2f(a0[i]) + bf2f(b0[i]);
    t1[i] = bf2f(a1[i]) + bf2f(b1[i]);
  }
  float ss = 0.f;
#pragma unroll
  for (int i = 0; i < 4; ++i) ss += t0[i] * t0[i] + t1[i] * t1[i];
  ss = waveRedSum(ss);
  __shared__ float red[4];
  int wid = tid >> 6, lane = tid & 63;
  if (!lane) red[wid] = ss;
  __syncthreads();
  ss = red[0] + red[1] + red[2] + red[3];
  float rr = rsqrtf(ss * (1.0f / 2048.0f) + 1e-6f);
  const f32x4* wp = (const f32x4*)w;
  f32x4 w0 = wp[tid * 2], w1 = wp[tid * 2 + 1];
  f32x4* op = (f32x4*)(out + row * 2048);
  f32x4 o0 = t0 * rr * w0;
  f32x4 o1 = t1 * rr * w1;
  __builtin_nontemporal_store(o0, op + tid * 2);
  __builtin_nontemporal_store(o1, op + tid * 2 + 1);
}

// ---- merged k/v projections (z=0: kh = xq@wkT^T; z=1: vhT = (xb@wvT^T)^T) --
__global__ __launch_bounds__(256, 2) void kvproj(
    const unsigned short* __restrict__ xq, const unsigned short* __restrict__ xb,
    const unsigned short* __restrict__ wkT, const unsigned short* __restrict__ wvT,
    unsigned short* __restrict__ kh, unsigned short* __restrict__ vhT) {
  const bool isV = blockIdx.z != 0;
  const unsigned short* A  = isV ? xb : xq;
  const unsigned short* Bt = isV ? wvT : wkT;
  __shared__ unsigned short As[128 * 32];
  __shared__ unsigned short Bs[128 * 32];
  const int tid = threadIdx.x;
  const int bm0 = blockIdx.y * 128, bn0 = blockIdx.x * 128;

  f32x4 acc[4][4] = {};

  const int lane = tid & 63, wid = tid >> 6;
  const int wr = wid >> 1, wc = wid & 1;
  const int lr = lane & 15, kq = lane >> 4;
  const int srow = tid >> 2;        // 0..63
  const int scol = (tid & 3) * 8;   // 0,8,16,24
  unsigned short* AsW = As + tid * 8;
  unsigned short* BsW = Bs + tid * 8;

  for (int kt = 0; kt < 2048; kt += 32) {
    ASYNC16(AsW,        A + (size_t)(bm0 + srow)      * 2048 + kt + scol);
    ASYNC16(AsW + 2048, A + (size_t)(bm0 + srow + 64) * 2048 + kt + scol);
    ASYNC16(BsW,        Bt + (size_t)(bn0 + srow)      * 2048 + kt + scol);
    ASYNC16(BsW + 2048, Bt + (size_t)(bn0 + srow + 64) * 2048 + kt + scol);
    __syncthreads();
    bf16x8 afr[4], bfr[4];
#pragma unroll
    for (int i = 0; i < 4; ++i)
      afr[i] = *(const bf16x8*)&As[(wr * 64 + i * 16 + lr) * 32 + kq * 8];
#pragma unroll
    for (int j = 0; j < 4; ++j)
      bfr[j] = *(const bf16x8*)&Bs[(wc * 64 + j * 16 + lr) * 32 + kq * 8];
#pragma unroll
    for (int i = 0; i < 4; ++i)
#pragma unroll
      for (int j = 0; j < 4; ++j)
        acc[i][j] = __builtin_amdgcn_mfma_f32_16x16x32_bf16(afr[i], bfr[j],
                                                            acc[i][j], 0, 0, 0);
    __syncthreads();
  }

#pragma unroll
  for (int i = 0; i < 4; ++i)
#pragma unroll
    for (int j = 0; j < 4; ++j) {
      int rowb = bm0 + wr * 64 + i * 16 + kq * 4;
      int col = bn0 + wc * 64 + j * 16 + lr;
#pragma unroll
      for (int r = 0; r < 4; ++r) {
        unsigned short v = f2bf(acc[i][j][r]);
        if (isV) vhT[(size_t)col * 4096 + (rowb + r)] = v;
        else     kh[(size_t)(rowb + r) * 512 + col] = v;
      }
    }
}

// ===========================================================================
// Fused attention v8: v7 + s_setprio around MFMA clusters (T5).
// scores: wave-private K staging, counted vmcnt(4); PV: LDS V dbuf,
// counted vmcnt(1). NT attn stores. XCD swizzle g8 = bid&7. 80KB -> 2/CU.
// ===========================================================================
__global__ __launch_bounds__(512, 4) void kattn(
    const unsigned short* __restrict__ qh,   // [b][n][h*128+d] ld 2048
    const unsigned short* __restrict__ kh,   // [b][n][g*128+d] ld 512
    const unsigned short* __restrict__ vT,   // [g*128+d][b*2048+key] ld 4096
    float* __restrict__ attn,                // [b][h][q][key]
    unsigned short* __restrict__ ctx) {      // [b][n][h*128+d] ld 2048
  __shared__ __align__(16) char U[65536];
  __shared__ __align__(16) char Vb[16384];
  float* redm = (float*)Vb;         // [8][16]
  float* reds = redm + 128;         // [8][16]

  const int tid = threadIdx.x;
  const int lane = tid & 63, w = tid >> 6;   // w 0..7
  const int lr = lane & 15, kq = lane >> 4;  // q = lr, quarter = kq
  const int bid = blockIdx.x;
  const int g8 = bid & 7;          // (b,g) slice, 0..7
  const int j  = bid >> 3;         // 0..511
  const int bz = g8 >> 2;          // batch
  const int gz = g8 & 3;           // kv group
  const int hz = gz * 4 + (j & 3); // head (hz>>2 == gz)
  const int q0 = (j >> 2) << 4;    // q-tile * 16
  const int z  = bz * 16 + hz;

  const unsigned short* Aq =
      qh + ((size_t)(bz * 2048 + q0 + lr) * 2048 + hz * 128);
  bf16x8 qfr[4];
#pragma unroll
  for (int kk = 0; kk < 4; ++kk)
    qfr[kk] = *(const bf16x8*)(Aq + kk * 32 + kq * 8);

  // --- scores: wave-private K staging, counted-vmcnt pipeline --------------
  const unsigned short* Kb =
      kh + ((size_t)(bz * 2048) * 512 + gz * 128);
  int krow[4], kcs[4];
#pragma unroll
  for (int R = 0; R < 4; ++R) {
    int idx = R * 64 + lane;
    krow[R] = idx >> 4;
    kcs[R] = (idx & 15) ^ (krow[R] & 7);  // pre-swizzled source chunk
  }
  auto stageK = [&](int buf, int t) {
#pragma unroll
    for (int R = 0; R < 4; ++R)
      ASYNC16(U + buf * 32768 + w * 4096 + (R * 64 + lane) * 16,
              Kb + (size_t)(t * 128 + w * 16 + krow[R]) * 512 + kcs[R] * 8);
  };

  f32x4 acc[16];
#pragma unroll
  for (int t = 0; t < 16; ++t) acc[t] = f32x4{0.f, 0.f, 0.f, 0.f};

  stageK(0, 0);
  stageK(1, 1);
#pragma unroll
  for (int t = 0; t < 16; ++t) {
    if (t < 15) asm volatile("s_waitcnt vmcnt(4)" ::: "memory");
    else        asm volatile("s_waitcnt vmcnt(0)" ::: "memory");
    __builtin_amdgcn_sched_barrier(0);
    const char* Kw = U + (t & 1) * 32768 + w * 4096;
    bf16x8 kfr[4];
#pragma unroll
    for (int kk = 0; kk < 4; ++kk) {
      int cch = (kk * 4 + kq) ^ (lr & 7);
      kfr[kk] = *(const bf16x8*)(Kw + lr * 256 + cch * 16);
    }
    asm volatile("s_waitcnt lgkmcnt(0)" ::: "memory");
    __builtin_amdgcn_sched_barrier(0);
    if (t + 2 < 16) stageK(t & 1, t + 2);  // reuse just-read buffer
    __builtin_amdgcn_s_setprio(1);
#pragma unroll
    for (int kk = 0; kk < 4; ++kk)
      acc[t] = __builtin_amdgcn_mfma_f32_16x16x32_bf16(kfr[kk], qfr[kk],
                                                       acc[t], 0, 0, 0);
    __builtin_amdgcn_s_setprio(0);
  }

  // --- softmax (per-lane q-row = lr) ---------------------------------------
  const float scale = 0.08838834764831845f;
  float mx = -3.4e38f;
#pragma unroll
  for (int t = 0; t < 16; ++t) {
    acc[t] *= scale;
#pragma unroll
    for (int r = 0; r < 4; ++r) mx = fmaxf(mx, acc[t][r]);
  }
  mx = fmaxf(mx, __shfl_xor(mx, 16));
  mx = fmaxf(mx, __shfl_xor(mx, 32));
  if (kq == 0) redm[w * 16 + lr] = mx;
  __syncthreads();  // barrier A
  mx = redm[lr];
#pragma unroll
  for (int ww = 1; ww < 8; ++ww) mx = fmaxf(mx, redm[ww * 16 + lr]);

  float sm = 0.f;
#pragma unroll
  for (int t = 0; t < 16; ++t) {
#pragma unroll
    for (int r = 0; r < 4; ++r) {
      float e = __expf(acc[t][r] - mx);
      acc[t][r] = e;
      sm += e;
    }
  }
  sm += __shfl_xor(sm, 16);
  sm += __shfl_xor(sm, 32);
  if (kq == 0) reds[w * 16 + lr] = sm;
  __syncthreads();  // barrier B
  float smt = reds[lr];
#pragma unroll
  for (int ww = 1; ww < 8; ++ww) smt += reds[ww * 16 + lr];
  float inv = 1.0f / smt;

  // --- write attn f32 (NT) + P bf16 into U (swizzled chunks) ---------------
  float* arow = attn + (((size_t)z * 2048 + q0 + lr) * 2048);
#pragma unroll
  for (int t = 0; t < 16; ++t) {
    int key = t * 128 + w * 16 + kq * 4;
    f32x4 p = acc[t] * inv;
    __builtin_nontemporal_store(p, (f32x4*)(arow + key));
    bf16x4 pb;
#pragma unroll
    for (int r = 0; r < 4; ++r) pb[r] = (short)f2bf(p[r]);
    int c8 = key >> 3;  // 16B chunk index in q-row
    *(bf16x4*)(U + lr * 4096 + ((c8 ^ (lr & 7)) << 4) + ((key & 7) << 1)) = pb;
  }
  __syncthreads();  // barrier C: P ready, red reads done, stores drained

  // --- PV: wave-private V staging, counted-vmcnt pipeline ------------------
  const unsigned short* Bv = vT + (size_t)gz * 524288 + bz * 2048;
  const int d0 = w * 16;
  const int vd = lane >> 2;                 // 0..15 local d-row
  const int vcs = (lane & 3) ^ (vd & 3);    // pre-swizzled source chunk
  auto stageV = [&](int buf, int t) {
    ASYNC16(Vb + buf * 8192 + w * 1024 + lane * 16,
            Bv + (size_t)(d0 + vd) * 4096 + t * 32 + vcs * 8);
  };

  f32x4 cfr = {};
  stageV(0, 0);
  stageV(1, 1);
#pragma unroll
  for (int t = 0; t < 64; ++t) {
    if (t < 63) asm volatile("s_waitcnt vmcnt(1)" ::: "memory");
    else        asm volatile("s_waitcnt vmcnt(0)" ::: "memory");
    __builtin_amdgcn_sched_barrier(0);
    int c8 = t * 4 + kq;
    bf16x8 pfr = *(const bf16x8*)(U + lr * 4096 + ((c8 ^ (lr & 7)) << 4));
    const char* Vw = Vb + (t & 1) * 8192 + w * 1024;
    bf16x8 vfr = *(const bf16x8*)(Vw + lr * 64 + ((kq ^ (lr & 3)) << 4));
    asm volatile("s_waitcnt lgkmcnt(0)" ::: "memory");
    __builtin_amdgcn_sched_barrier(0);
    if (t + 2 < 64) stageV(t & 1, t + 2);  // reuse just-read buffer
    __builtin_amdgcn_s_setprio(1);
    cfr = __builtin_amdgcn_mfma_f32_16x16x32_bf16(pfr, vfr, cfr, 0, 0, 0);
    __builtin_amdgcn_s_setprio(0);
  }
#pragma unroll
  for (int r = 0; r < 4; ++r) {
    int q = kq * 4 + r;
    ctx[((size_t)(bz * 2048 + q0 + q) * 2048) + hz * 128 + d0 + lr] =
        f2bf(cfr[r]);
  }
}

// ===========================================================================
// 128x128 8-wave GEMM, BK=64 — R11 depth-2 counted-vmcnt schedule, 2/CU.
// ===========================================================================
template <bool OUT_BF16>
__global__ __launch_bounds__(512, 2) void gemm128(
    const unsigned short* __restrict__ A, const unsigned short* __restrict__ Bt,
    void* __restrict__ C_, int K, int lda, int ldb, int ldc) {
  __shared__ unsigned short As[2][128 * 64];  // 32 KB
  __shared__ unsigned short Bs[2][128 * 64];  // 32 KB
  const int tid = threadIdx.x;
  const int bm0 = blockIdx.y * 128, bn0 = blockIdx.x * 128;
  const int lane = tid & 63, wid = tid >> 6;
  const int wr = wid >> 2, wc = wid & 3;      // 2M x 4N
  const int lr = lane & 15, kq = lane >> 4;

  f32x4 acc[4][2] = {};

  int sArow[2], sAcc[2];
#pragma unroll
  for (int R = 0; R < 2; ++R) {
    int c = R * 512 + tid;                    // 0..1023
    sArow[R] = c >> 3;
    sAcc[R]  = (c & 7) ^ (sArow[R] & 7);
  }

  auto stage = [&](int buf, int k0) {  // 4 loads/thread
#pragma unroll
    for (int R = 0; R < 2; ++R)
      ASYNC16(&As[buf][(R * 512 + tid) * 8],
              A + (size_t)(bm0 + sArow[R]) * lda + k0 + sAcc[R] * 8);
#pragma unroll
    for (int R = 0; R < 2; ++R)
      ASYNC16(&Bs[buf][(R * 512 + tid) * 8],
              Bt + (size_t)(bn0 + sArow[R]) * ldb + k0 + sAcc[R] * 8);
  };

  const int NT = K >> 6;
  stage(0, 0);
  stage(1, 64);
  int cur = 0;
  for (int t = 0; t < NT; ++t) {
    if (t + 1 < NT) asm volatile("s_waitcnt vmcnt(4)" ::: "memory");
    else            asm volatile("s_waitcnt vmcnt(0)" ::: "memory");
    __builtin_amdgcn_sched_barrier(0);
    __builtin_amdgcn_s_barrier();
    __builtin_amdgcn_sched_barrier(0);
    const unsigned short* Ac = As[cur];
    const unsigned short* Bc = Bs[cur];
    // ---- ks = 0 ----
    bf16x8 afr0[4], bfr0[2];
#pragma unroll
    for (int i = 0; i < 4; ++i) {
      int row = wr * 64 + i * 16 + lr;
      afr0[i] = *(const bf16x8*)&Ac[(row * 8 + (kq ^ (row & 7))) * 8];
    }
#pragma unroll
    for (int j2 = 0; j2 < 2; ++j2) {
      int brow = wc * 32 + j2 * 16 + lr;
      bfr0[j2] = *(const bf16x8*)&Bc[(brow * 8 + (kq ^ (brow & 7))) * 8];
    }
    __builtin_amdgcn_s_setprio(1);
#pragma unroll
    for (int j2 = 0; j2 < 2; ++j2)
#pragma unroll
      for (int i = 0; i < 4; ++i)
        acc[i][j2] = __builtin_amdgcn_mfma_f32_16x16x32_bf16(afr0[i], bfr0[j2],
                                                             acc[i][j2], 0, 0, 0);
    __builtin_amdgcn_s_setprio(0);
    // ---- ks = 1 ----
    bf16x8 afr1[4], bfr1[2];
#pragma unroll
    for (int i = 0; i < 4; ++i) {
      int row = wr * 64 + i * 16 + lr;
      afr1[i] = *(const bf16x8*)&Ac[(row * 8 + ((4 + kq) ^ (row & 7))) * 8];
    }
#pragma unroll
    for (int j2 = 0; j2 < 2; ++j2) {
      int brow = wc * 32 + j2 * 16 + lr;
      bfr1[j2] = *(const bf16x8*)&Bc[(brow * 8 + ((4 + kq) ^ (brow & 7))) * 8];
    }
    asm volatile("s_waitcnt lgkmcnt(0)" ::: "memory");
    __builtin_amdgcn_sched_barrier(0);
    __builtin_amdgcn_s_barrier();   // all waves' reads of buf[cur] done
    __builtin_amdgcn_sched_barrier(0);
    if (t + 2 < NT) stage(cur, (t + 2) << 6);
    __builtin_amdgcn_s_setprio(1);
#pragma unroll
    for (int j2 = 0; j2 < 2; ++j2)
#pragma unroll
      for (int i = 0; i < 4; ++i)
        acc[i][j2] = __builtin_amdgcn_mfma_f32_16x16x32_bf16(afr1[i], bfr1[j2],
                                                             acc[i][j2], 0, 0, 0);
    __builtin_amdgcn_s_setprio(0);
    cur ^= 1;
  }

#pragma unroll
  for (int i = 0; i < 4; ++i)
#pragma unroll
    for (int j = 0; j < 2; ++j) {
      int rowb = bm0 + wr * 64 + i * 16 + kq * 4;
      int col = bn0 + wc * 32 + j * 16 + lr;
#pragma unroll
      for (int r = 0; r < 4; ++r) {
        if constexpr (OUT_BF16)
          ((unsigned short*)C_)[(size_t)(rowb + r) * ldc + col] = f2bf(acc[i][j][r]);
        else
          ((float*)C_)[(size_t)(rowb + r) * ldc + col] = acc[i][j][r];
      }
    }
}

// ---- GeGLU dual GEMM: R11 depth-2 counted-vmcnt schedule -------------------
__global__ __launch_bounds__(512, 2) void gemm_geglu256(
    const unsigned short* __restrict__ A, const unsigned short* __restrict__ B1,
    const unsigned short* __restrict__ B2, unsigned short* __restrict__ H_,
    int K, int lda, int ldb, int ldc) {
  __shared__ unsigned short As[2][256 * 64];   // 64 KB
  __shared__ unsigned short B1s[2][128 * 64];  // 32 KB
  __shared__ unsigned short B2s[2][128 * 64];  // 32 KB
  const int tid = threadIdx.x;
  const int bm0 = blockIdx.y * 256, bn0 = blockIdx.x * 128;
  const int lane = tid & 63, wid = tid >> 6;
  const int wr = wid >> 2, wc = wid & 3;
  const int lr = lane & 15, kq = lane >> 4;

  f32x4 accu[8][2] = {};
  f32x4 accg[8][2] = {};

  int sArow[4], sAcc[4], sBrow[2], sBcc[2];
#pragma unroll
  for (int R = 0; R < 4; ++R) {
    int c = R * 512 + tid;
    sArow[R] = c >> 3;
    sAcc[R]  = (c & 7) ^ (sArow[R] & 7);
  }
#pragma unroll
  for (int R = 0; R < 2; ++R) {
    int c = R * 512 + tid;
    sBrow[R] = c >> 3;
    sBcc[R]  = (c & 7) ^ (sBrow[R] & 7);
  }

  auto stage = [&](int buf, int k0) {  // 8 loads/thread
#pragma unroll
    for (int R = 0; R < 4; ++R)
      ASYNC16(&As[buf][(R * 512 + tid) * 8],
              A + (size_t)(bm0 + sArow[R]) * lda + k0 + sAcc[R] * 8);
#pragma unroll
    for (int R = 0; R < 2; ++R)
      ASYNC16(&B1s[buf][(R * 512 + tid) * 8],
              B1 + (size_t)(bn0 + sBrow[R]) * ldb + k0 + sBcc[R] * 8);
#pragma unroll
    for (int R = 0; R < 2; ++R)
      ASYNC16(&B2s[buf][(R * 512 + tid) * 8],
              B2 + (size_t)(bn0 + sBrow[R]) * ldb + k0 + sBcc[R] * 8);
  };

  const int NT = K >> 6;
  stage(0, 0);
  stage(1, 64);
  int cur = 0;
  for (int t = 0; t < NT; ++t) {
    if (t + 1 < NT) asm volatile("s_waitcnt vmcnt(8)" ::: "memory");
    else            asm volatile("s_waitcnt vmcnt(0)" ::: "memory");
    __builtin_amdgcn_sched_barrier(0);
    __builtin_amdgcn_s_barrier();
    __builtin_amdgcn_sched_barrier(0);
    const unsigned short* Ac = As[cur];
    const unsigned short* B1c = B1s[cur];
    const unsigned short* B2c = B2s[cur];
    // ---- ks = 0 ----
    bf16x8 afr0[8], b10[2], b20[2];
#pragma unroll
    for (int i = 0; i < 8; ++i) {
      int row = wr * 128 + i * 16 + lr;
      afr0[i] = *(const bf16x8*)&Ac[(row * 8 + (kq ^ (row & 7))) * 8];
    }
#pragma unroll
    for (int j2 = 0; j2 < 2; ++j2) {
      int brow = wc * 32 + j2 * 16 + lr;
      b10[j2] = *(const bf16x8*)&B1c[(brow * 8 + (kq ^ (brow & 7))) * 8];
      b20[j2] = *(const bf16x8*)&B2c[(brow * 8 + (kq ^ (brow & 7))) * 8];
    }
    __builtin_amdgcn_s_setprio(1);
#pragma unroll
    for (int j2 = 0; j2 < 2; ++j2)
#pragma unroll
      for (int i = 0; i < 8; ++i) {
        accu[i][j2] = __builtin_amdgcn_mfma_f32_16x16x32_bf16(afr0[i], b10[j2],
                                                              accu[i][j2], 0, 0, 0);
        accg[i][j2] = __builtin_amdgcn_mfma_f32_16x16x32_bf16(afr0[i], b20[j2],
                                                              accg[i][j2], 0, 0, 0);
      }
    __builtin_amdgcn_s_setprio(0);
    // ---- ks = 1 ----
    bf16x8 afr1[8], b11[2], b21[2];
#pragma unroll
    for (int i = 0; i < 8; ++i) {
      int row = wr * 128 + i * 16 + lr;
      afr1[i] = *(const bf16x8*)&Ac[(row * 8 + ((4 + kq) ^ (row & 7))) * 8];
    }
#pragma unroll
    for (int j2 = 0; j2 < 2; ++j2) {
      int brow = wc * 32 + j2 * 16 + lr;
      b11[j2] = *(const bf16x8*)&B1c[(brow * 8 + ((4 + kq) ^ (brow & 7))) * 8];
      b21[j2] = *(const bf16x8*)&B2c[(brow * 8 + ((4 + kq) ^ (brow & 7))) * 8];
    }
    asm volatile("s_waitcnt lgkmcnt(0)" ::: "memory");
    __builtin_amdgcn_sched_barrier(0);
    __builtin_amdgcn_s_barrier();
    __builtin_amdgcn_sched_barrier(0);
    if (t + 2 < NT) stage(cur, (t + 2) << 6);
    __builtin_amdgcn_s_setprio(1);
#pragma unroll
    for (int j2 = 0; j2 < 2; ++j2)
#pragma unroll
      for (int i = 0; i < 8; ++i) {
        accu[i][j2] = __builtin_amdgcn_mfma_f32_16x16x32_bf16(afr1[i], b11[j2],
                                                              accu[i][j2], 0, 0, 0);
        accg[i][j2] = __builtin_amdgcn_mfma_f32_16x16x32_bf16(afr1[i], b21[j2],
                                                              accg[i][j2], 0, 0, 0);
      }
    __builtin_amdgcn_s_setprio(0);
    cur ^= 1;
  }

#pragma unroll
  for (int i = 0; i < 8; ++i)
#pragma unroll
    for (int j = 0; j < 2; ++j) {
      int rowb = bm0 + wr * 128 + i * 16 + kq * 4;
      int col = bn0 + wc * 32 + j * 16 + lr;
#pragma unroll
      for (int r = 0; r < 4; ++r) {
        float u = accu[i][j][r];
        float g = accg[i][j][r];
        float tv = tanhf(0.7978845608028654f * (g + 0.044715f * g * g * g));
        float hv = u * 0.5f * g * (1.0f + tv);
        H_[(size_t)(rowb + r) * ldc + col] = f2bf(hv);
      }
    }
}

// ---------------------------------------------------------------------------
extern "C" void kernel_launch(void* const* d_in, const int* in_sizes, int n_in,
                              void* d_out, int out_size, void* d_ws, size_t ws_size,
                              hipStream_t stream) {
  const float* x   = (const float*)d_in[0];
  const float* wq  = (const float*)d_in[1];
  const float* wk  = (const float*)d_in[2];
  const float* wv  = (const float*)d_in[3];
  const float* wo  = (const float*)d_in[4];
  const float* w1  = (const float*)d_in[5];
  const float* w2  = (const float*)d_in[6];
  const float* n1w = (const float*)d_in[7];
  const float* n2w = (const float*)d_in[8];

  float* out    = (float*)d_out;
  float* x2_out = out;
  float* k_out  = out + 8388608;
  float* v_out  = out + 16777216;
  float* attn   = out + 25165824;  // 134,217,728 f32

  char* ws = (char*)d_ws;
  unsigned short* wqT  = (unsigned short*)(ws + 0);
  unsigned short* wkT  = (unsigned short*)(ws + 8388608);
  unsigned short* wvT  = (unsigned short*)(ws + 10485760);
  unsigned short* woT  = (unsigned short*)(ws + 12582912);
  unsigned short* w1T  = (unsigned short*)(ws + 20971520);
  unsigned short* w2T  = (unsigned short*)(ws + 88080384);
  unsigned short* qh   = (unsigned short*)(ws + 121634816);
  unsigned short* kh   = (unsigned short*)(ws + 138412032);
  unsigned short* vhT  = (unsigned short*)(ws + 142606336);
  unsigned short* ctx  = (unsigned short*)(ws + 146800640);
  float*          ao   = (float*)(ws + 163577856);
  unsigned short* hbuf = (unsigned short*)(ws + 121634816);  // alias qh..ao (dead)
  unsigned short* x1b  = (unsigned short*)(ws + 197132288);
  unsigned short* fc   = (unsigned short*)(ws + 213909504);
  // ws total: 230,686,720 bytes

  // bf16 scratch inside not-yet-written attn region of d_out
  unsigned short* xb = (unsigned short*)attn;   // bf16(x), 8,388,608 elems
  unsigned short* xq = xb + 8388608;            // bf16(rope(x))

  dim3 blk(256);
  dim3 blk512(512);

  // 1) weight convert+transpose: wq|wk|wv|wo|w1 fused (contiguous dests), w2
  kconvAll<<<dim3(672, 64), blk, 0, stream>>>(wq, wk, wv, wo, w1, wqT);
  kconvT<<<dim3(64, 256), blk, 0, stream>>>(w2, w2T, 8192, 2048);

  // 2) k_flat = rope(x), v_flat = x, xq/xb bf16 (fused)
  krope<<<16384, blk, 0, stream>>>(x, k_out, v_out, xq, xb);

  // 3) projections (q: 512 blocks = 2/CU; k+v merged)
  gemm128<true><<<dim3(16, 32), blk512, 0, stream>>>(
      xq, wqT, qh, 2048, 2048, 2048, 2048);
  kvproj<<<dim3(4, 32, 2), blk, 0, stream>>>(xq, xb, wkT, wvT, kh, vhT);

  // 4) fused scores + softmax + attn write + PV -> ctx (XCD-swizzled 1D grid)
  kattn<<<dim3(4096), blk512, 0, stream>>>(qh, kh, vhT, attn, ctx);

  // 5) attn_out = ctx @ wo (f32)
  gemm128<false><<<dim3(16, 32), blk512, 0, stream>>>(
      ctx, woT, (void*)ao, 2048, 2048, 2048, 2048);
  // 6) x1b = rmsnorm(x + ao) * n1w
  krms1<<<4096, blk, 0, stream>>>(x, ao, n1w, x1b);
  // 7) h = u * gelu(gate)  (fused dual GEMM, uv never materialized)
  gemm_geglu256<<<dim3(64, 16), blk512, 0, stream>>>(
      x1b, w1T, w1T + 16777216, hbuf, 2048, 2048, 2048, 8192);
  // 8) fc = h @ w2
  gemm128<true><<<dim3(16, 32), blk512, 0, stream>>>(
      hbuf, w2T, fc, 8192, 8192, 8192, 2048);
  // 9) x2 = rmsnorm(x1 + fc) * n2w
  krms2<<<4096, blk, 0, stream>>>(x1b, fc, n2w, x2_out);
}

// Round 17
// 913.243 us; speedup vs baseline: 1.2818x; 1.0021x over previous
//
#include <hip/hip_runtime.h>
#include <hip/hip_bf16.h>

// ---------------------------------------------------------------------------
// TransformerBlock: B=2 N=2048 E=2048 H=16 G=4 D=128 HID=8192
// out = [ x2 (8.39M f32) | k_flat (8.39M) | v_flat (8.39M) | attn (134.2M) ]
// R17: XCD-chunked grid tiling for gemm128 (q/wo/fc) and gemm_geglu256.
//      Each XCD's 64 co-resident blocks form an 8x8 (MxN) tile -> per K-step
//      its L2 fetches 8 A-slices + 8 B-slices for 64 blocks (was ~34 slices
//      with round-robin scatter). Mechanism = T1 (bid&7->XCD confirmed R10).
//      Bijective decode; everything else identical to R16 (915us).
// ---------------------------------------------------------------------------

using f32x4  = __attribute__((ext_vector_type(4))) float;
using bf16x8 = __attribute__((ext_vector_type(8))) short;
using bf16x4 = __attribute__((ext_vector_type(4))) short;
using u16x4  = __attribute__((ext_vector_type(4))) unsigned short;

#define DEV __device__ __forceinline__

// async global->LDS, 16B per lane; LDS dest must be wave-uniform base + lane*16
#define ASYNC16(lds, g)                                                        \
  __builtin_amdgcn_global_load_lds(                                           \
      (const __attribute__((address_space(1))) void*)(g),                      \
      (__attribute__((address_space(3))) void*)(lds), 16, 0, 0)

DEV unsigned short f2bf(float f) {
  unsigned int u = __float_as_uint(f);
  return (unsigned short)((u + 0x7fffu + ((u >> 16) & 1u)) >> 16);
}
DEV float bf2f(unsigned short h) {
  return __uint_as_float(((unsigned int)h) << 16);
}

DEV float waveRedSum(float v) {
#pragma unroll
  for (int o = 32; o; o >>= 1) v += __shfl_xor(v, o);
  return v;
}

// ---- merged transpose+convert for the five K=2048 weights ------------------
__global__ __launch_bounds__(256) void kconvAll(
    const float* __restrict__ wq, const float* __restrict__ wk,
    const float* __restrict__ wv, const float* __restrict__ wo,
    const float* __restrict__ w1, unsigned short* __restrict__ dst) {
  __shared__ float tile[32][33];
  int bx = blockIdx.x * 32;  // global out-row (= src col) 0..21503
  int by = blockIdx.y * 32;  // K dim 0..2047
  const float* src; int nsrc, c0;
  if (bx < 2048)      { src = wq; nsrc = 2048;  c0 = bx; }
  else if (bx < 2560) { src = wk; nsrc = 512;   c0 = bx - 2048; }
  else if (bx < 3072) { src = wv; nsrc = 512;   c0 = bx - 2560; }
  else if (bx < 5120) { src = wo; nsrc = 2048;  c0 = bx - 3072; }
  else                { src = w1; nsrc = 16384; c0 = bx - 5120; }
  int tx = threadIdx.x & 31;
  int ty = threadIdx.x >> 5;  // 0..7
#pragma unroll
  for (int i = 0; i < 32; i += 8)
    tile[ty + i][tx] = src[(size_t)(by + ty + i) * nsrc + c0 + tx];
  __syncthreads();
#pragma unroll
  for (int i = 0; i < 32; i += 8)
    dst[(size_t)(bx + ty + i) * 2048 + by + tx] = f2bf(tile[tx][ty + i]);
}

// ---- transpose+convert: in f32 [K,N] -> out bf16 [N,K] (w2) ----------------
__global__ __launch_bounds__(256) void kconvT(const float* __restrict__ in,
                                              unsigned short* __restrict__ out,
                                              int K, int N) {
  __shared__ float tile[32][33];
  int bx = blockIdx.x * 32;  // N dim
  int by = blockIdx.y * 32;  // K dim
  int tx = threadIdx.x & 31;
  int ty = threadIdx.x >> 5;  // 0..7
#pragma unroll
  for (int i = 0; i < 32; i += 8)
    tile[ty + i][tx] = in[(size_t)(by + ty + i) * N + bx + tx];
  __syncthreads();
#pragma unroll
  for (int i = 0; i < 32; i += 8)
    out[(size_t)(bx + ty + i) * K + by + tx] = f2bf(tile[tx][ty + i]);
}

// ---- RoPE + v_flat copy + bf16 casts (fused); k/v outs nontemporal ---------
__global__ __launch_bounds__(256) void krope(const float* __restrict__ x,
                                             float* __restrict__ kout,
                                             float* __restrict__ vout,
                                             unsigned short* __restrict__ xq,
                                             unsigned short* __restrict__ xb) {
  int idx = blockIdx.x * 256 + threadIdx.x;  // B*N*H*64 = 4,194,304
  int f  = idx & 63;
  int h  = (idx >> 6) & 15;
  int bn = idx >> 10;          // b*2048+n
  int n  = bn & 2047;
  size_t base = (size_t)bn * 2048 + h * 128;
  float inv = exp2f((float)f * (-13.287712379549449f / 64.0f));
  float ang = (float)n * inv;
  float c = cosf(ang), s = sinf(ang);
  float a = x[base + f], b = x[base + f + 64];
  float k1 = a * c - b * s;
  float k2 = b * c + a * s;
  __builtin_nontemporal_store(k1, kout + base + f);
  __builtin_nontemporal_store(k2, kout + base + f + 64);
  xq[base + f]      = f2bf(k1);
  xq[base + f + 64] = f2bf(k2);
  __builtin_nontemporal_store(a, vout + base + f);
  __builtin_nontemporal_store(b, vout + base + f + 64);
  xb[base + f]      = f2bf(a);
  xb[base + f + 64] = f2bf(b);
}

// ---- x1b = bf16(rmsnorm(x + ao) * w) ---------------------------------------
__global__ __launch_bounds__(256) void krms1(const float* __restrict__ x,
                                             const float* __restrict__ ao,
                                             const float* __restrict__ w,
                                             unsigned short* __restrict__ x1b) {
  size_t row = blockIdx.x;
  const f32x4* xp = (const f32x4*)(x + row * 2048);
  const f32x4* ap = (const f32x4*)(ao + row * 2048);
  int tid = threadIdx.x;
  f32x4 t0 = xp[tid * 2] + ap[tid * 2];
  f32x4 t1 = xp[tid * 2 + 1] + ap[tid * 2 + 1];
  float ss = 0.f;
#pragma unroll
  for (int i = 0; i < 4; ++i) ss += t0[i] * t0[i] + t1[i] * t1[i];
  ss = waveRedSum(ss);
  __shared__ float red[4];
  int wid = tid >> 6, lane = tid & 63;
  if (!lane) red[wid] = ss;
  __syncthreads();
  ss = red[0] + red[1] + red[2] + red[3];
  float rr = rsqrtf(ss * (1.0f / 2048.0f) + 1e-6f);
  const f32x4* wp = (const f32x4*)w;
  f32x4 w0 = wp[tid * 2], w1 = wp[tid * 2 + 1];
  u16x4 o0, o1;
#pragma unroll
  for (int i = 0; i < 4; ++i) {
    o0[i] = f2bf(t0[i] * rr * w0[i]);
    o1[i] = f2bf(t1[i] * rr * w1[i]);
  }
  u16x4* op = (u16x4*)(x1b + row * 2048);
  op[tid * 2] = o0;
  op[tid * 2 + 1] = o1;
}

// ---- x2 = f32(rmsnorm(x1b + fc) * w) -> d_out (nontemporal) ----------------
__global__ __launch_bounds__(256) void krms2(const unsigned short* __restrict__ x1b,
                                             const unsigned short* __restrict__ fc,
                                             const float* __restrict__ w,
                                             float* __restrict__ out) {
  size_t row = blockIdx.x;
  const u16x4* xp = (const u16x4*)(x1b + row * 2048);
  const u16x4* fp = (const u16x4*)(fc + row * 2048);
  int tid = threadIdx.x;
  u16x4 a0 = xp[tid * 2], a1 = xp[tid * 2 + 1];
  u16x4 b0 = fp[tid * 2], b1 = fp[tid * 2 + 1];
  f32x4 t0, t1;
#pragma unroll
  for (int i = 0; i < 4; ++i) {
    t0[i] = bf2f(a0[i]) + bf2f(b0[i]);
    t1[i] = bf2f(a1[i]) + bf2f(b1[i]);
  }
  float ss = 0.f;
#pragma unroll
  for (int i = 0; i < 4; ++i) ss += t0[i] * t0[i] + t1[i] * t1[i];
  ss = waveRedSum(ss);
  __shared__ float red[4];
  int wid = tid >> 6, lane = tid & 63;
  if (!lane) red[wid] = ss;
  __syncthreads();
  ss = red[0] + red[1] + red[2] + red[3];
  float rr = rsqrtf(ss * (1.0f / 2048.0f) + 1e-6f);
  const f32x4* wp = (const f32x4*)w;
  f32x4 w0 = wp[tid * 2], w1 = wp[tid * 2 + 1];
  f32x4* op = (f32x4*)(out + row * 2048);
  f32x4 o0 = t0 * rr * w0;
  f32x4 o1 = t1 * rr * w1;
  __builtin_nontemporal_store(o0, op + tid * 2);
  __builtin_nontemporal_store(o1, op + tid * 2 + 1);
}

// ---- merged k/v projections (z=0: kh = xq@wkT^T; z=1: vhT = (xb@wvT^T)^T) --
__global__ __launch_bounds__(256, 2) void kvproj(
    const unsigned short* __restrict__ xq, const unsigned short* __restrict__ xb,
    const unsigned short* __restrict__ wkT, const unsigned short* __restrict__ wvT,
    unsigned short* __restrict__ kh, unsigned short* __restrict__ vhT) {
  const bool isV = blockIdx.z != 0;
  const unsigned short* A  = isV ? xb : xq;
  const unsigned short* Bt = isV ? wvT : wkT;
  __shared__ unsigned short As[128 * 32];
  __shared__ unsigned short Bs[128 * 32];
  const int tid = threadIdx.x;
  const int bm0 = blockIdx.y * 128, bn0 = blockIdx.x * 128;

  f32x4 acc[4][4] = {};

  const int lane = tid & 63, wid = tid >> 6;
  const int wr = wid >> 1, wc = wid & 1;
  const int lr = lane & 15, kq = lane >> 4;
  const int srow = tid >> 2;        // 0..63
  const int scol = (tid & 3) * 8;   // 0,8,16,24
  unsigned short* AsW = As + tid * 8;
  unsigned short* BsW = Bs + tid * 8;

  for (int kt = 0; kt < 2048; kt += 32) {
    ASYNC16(AsW,        A + (size_t)(bm0 + srow)      * 2048 + kt + scol);
    ASYNC16(AsW + 2048, A + (size_t)(bm0 + srow + 64) * 2048 + kt + scol);
    ASYNC16(BsW,        Bt + (size_t)(bn0 + srow)      * 2048 + kt + scol);
    ASYNC16(BsW + 2048, Bt + (size_t)(bn0 + srow + 64) * 2048 + kt + scol);
    __syncthreads();
    bf16x8 afr[4], bfr[4];
#pragma unroll
    for (int i = 0; i < 4; ++i)
      afr[i] = *(const bf16x8*)&As[(wr * 64 + i * 16 + lr) * 32 + kq * 8];
#pragma unroll
    for (int j = 0; j < 4; ++j)
      bfr[j] = *(const bf16x8*)&Bs[(wc * 64 + j * 16 + lr) * 32 + kq * 8];
#pragma unroll
    for (int i = 0; i < 4; ++i)
#pragma unroll
      for (int j = 0; j < 4; ++j)
        acc[i][j] = __builtin_amdgcn_mfma_f32_16x16x32_bf16(afr[i], bfr[j],
                                                            acc[i][j], 0, 0, 0);
    __syncthreads();
  }

#pragma unroll
  for (int i = 0; i < 4; ++i)
#pragma unroll
    for (int j = 0; j < 4; ++j) {
      int rowb = bm0 + wr * 64 + i * 16 + kq * 4;
      int col = bn0 + wc * 64 + j * 16 + lr;
#pragma unroll
      for (int r = 0; r < 4; ++r) {
        unsigned short v = f2bf(acc[i][j][r]);
        if (isV) vhT[(size_t)col * 4096 + (rowb + r)] = v;
        else     kh[(size_t)(rowb + r) * 512 + col] = v;
      }
    }
}

// ===========================================================================
// Fused attention v8 (unchanged from R16): counted-vmcnt pipelines, NT attn
// stores, T5 setprio, XCD swizzle g8 = bid&7. 80KB -> 2/CU.
// ===========================================================================
__global__ __launch_bounds__(512, 4) void kattn(
    const unsigned short* __restrict__ qh,   // [b][n][h*128+d] ld 2048
    const unsigned short* __restrict__ kh,   // [b][n][g*128+d] ld 512
    const unsigned short* __restrict__ vT,   // [g*128+d][b*2048+key] ld 4096
    float* __restrict__ attn,                // [b][h][q][key]
    unsigned short* __restrict__ ctx) {      // [b][n][h*128+d] ld 2048
  __shared__ __align__(16) char U[65536];
  __shared__ __align__(16) char Vb[16384];
  float* redm = (float*)Vb;         // [8][16]
  float* reds = redm + 128;         // [8][16]

  const int tid = threadIdx.x;
  const int lane = tid & 63, w = tid >> 6;   // w 0..7
  const int lr = lane & 15, kq = lane >> 4;  // q = lr, quarter = kq
  const int bid = blockIdx.x;
  const int g8 = bid & 7;          // (b,g) slice, 0..7
  const int j  = bid >> 3;         // 0..511
  const int bz = g8 >> 2;          // batch
  const int gz = g8 & 3;           // kv group
  const int hz = gz * 4 + (j & 3); // head (hz>>2 == gz)
  const int q0 = (j >> 2) << 4;    // q-tile * 16
  const int z  = bz * 16 + hz;

  const unsigned short* Aq =
      qh + ((size_t)(bz * 2048 + q0 + lr) * 2048 + hz * 128);
  bf16x8 qfr[4];
#pragma unroll
  for (int kk = 0; kk < 4; ++kk)
    qfr[kk] = *(const bf16x8*)(Aq + kk * 32 + kq * 8);

  // --- scores: wave-private K staging, counted-vmcnt pipeline --------------
  const unsigned short* Kb =
      kh + ((size_t)(bz * 2048) * 512 + gz * 128);
  int krow[4], kcs[4];
#pragma unroll
  for (int R = 0; R < 4; ++R) {
    int idx = R * 64 + lane;
    krow[R] = idx >> 4;
    kcs[R] = (idx & 15) ^ (krow[R] & 7);  // pre-swizzled source chunk
  }
  auto stageK = [&](int buf, int t) {
#pragma unroll
    for (int R = 0; R < 4; ++R)
      ASYNC16(U + buf * 32768 + w * 4096 + (R * 64 + lane) * 16,
              Kb + (size_t)(t * 128 + w * 16 + krow[R]) * 512 + kcs[R] * 8);
  };

  f32x4 acc[16];
#pragma unroll
  for (int t = 0; t < 16; ++t) acc[t] = f32x4{0.f, 0.f, 0.f, 0.f};

  stageK(0, 0);
  stageK(1, 1);
#pragma unroll
  for (int t = 0; t < 16; ++t) {
    if (t < 15) asm volatile("s_waitcnt vmcnt(4)" ::: "memory");
    else        asm volatile("s_waitcnt vmcnt(0)" ::: "memory");
    __builtin_amdgcn_sched_barrier(0);
    const char* Kw = U + (t & 1) * 32768 + w * 4096;
    bf16x8 kfr[4];
#pragma unroll
    for (int kk = 0; kk < 4; ++kk) {
      int cch = (kk * 4 + kq) ^ (lr & 7);
      kfr[kk] = *(const bf16x8*)(Kw + lr * 256 + cch * 16);
    }
    asm volatile("s_waitcnt lgkmcnt(0)" ::: "memory");
    __builtin_amdgcn_sched_barrier(0);
    if (t + 2 < 16) stageK(t & 1, t + 2);  // reuse just-read buffer
    __builtin_amdgcn_s_setprio(1);
#pragma unroll
    for (int kk = 0; kk < 4; ++kk)
      acc[t] = __builtin_amdgcn_mfma_f32_16x16x32_bf16(kfr[kk], qfr[kk],
                                                       acc[t], 0, 0, 0);
    __builtin_amdgcn_s_setprio(0);
  }

  // --- softmax (per-lane q-row = lr) ---------------------------------------
  const float scale = 0.08838834764831845f;
  float mx = -3.4e38f;
#pragma unroll
  for (int t = 0; t < 16; ++t) {
    acc[t] *= scale;
#pragma unroll
    for (int r = 0; r < 4; ++r) mx = fmaxf(mx, acc[t][r]);
  }
  mx = fmaxf(mx, __shfl_xor(mx, 16));
  mx = fmaxf(mx, __shfl_xor(mx, 32));
  if (kq == 0) redm[w * 16 + lr] = mx;
  __syncthreads();  // barrier A
  mx = redm[lr];
#pragma unroll
  for (int ww = 1; ww < 8; ++ww) mx = fmaxf(mx, redm[ww * 16 + lr]);

  float sm = 0.f;
#pragma unroll
  for (int t = 0; t < 16; ++t) {
#pragma unroll
    for (int r = 0; r < 4; ++r) {
      float e = __expf(acc[t][r] - mx);
      acc[t][r] = e;
      sm += e;
    }
  }
  sm += __shfl_xor(sm, 16);
  sm += __shfl_xor(sm, 32);
  if (kq == 0) reds[w * 16 + lr] = sm;
  __syncthreads();  // barrier B
  float smt = reds[lr];
#pragma unroll
  for (int ww = 1; ww < 8; ++ww) smt += reds[ww * 16 + lr];
  float inv = 1.0f / smt;

  // --- write attn f32 (NT) + P bf16 into U (swizzled chunks) ---------------
  float* arow = attn + (((size_t)z * 2048 + q0 + lr) * 2048);
#pragma unroll
  for (int t = 0; t < 16; ++t) {
    int key = t * 128 + w * 16 + kq * 4;
    f32x4 p = acc[t] * inv;
    __builtin_nontemporal_store(p, (f32x4*)(arow + key));
    bf16x4 pb;
#pragma unroll
    for (int r = 0; r < 4; ++r) pb[r] = (short)f2bf(p[r]);
    int c8 = key >> 3;  // 16B chunk index in q-row
    *(bf16x4*)(U + lr * 4096 + ((c8 ^ (lr & 7)) << 4) + ((key & 7) << 1)) = pb;
  }
  __syncthreads();  // barrier C: P ready, red reads done, stores drained

  // --- PV: wave-private V staging, counted-vmcnt pipeline ------------------
  const unsigned short* Bv = vT + (size_t)gz * 524288 + bz * 2048;
  const int d0 = w * 16;
  const int vd = lane >> 2;                 // 0..15 local d-row
  const int vcs = (lane & 3) ^ (vd & 3);    // pre-swizzled source chunk
  auto stageV = [&](int buf, int t) {
    ASYNC16(Vb + buf * 8192 + w * 1024 + lane * 16,
            Bv + (size_t)(d0 + vd) * 4096 + t * 32 + vcs * 8);
  };

  f32x4 cfr = {};
  stageV(0, 0);
  stageV(1, 1);
#pragma unroll
  for (int t = 0; t < 64; ++t) {
    if (t < 63) asm volatile("s_waitcnt vmcnt(1)" ::: "memory");
    else        asm volatile("s_waitcnt vmcnt(0)" ::: "memory");
    __builtin_amdgcn_sched_barrier(0);
    int c8 = t * 4 + kq;
    bf16x8 pfr = *(const bf16x8*)(U + lr * 4096 + ((c8 ^ (lr & 7)) << 4));
    const char* Vw = Vb + (t & 1) * 8192 + w * 1024;
    bf16x8 vfr = *(const bf16x8*)(Vw + lr * 64 + ((kq ^ (lr & 3)) << 4));
    asm volatile("s_waitcnt lgkmcnt(0)" ::: "memory");
    __builtin_amdgcn_sched_barrier(0);
    if (t + 2 < 64) stageV(t & 1, t + 2);  // reuse just-read buffer
    __builtin_amdgcn_s_setprio(1);
    cfr = __builtin_amdgcn_mfma_f32_16x16x32_bf16(pfr, vfr, cfr, 0, 0, 0);
    __builtin_amdgcn_s_setprio(0);
  }
#pragma unroll
  for (int r = 0; r < 4; ++r) {
    int q = kq * 4 + r;
    ctx[((size_t)(bz * 2048 + q0 + q) * 2048) + hz * 128 + d0 + lr] =
        f2bf(cfr[r]);
  }
}

// ===========================================================================
// 128x128 8-wave GEMM, BK=64 — R11 depth-2 counted-vmcnt schedule, 2/CU.
// R17: 1D grid 512, XCD-chunked decode: each XCD's 64 resident blocks form
// an 8x8 (M x N) tile of the 32x16 block grid (bijective).
// ===========================================================================
template <bool OUT_BF16>
__global__ __launch_bounds__(512, 2) void gemm128(
    const unsigned short* __restrict__ A, const unsigned short* __restrict__ Bt,
    void* __restrict__ C_, int K, int lda, int ldb, int ldc) {
  __shared__ unsigned short As[2][128 * 64];  // 32 KB
  __shared__ unsigned short Bs[2][128 * 64];  // 32 KB
  const int tid = threadIdx.x;
  // XCD-chunked decode (grid = 512 = 32 M-blocks x 16 N-blocks):
  const int bid = blockIdx.x;
  const int xcd = bid & 7, ii = bid >> 3;       // ii 0..63
  const int my = (xcd >> 1) * 8 + (ii & 7);     // M-block 0..31
  const int nx = (xcd & 1) * 8 + (ii >> 3);     // N-block 0..15
  const int bm0 = my * 128, bn0 = nx * 128;
  const int lane = tid & 63, wid = tid >> 6;
  const int wr = wid >> 2, wc = wid & 3;        // 2M x 4N
  const int lr = lane & 15, kq = lane >> 4;

  f32x4 acc[4][2] = {};

  int sArow[2], sAcc[2];
#pragma unroll
  for (int R = 0; R < 2; ++R) {
    int c = R * 512 + tid;                    // 0..1023
    sArow[R] = c >> 3;
    sAcc[R]  = (c & 7) ^ (sArow[R] & 7);
  }

  auto stage = [&](int buf, int k0) {  // 4 loads/thread
#pragma unroll
    for (int R = 0; R < 2; ++R)
      ASYNC16(&As[buf][(R * 512 + tid) * 8],
              A + (size_t)(bm0 + sArow[R]) * lda + k0 + sAcc[R] * 8);
#pragma unroll
    for (int R = 0; R < 2; ++R)
      ASYNC16(&Bs[buf][(R * 512 + tid) * 8],
              Bt + (size_t)(bn0 + sArow[R]) * ldb + k0 + sAcc[R] * 8);
  };

  const int NT = K >> 6;
  stage(0, 0);
  stage(1, 64);
  int cur = 0;
  for (int t = 0; t < NT; ++t) {
    if (t + 1 < NT) asm volatile("s_waitcnt vmcnt(4)" ::: "memory");
    else            asm volatile("s_waitcnt vmcnt(0)" ::: "memory");
    __builtin_amdgcn_sched_barrier(0);
    __builtin_amdgcn_s_barrier();
    __builtin_amdgcn_sched_barrier(0);
    const unsigned short* Ac = As[cur];
    const unsigned short* Bc = Bs[cur];
    // ---- ks = 0 ----
    bf16x8 afr0[4], bfr0[2];
#pragma unroll
    for (int i = 0; i < 4; ++i) {
      int row = wr * 64 + i * 16 + lr;
      afr0[i] = *(const bf16x8*)&Ac[(row * 8 + (kq ^ (row & 7))) * 8];
    }
#pragma unroll
    for (int j2 = 0; j2 < 2; ++j2) {
      int brow = wc * 32 + j2 * 16 + lr;
      bfr0[j2] = *(const bf16x8*)&Bc[(brow * 8 + (kq ^ (brow & 7))) * 8];
    }
    __builtin_amdgcn_s_setprio(1);
#pragma unroll
    for (int j2 = 0; j2 < 2; ++j2)
#pragma unroll
      for (int i = 0; i < 4; ++i)
        acc[i][j2] = __builtin_amdgcn_mfma_f32_16x16x32_bf16(afr0[i], bfr0[j2],
                                                             acc[i][j2], 0, 0, 0);
    __builtin_amdgcn_s_setprio(0);
    // ---- ks = 1 ----
    bf16x8 afr1[4], bfr1[2];
#pragma unroll
    for (int i = 0; i < 4; ++i) {
      int row = wr * 64 + i * 16 + lr;
      afr1[i] = *(const bf16x8*)&Ac[(row * 8 + ((4 + kq) ^ (row & 7))) * 8];
    }
#pragma unroll
    for (int j2 = 0; j2 < 2; ++j2) {
      int brow = wc * 32 + j2 * 16 + lr;
      bfr1[j2] = *(const bf16x8*)&Bc[(brow * 8 + ((4 + kq) ^ (brow & 7))) * 8];
    }
    asm volatile("s_waitcnt lgkmcnt(0)" ::: "memory");
    __builtin_amdgcn_sched_barrier(0);
    __builtin_amdgcn_s_barrier();   // all waves' reads of buf[cur] done
    __builtin_amdgcn_sched_barrier(0);
    if (t + 2 < NT) stage(cur, (t + 2) << 6);
    __builtin_amdgcn_s_setprio(1);
#pragma unroll
    for (int j2 = 0; j2 < 2; ++j2)
#pragma unroll
      for (int i = 0; i < 4; ++i)
        acc[i][j2] = __builtin_amdgcn_mfma_f32_16x16x32_bf16(afr1[i], bfr1[j2],
                                                             acc[i][j2], 0, 0, 0);
    __builtin_amdgcn_s_setprio(0);
    cur ^= 1;
  }

#pragma unroll
  for (int i = 0; i < 4; ++i)
#pragma unroll
    for (int j = 0; j < 2; ++j) {
      int rowb = bm0 + wr * 64 + i * 16 + kq * 4;
      int col = bn0 + wc * 32 + j * 16 + lr;
#pragma unroll
      for (int r = 0; r < 4; ++r) {
        if constexpr (OUT_BF16)
          ((unsigned short*)C_)[(size_t)(rowb + r) * ldc + col] = f2bf(acc[i][j][r]);
        else
          ((float*)C_)[(size_t)(rowb + r) * ldc + col] = acc[i][j][r];
      }
    }
}

// ---- GeGLU dual GEMM: R11 depth-2 schedule + XCD-chunked 1D grid -----------
// grid = 1024 = 16 M-blocks x 64 N-blocks; XCD tile = 8M x 16N (resident 8x8)
__global__ __launch_bounds__(512, 2) void gemm_geglu256(
    const unsigned short* __restrict__ A, const unsigned short* __restrict__ B1,
    const unsigned short* __restrict__ B2, unsigned short* __restrict__ H_,
    int K, int lda, int ldb, int ldc) {
  __shared__ unsigned short As[2][256 * 64];   // 64 KB
  __shared__ unsigned short B1s[2][128 * 64];  // 32 KB
  __shared__ unsigned short B2s[2][128 * 64];  // 32 KB
  const int tid = threadIdx.x;
  const int bid = blockIdx.x;
  const int xcd = bid & 7, ii = bid >> 3;        // ii 0..127
  const int my = (xcd >> 2) * 8 + (ii & 7);      // M-block 0..15
  const int nx = (xcd & 3) * 16 + (ii >> 3);     // N-block 0..63
  const int bm0 = my * 256, bn0 = nx * 128;
  const int lane = tid & 63, wid = tid >> 6;
  const int wr = wid >> 2, wc = wid & 3;
  const int lr = lane & 15, kq = lane >> 4;

  f32x4 accu[8][2] = {};
  f32x4 accg[8][2] = {};

  int sArow[4], sAcc[4], sBrow[2], sBcc[2];
#pragma unroll
  for (int R = 0; R < 4; ++R) {
    int c = R * 512 + tid;
    sArow[R] = c >> 3;
    sAcc[R]  = (c & 7) ^ (sArow[R] & 7);
  }
#pragma unroll
  for (int R = 0; R < 2; ++R) {
    int c = R * 512 + tid;
    sBrow[R] = c >> 3;
    sBcc[R]  = (c & 7) ^ (sBrow[R] & 7);
  }

  auto stage = [&](int buf, int k0) {  // 8 loads/thread
#pragma unroll
    for (int R = 0; R < 4; ++R)
      ASYNC16(&As[buf][(R * 512 + tid) * 8],
              A + (size_t)(bm0 + sArow[R]) * lda + k0 + sAcc[R] * 8);
#pragma unroll
    for (int R = 0; R < 2; ++R)
      ASYNC16(&B1s[buf][(R * 512 + tid) * 8],
              B1 + (size_t)(bn0 + sBrow[R]) * ldb + k0 + sBcc[R] * 8);
#pragma unroll
    for (int R = 0; R < 2; ++R)
      ASYNC16(&B2s[buf][(R * 512 + tid) * 8],
              B2 + (size_t)(bn0 + sBrow[R]) * ldb + k0 + sBcc[R] * 8);
  };

  const int NT = K >> 6;
  stage(0, 0);
  stage(1, 64);
  int cur = 0;
  for (int t = 0; t < NT; ++t) {
    if (t + 1 < NT) asm volatile("s_waitcnt vmcnt(8)" ::: "memory");
    else            asm volatile("s_waitcnt vmcnt(0)" ::: "memory");
    __builtin_amdgcn_sched_barrier(0);
    __builtin_amdgcn_s_barrier();
    __builtin_amdgcn_sched_barrier(0);
    const unsigned short* Ac = As[cur];
    const unsigned short* B1c = B1s[cur];
    const unsigned short* B2c = B2s[cur];
    // ---- ks = 0 ----
    bf16x8 afr0[8], b10[2], b20[2];
#pragma unroll
    for (int i = 0; i < 8; ++i) {
      int row = wr * 128 + i * 16 + lr;
      afr0[i] = *(const bf16x8*)&Ac[(row * 8 + (kq ^ (row & 7))) * 8];
    }
#pragma unroll
    for (int j2 = 0; j2 < 2; ++j2) {
      int brow = wc * 32 + j2 * 16 + lr;
      b10[j2] = *(const bf16x8*)&B1c[(brow * 8 + (kq ^ (brow & 7))) * 8];
      b20[j2] = *(const bf16x8*)&B2c[(brow * 8 + (kq ^ (brow & 7))) * 8];
    }
    __builtin_amdgcn_s_setprio(1);
#pragma unroll
    for (int j2 = 0; j2 < 2; ++j2)
#pragma unroll
      for (int i = 0; i < 8; ++i) {
        accu[i][j2] = __builtin_amdgcn_mfma_f32_16x16x32_bf16(afr0[i], b10[j2],
                                                              accu[i][j2], 0, 0, 0);
        accg[i][j2] = __builtin_amdgcn_mfma_f32_16x16x32_bf16(afr0[i], b20[j2],
                                                              accg[i][j2], 0, 0, 0);
      }
    __builtin_amdgcn_s_setprio(0);
    // ---- ks = 1 ----
    bf16x8 afr1[8], b11[2], b21[2];
#pragma unroll
    for (int i = 0; i < 8; ++i) {
      int row = wr * 128 + i * 16 + lr;
      afr1[i] = *(const bf16x8*)&Ac[(row * 8 + ((4 + kq) ^ (row & 7))) * 8];
    }
#pragma unroll
    for (int j2 = 0; j2 < 2; ++j2) {
      int brow = wc * 32 + j2 * 16 + lr;
      b11[j2] = *(const bf16x8*)&B1c[(brow * 8 + ((4 + kq) ^ (brow & 7))) * 8];
      b21[j2] = *(const bf16x8*)&B2c[(brow * 8 + ((4 + kq) ^ (brow & 7))) * 8];
    }
    asm volatile("s_waitcnt lgkmcnt(0)" ::: "memory");
    __builtin_amdgcn_sched_barrier(0);
    __builtin_amdgcn_s_barrier();
    __builtin_amdgcn_sched_barrier(0);
    if (t + 2 < NT) stage(cur, (t + 2) << 6);
    __builtin_amdgcn_s_setprio(1);
#pragma unroll
    for (int j2 = 0; j2 < 2; ++j2)
#pragma unroll
      for (int i = 0; i < 8; ++i) {
        accu[i][j2] = __builtin_amdgcn_mfma_f32_16x16x32_bf16(afr1[i], b11[j2],
                                                              accu[i][j2], 0, 0, 0);
        accg[i][j2] = __builtin_amdgcn_mfma_f32_16x16x32_bf16(afr1[i], b21[j2],
                                                              accg[i][j2], 0, 0, 0);
      }
    __builtin_amdgcn_s_setprio(0);
    cur ^= 1;
  }

#pragma unroll
  for (int i = 0; i < 8; ++i)
#pragma unroll
    for (int j = 0; j < 2; ++j) {
      int rowb = bm0 + wr * 128 + i * 16 + kq * 4;
      int col = bn0 + wc * 32 + j * 16 + lr;
#pragma unroll
      for (int r = 0; r < 4; ++r) {
        float u = accu[i][j][r];
        float g = accg[i][j][r];
        float tv = tanhf(0.7978845608028654f * (g + 0.044715f * g * g * g));
        float hv = u * 0.5f * g * (1.0f + tv);
        H_[(size_t)(rowb + r) * ldc + col] = f2bf(hv);
      }
    }
}

// ---------------------------------------------------------------------------
extern "C" void kernel_launch(void* const* d_in, const int* in_sizes, int n_in,
                              void* d_out, int out_size, void* d_ws, size_t ws_size,
                              hipStream_t stream) {
  const float* x   = (const float*)d_in[0];
  const float* wq  = (const float*)d_in[1];
  const float* wk  = (const float*)d_in[2];
  const float* wv  = (const float*)d_in[3];
  const float* wo  = (const float*)d_in[4];
  const float* w1  = (const float*)d_in[5];
  const float* w2  = (const float*)d_in[6];
  const float* n1w = (const float*)d_in[7];
  const float* n2w = (const float*)d_in[8];

  float* out    = (float*)d_out;
  float* x2_out = out;
  float* k_out  = out + 8388608;
  float* v_out  = out + 16777216;
  float* attn   = out + 25165824;  // 134,217,728 f32

  char* ws = (char*)d_ws;
  unsigned short* wqT  = (unsigned short*)(ws + 0);
  unsigned short* wkT  = (unsigned short*)(ws + 8388608);
  unsigned short* wvT  = (unsigned short*)(ws + 10485760);
  unsigned short* woT  = (unsigned short*)(ws + 12582912);
  unsigned short* w1T  = (unsigned short*)(ws + 20971520);
  unsigned short* w2T  = (unsigned short*)(ws + 88080384);
  unsigned short* qh   = (unsigned short*)(ws + 121634816);
  unsigned short* kh   = (unsigned short*)(ws + 138412032);
  unsigned short* vhT  = (unsigned short*)(ws + 142606336);
  unsigned short* ctx  = (unsigned short*)(ws + 146800640);
  float*          ao   = (float*)(ws + 163577856);
  unsigned short* hbuf = (unsigned short*)(ws + 121634816);  // alias qh..ao (dead)
  unsigned short* x1b  = (unsigned short*)(ws + 197132288);
  unsigned short* fc   = (unsigned short*)(ws + 213909504);
  // ws total: 230,686,720 bytes

  // bf16 scratch inside not-yet-written attn region of d_out
  unsigned short* xb = (unsigned short*)attn;   // bf16(x), 8,388,608 elems
  unsigned short* xq = xb + 8388608;            // bf16(rope(x))

  dim3 blk(256);
  dim3 blk512(512);

  // 1) weight convert+transpose: wq|wk|wv|wo|w1 fused (contiguous dests), w2
  kconvAll<<<dim3(672, 64), blk, 0, stream>>>(wq, wk, wv, wo, w1, wqT);
  kconvT<<<dim3(64, 256), blk, 0, stream>>>(w2, w2T, 8192, 2048);

  // 2) k_flat = rope(x), v_flat = x, xq/xb bf16 (fused)
  krope<<<16384, blk, 0, stream>>>(x, k_out, v_out, xq, xb);

  // 3) projections (q: 512 blocks = 2/CU, XCD-tiled; k+v merged)
  gemm128<true><<<dim3(512), blk512, 0, stream>>>(
      xq, wqT, qh, 2048, 2048, 2048, 2048);
  kvproj<<<dim3(4, 32, 2), blk, 0, stream>>>(xq, xb, wkT, wvT, kh, vhT);

  // 4) fused scores + softmax + attn write + PV -> ctx (XCD-swizzled 1D grid)
  kattn<<<dim3(4096), blk512, 0, stream>>>(qh, kh, vhT, attn, ctx);

  // 5) attn_out = ctx @ wo (f32)
  gemm128<false><<<dim3(512), blk512, 0, stream>>>(
      ctx, woT, (void*)ao, 2048, 2048, 2048, 2048);
  // 6) x1b = rmsnorm(x + ao) * n1w
  krms1<<<4096, blk, 0, stream>>>(x, ao, n1w, x1b);
  // 7) h = u * gelu(gate)  (fused dual GEMM, uv never materialized)
  gemm_geglu256<<<dim3(1024), blk512, 0, stream>>>(
      x1b, w1T, w1T + 16777216, hbuf, 2048, 2048, 2048, 8192);
  // 8) fc = h @ w2
  gemm128<true><<<dim3(512), blk512, 0, stream>>>(
      hbuf, w2T, fc, 8192, 8192, 8192, 2048);
  // 9) x2 = rmsnorm(x1 + fc) * n2w
  krms2<<<4096, blk, 0, stream>>>(x1b, fc, n2w, x2_out);
}

// Round 18
// 904.963 us; speedup vs baseline: 1.2936x; 1.0091x over previous
//
#include <hip/hip_runtime.h>
#include <hip/hip_bf16.h>

// ---------------------------------------------------------------------------
// TransformerBlock: B=2 N=2048 E=2048 H=16 G=4 D=128 HID=8192
// out = [ x2 (8.39M f32) | k_flat (8.39M) | v_flat (8.39M) | attn (134.2M) ]
// R18: safe consolidations on R17 (913us):
//  - kvproj -> counted-vmcnt depth-2 (BK=32, vmcnt(4), c^=(row&3) swizzle)
//  - kattn softmax -> two-level online reduce: ONE barrier (was 2); combine
//    factor folded into existing write-pass multiply (identical math)
//  - ao stored bf16 (wo GEMM bf16-out, krms1 reads bf16): -67MB HBM
// ---------------------------------------------------------------------------

using f32x4  = __attribute__((ext_vector_type(4))) float;
using bf16x8 = __attribute__((ext_vector_type(8))) short;
using bf16x4 = __attribute__((ext_vector_type(4))) short;
using u16x4  = __attribute__((ext_vector_type(4))) unsigned short;

#define DEV __device__ __forceinline__

// async global->LDS, 16B per lane; LDS dest must be wave-uniform base + lane*16
#define ASYNC16(lds, g)                                                        \
  __builtin_amdgcn_global_load_lds(                                           \
      (const __attribute__((address_space(1))) void*)(g),                      \
      (__attribute__((address_space(3))) void*)(lds), 16, 0, 0)

DEV unsigned short f2bf(float f) {
  unsigned int u = __float_as_uint(f);
  return (unsigned short)((u + 0x7fffu + ((u >> 16) & 1u)) >> 16);
}
DEV float bf2f(unsigned short h) {
  return __uint_as_float(((unsigned int)h) << 16);
}

DEV float waveRedSum(float v) {
#pragma unroll
  for (int o = 32; o; o >>= 1) v += __shfl_xor(v, o);
  return v;
}

// ---- merged transpose+convert for the five K=2048 weights ------------------
__global__ __launch_bounds__(256) void kconvAll(
    const float* __restrict__ wq, const float* __restrict__ wk,
    const float* __restrict__ wv, const float* __restrict__ wo,
    const float* __restrict__ w1, unsigned short* __restrict__ dst) {
  __shared__ float tile[32][33];
  int bx = blockIdx.x * 32;  // global out-row (= src col) 0..21503
  int by = blockIdx.y * 32;  // K dim 0..2047
  const float* src; int nsrc, c0;
  if (bx < 2048)      { src = wq; nsrc = 2048;  c0 = bx; }
  else if (bx < 2560) { src = wk; nsrc = 512;   c0 = bx - 2048; }
  else if (bx < 3072) { src = wv; nsrc = 512;   c0 = bx - 2560; }
  else if (bx < 5120) { src = wo; nsrc = 2048;  c0 = bx - 3072; }
  else                { src = w1; nsrc = 16384; c0 = bx - 5120; }
  int tx = threadIdx.x & 31;
  int ty = threadIdx.x >> 5;  // 0..7
#pragma unroll
  for (int i = 0; i < 32; i += 8)
    tile[ty + i][tx] = src[(size_t)(by + ty + i) * nsrc + c0 + tx];
  __syncthreads();
#pragma unroll
  for (int i = 0; i < 32; i += 8)
    dst[(size_t)(bx + ty + i) * 2048 + by + tx] = f2bf(tile[tx][ty + i]);
}

// ---- transpose+convert: in f32 [K,N] -> out bf16 [N,K] (w2) ----------------
__global__ __launch_bounds__(256) void kconvT(const float* __restrict__ in,
                                              unsigned short* __restrict__ out,
                                              int K, int N) {
  __shared__ float tile[32][33];
  int bx = blockIdx.x * 32;  // N dim
  int by = blockIdx.y * 32;  // K dim
  int tx = threadIdx.x & 31;
  int ty = threadIdx.x >> 5;  // 0..7
#pragma unroll
  for (int i = 0; i < 32; i += 8)
    tile[ty + i][tx] = in[(size_t)(by + ty + i) * N + bx + tx];
  __syncthreads();
#pragma unroll
  for (int i = 0; i < 32; i += 8)
    out[(size_t)(bx + ty + i) * K + by + tx] = f2bf(tile[tx][ty + i]);
}

// ---- RoPE + v_flat copy + bf16 casts (fused); k/v outs nontemporal ---------
__global__ __launch_bounds__(256) void krope(const float* __restrict__ x,
                                             float* __restrict__ kout,
                                             float* __restrict__ vout,
                                             unsigned short* __restrict__ xq,
                                             unsigned short* __restrict__ xb) {
  int idx = blockIdx.x * 256 + threadIdx.x;  // B*N*H*64 = 4,194,304
  int f  = idx & 63;
  int h  = (idx >> 6) & 15;
  int bn = idx >> 10;          // b*2048+n
  int n  = bn & 2047;
  size_t base = (size_t)bn * 2048 + h * 128;
  float inv = exp2f((float)f * (-13.287712379549449f / 64.0f));
  float ang = (float)n * inv;
  float c = cosf(ang), s = sinf(ang);
  float a = x[base + f], b = x[base + f + 64];
  float k1 = a * c - b * s;
  float k2 = b * c + a * s;
  __builtin_nontemporal_store(k1, kout + base + f);
  __builtin_nontemporal_store(k2, kout + base + f + 64);
  xq[base + f]      = f2bf(k1);
  xq[base + f + 64] = f2bf(k2);
  __builtin_nontemporal_store(a, vout + base + f);
  __builtin_nontemporal_store(b, vout + base + f + 64);
  xb[base + f]      = f2bf(a);
  xb[base + f + 64] = f2bf(b);
}

// ---- x1b = bf16(rmsnorm(x + ao_bf16) * w) ----------------------------------
__global__ __launch_bounds__(256) void krms1(const float* __restrict__ x,
                                             const unsigned short* __restrict__ ao,
                                             const float* __restrict__ w,
                                             unsigned short* __restrict__ x1b) {
  size_t row = blockIdx.x;
  const f32x4* xp = (const f32x4*)(x + row * 2048);
  const u16x4* ap = (const u16x4*)(ao + row * 2048);
  int tid = threadIdx.x;
  f32x4 x0 = xp[tid * 2], x1v = xp[tid * 2 + 1];
  u16x4 a0 = ap[tid * 2], a1 = ap[tid * 2 + 1];
  f32x4 t0, t1;
#pragma unroll
  for (int i = 0; i < 4; ++i) {
    t0[i] = x0[i] + bf2f(a0[i]);
    t1[i] = x1v[i] + bf2f(a1[i]);
  }
  float ss = 0.f;
#pragma unroll
  for (int i = 0; i < 4; ++i) ss += t0[i] * t0[i] + t1[i] * t1[i];
  ss = waveRedSum(ss);
  __shared__ float red[4];
  int wid = tid >> 6, lane = tid & 63;
  if (!lane) red[wid] = ss;
  __syncthreads();
  ss = red[0] + red[1] + red[2] + red[3];
  float rr = rsqrtf(ss * (1.0f / 2048.0f) + 1e-6f);
  const f32x4* wp = (const f32x4*)w;
  f32x4 w0 = wp[tid * 2], w1 = wp[tid * 2 + 1];
  u16x4 o0, o1;
#pragma unroll
  for (int i = 0; i < 4; ++i) {
    o0[i] = f2bf(t0[i] * rr * w0[i]);
    o1[i] = f2bf(t1[i] * rr * w1[i]);
  }
  u16x4* op = (u16x4*)(x1b + row * 2048);
  op[tid * 2] = o0;
  op[tid * 2 + 1] = o1;
}

// ---- x2 = f32(rmsnorm(x1b + fc) * w) -> d_out (nontemporal) ----------------
__global__ __launch_bounds__(256) void krms2(const unsigned short* __restrict__ x1b,
                                             const unsigned short* __restrict__ fc,
                                             const float* __restrict__ w,
                                             float* __restrict__ out) {
  size_t row = blockIdx.x;
  const u16x4* xp = (const u16x4*)(x1b + row * 2048);
  const u16x4* fp = (const u16x4*)(fc + row * 2048);
  int tid = threadIdx.x;
  u16x4 a0 = xp[tid * 2], a1 = xp[tid * 2 + 1];
  u16x4 b0 = fp[tid * 2], b1 = fp[tid * 2 + 1];
  f32x4 t0, t1;
#pragma unroll
  for (int i = 0; i < 4; ++i) {
    t0[i] = bf2f(a0[i]) + bf2f(b0[i]);
    t1[i] = bf2f(a1[i]) + bf2f(b1[i]);
  }
  float ss = 0.f;
#pragma unroll
  for (int i = 0; i < 4; ++i) ss += t0[i] * t0[i] + t1[i] * t1[i];
  ss = waveRedSum(ss);
  __shared__ float red[4];
  int wid = tid >> 6, lane = tid & 63;
  if (!lane) red[wid] = ss;
  __syncthreads();
  ss = red[0] + red[1] + red[2] + red[3];
  float rr = rsqrtf(ss * (1.0f / 2048.0f) + 1e-6f);
  const f32x4* wp = (const f32x4*)w;
  f32x4 w0 = wp[tid * 2], w1 = wp[tid * 2 + 1];
  f32x4* op = (f32x4*)(out + row * 2048);
  f32x4 o0 = t0 * rr * w0;
  f32x4 o1 = t1 * rr * w1;
  __builtin_nontemporal_store(o0, op + tid * 2);
  __builtin_nontemporal_store(o1, op + tid * 2 + 1);
}

// ---- merged k/v projections, counted-vmcnt depth-2 (BK=32) -----------------
// z=0: kh = xq@wkT^T (ld 512); z=1: vhT = (xb@wvT^T)^T (ld 4096)
__global__ __launch_bounds__(256, 2) void kvproj(
    const unsigned short* __restrict__ xq, const unsigned short* __restrict__ xb,
    const unsigned short* __restrict__ wkT, const unsigned short* __restrict__ wvT,
    unsigned short* __restrict__ kh, unsigned short* __restrict__ vhT) {
  const bool isV = blockIdx.z != 0;
  const unsigned short* A  = isV ? xb : xq;
  const unsigned short* Bt = isV ? wvT : wkT;
  __shared__ unsigned short As[2][128 * 32];  // 8 KB x2
  __shared__ unsigned short Bs[2][128 * 32];
  const int tid = threadIdx.x;
  const int bm0 = blockIdx.y * 128, bn0 = blockIdx.x * 128;

  f32x4 acc[4][4] = {};

  const int lane = tid & 63, wid = tid >> 6;
  const int wr = wid >> 1, wc = wid & 1;
  const int lr = lane & 15, kq = lane >> 4;

  int srow[2], scc[2];
#pragma unroll
  for (int R = 0; R < 2; ++R) {
    int slot = R * 256 + tid;                 // 0..511
    srow[R] = slot >> 2;                      // 0..127
    scc[R]  = (slot & 3) ^ (srow[R] & 3);     // pre-swizzled source chunk
  }
  auto stage = [&](int buf, int k0) {  // 4 loads/thread
#pragma unroll
    for (int R = 0; R < 2; ++R)
      ASYNC16(&As[buf][(R * 256 + tid) * 8],
              A + (size_t)(bm0 + srow[R]) * 2048 + k0 + scc[R] * 8);
#pragma unroll
    for (int R = 0; R < 2; ++R)
      ASYNC16(&Bs[buf][(R * 256 + tid) * 8],
              Bt + (size_t)(bn0 + srow[R]) * 2048 + k0 + scc[R] * 8);
  };

  const int NT = 64;  // 2048 / 32
  stage(0, 0);
  stage(1, 32);
  int cur = 0;
  for (int t = 0; t < NT; ++t) {
    if (t + 1 < NT) asm volatile("s_waitcnt vmcnt(4)" ::: "memory");
    else            asm volatile("s_waitcnt vmcnt(0)" ::: "memory");
    __builtin_amdgcn_sched_barrier(0);
    __builtin_amdgcn_s_barrier();
    __builtin_amdgcn_sched_barrier(0);
    const unsigned short* Ac = As[cur];
    const unsigned short* Bc = Bs[cur];
    bf16x8 afr[4], bfr[4];
#pragma unroll
    for (int i = 0; i < 4; ++i) {
      int row = wr * 64 + i * 16 + lr;
      afr[i] = *(const bf16x8*)&Ac[row * 32 + ((kq ^ (row & 3)) * 8)];
    }
#pragma unroll
    for (int j = 0; j < 4; ++j) {
      int brow = wc * 64 + j * 16 + lr;
      bfr[j] = *(const bf16x8*)&Bc[brow * 32 + ((kq ^ (brow & 3)) * 8)];
    }
    asm volatile("s_waitcnt lgkmcnt(0)" ::: "memory");
    __builtin_amdgcn_sched_barrier(0);
    __builtin_amdgcn_s_barrier();   // all waves' reads of buf[cur] done
    __builtin_amdgcn_sched_barrier(0);
    if (t + 2 < NT) stage(cur, (t + 2) * 32);
    __builtin_amdgcn_s_setprio(1);
#pragma unroll
    for (int i = 0; i < 4; ++i)
#pragma unroll
      for (int j = 0; j < 4; ++j)
        acc[i][j] = __builtin_amdgcn_mfma_f32_16x16x32_bf16(afr[i], bfr[j],
                                                            acc[i][j], 0, 0, 0);
    __builtin_amdgcn_s_setprio(0);
    cur ^= 1;
  }

#pragma unroll
  for (int i = 0; i < 4; ++i)
#pragma unroll
    for (int j = 0; j < 4; ++j) {
      int rowb = bm0 + wr * 64 + i * 16 + kq * 4;
      int col = bn0 + wc * 64 + j * 16 + lr;
#pragma unroll
      for (int r = 0; r < 4; ++r) {
        unsigned short v = f2bf(acc[i][j][r]);
        if (isV) vhT[(size_t)col * 4096 + (rowb + r)] = v;
        else     kh[(size_t)(rowb + r) * 512 + col] = v;
      }
    }
}

// ===========================================================================
// Fused attention v9: v8 + single-barrier two-level softmax.
// Per-wave (mx_w, sm_w) published together; combine s = sum sm_w*exp(mx_w-m);
// scale exp(mx_w-m)/s folded into the existing write-pass multiply.
// 2 barriers total (softmax + P-publish). Counted-vmcnt pipelines, NT attn
// stores, T5 setprio, XCD swizzle g8 = bid&7. 80KB -> 2/CU.
// ===========================================================================
__global__ __launch_bounds__(512, 4) void kattn(
    const unsigned short* __restrict__ qh,   // [b][n][h*128+d] ld 2048
    const unsigned short* __restrict__ kh,   // [b][n][g*128+d] ld 512
    const unsigned short* __restrict__ vT,   // [g*128+d][b*2048+key] ld 4096
    float* __restrict__ attn,                // [b][h][q][key]
    unsigned short* __restrict__ ctx) {      // [b][n][h*128+d] ld 2048
  __shared__ __align__(16) char U[65536];
  __shared__ __align__(16) char Vb[16384];
  float* redm = (float*)Vb;         // [8][16]
  float* reds = redm + 128;         // [8][16]

  const int tid = threadIdx.x;
  const int lane = tid & 63, w = tid >> 6;   // w 0..7
  const int lr = lane & 15, kq = lane >> 4;  // q = lr, quarter = kq
  const int bid = blockIdx.x;
  const int g8 = bid & 7;          // (b,g) slice, 0..7
  const int j  = bid >> 3;         // 0..511
  const int bz = g8 >> 2;          // batch
  const int gz = g8 & 3;           // kv group
  const int hz = gz * 4 + (j & 3); // head (hz>>2 == gz)
  const int q0 = (j >> 2) << 4;    // q-tile * 16
  const int z  = bz * 16 + hz;

  const unsigned short* Aq =
      qh + ((size_t)(bz * 2048 + q0 + lr) * 2048 + hz * 128);
  bf16x8 qfr[4];
#pragma unroll
  for (int kk = 0; kk < 4; ++kk)
    qfr[kk] = *(const bf16x8*)(Aq + kk * 32 + kq * 8);

  // --- scores: wave-private K staging, counted-vmcnt pipeline --------------
  const unsigned short* Kb =
      kh + ((size_t)(bz * 2048) * 512 + gz * 128);
  int krow[4], kcs[4];
#pragma unroll
  for (int R = 0; R < 4; ++R) {
    int idx = R * 64 + lane;
    krow[R] = idx >> 4;
    kcs[R] = (idx & 15) ^ (krow[R] & 7);  // pre-swizzled source chunk
  }
  auto stageK = [&](int buf, int t) {
#pragma unroll
    for (int R = 0; R < 4; ++R)
      ASYNC16(U + buf * 32768 + w * 4096 + (R * 64 + lane) * 16,
              Kb + (size_t)(t * 128 + w * 16 + krow[R]) * 512 + kcs[R] * 8);
  };

  f32x4 acc[16];
#pragma unroll
  for (int t = 0; t < 16; ++t) acc[t] = f32x4{0.f, 0.f, 0.f, 0.f};

  stageK(0, 0);
  stageK(1, 1);
#pragma unroll
  for (int t = 0; t < 16; ++t) {
    if (t < 15) asm volatile("s_waitcnt vmcnt(4)" ::: "memory");
    else        asm volatile("s_waitcnt vmcnt(0)" ::: "memory");
    __builtin_amdgcn_sched_barrier(0);
    const char* Kw = U + (t & 1) * 32768 + w * 4096;
    bf16x8 kfr[4];
#pragma unroll
    for (int kk = 0; kk < 4; ++kk) {
      int cch = (kk * 4 + kq) ^ (lr & 7);
      kfr[kk] = *(const bf16x8*)(Kw + lr * 256 + cch * 16);
    }
    asm volatile("s_waitcnt lgkmcnt(0)" ::: "memory");
    __builtin_amdgcn_sched_barrier(0);
    if (t + 2 < 16) stageK(t & 1, t + 2);  // reuse just-read buffer
    __builtin_amdgcn_s_setprio(1);
#pragma unroll
    for (int kk = 0; kk < 4; ++kk)
      acc[t] = __builtin_amdgcn_mfma_f32_16x16x32_bf16(kfr[kk], qfr[kk],
                                                       acc[t], 0, 0, 0);
    __builtin_amdgcn_s_setprio(0);
  }

  // --- softmax: two-level online reduce, ONE barrier -----------------------
  const float scale = 0.08838834764831845f;
  float mx = -3.4e38f;
#pragma unroll
  for (int t = 0; t < 16; ++t) {
    acc[t] *= scale;
#pragma unroll
    for (int r = 0; r < 4; ++r) mx = fmaxf(mx, acc[t][r]);
  }
  mx = fmaxf(mx, __shfl_xor(mx, 16));
  mx = fmaxf(mx, __shfl_xor(mx, 32));   // mx = wave-local row max
  float sm = 0.f;
#pragma unroll
  for (int t = 0; t < 16; ++t) {
#pragma unroll
    for (int r = 0; r < 4; ++r) {
      float e = __expf(acc[t][r] - mx);
      acc[t][r] = e;
      sm += e;
    }
  }
  sm += __shfl_xor(sm, 16);
  sm += __shfl_xor(sm, 32);            // sm = wave-local sum of exp(x-mx)
  if (kq == 0) { redm[w * 16 + lr] = mx; reds[w * 16 + lr] = sm; }
  __syncthreads();  // single softmax barrier
  float m = redm[lr];
#pragma unroll
  for (int ww = 1; ww < 8; ++ww) m = fmaxf(m, redm[ww * 16 + lr]);
  float s = 0.f;
#pragma unroll
  for (int ww = 0; ww < 8; ++ww)
    s += reds[ww * 16 + lr] * __expf(redm[ww * 16 + lr] - m);
  float invw = __expf(mx - m) / s;     // per-wave rescale folded into write

  // --- write attn f32 (NT) + P bf16 into U (swizzled chunks) ---------------
  float* arow = attn + (((size_t)z * 2048 + q0 + lr) * 2048);
#pragma unroll
  for (int t = 0; t < 16; ++t) {
    int key = t * 128 + w * 16 + kq * 4;
    f32x4 p = acc[t] * invw;
    __builtin_nontemporal_store(p, (f32x4*)(arow + key));
    bf16x4 pb;
#pragma unroll
    for (int r = 0; r < 4; ++r) pb[r] = (short)f2bf(p[r]);
    int c8 = key >> 3;  // 16B chunk index in q-row
    *(bf16x4*)(U + lr * 4096 + ((c8 ^ (lr & 7)) << 4) + ((key & 7) << 1)) = pb;
  }
  __syncthreads();  // barrier: P ready, red reads done, K staging drained

  // --- PV: wave-private V staging, counted-vmcnt pipeline ------------------
  const unsigned short* Bv = vT + (size_t)gz * 524288 + bz * 2048;
  const int d0 = w * 16;
  const int vd = lane >> 2;                 // 0..15 local d-row
  const int vcs = (lane & 3) ^ (vd & 3);    // pre-swizzled source chunk
  auto stageV = [&](int buf, int t) {
    ASYNC16(Vb + buf * 8192 + w * 1024 + lane * 16,
            Bv + (size_t)(d0 + vd) * 4096 + t * 32 + vcs * 8);
  };

  f32x4 cfr = {};
  stageV(0, 0);
  stageV(1, 1);
#pragma unroll
  for (int t = 0; t < 64; ++t) {
    if (t < 63) asm volatile("s_waitcnt vmcnt(1)" ::: "memory");
    else        asm volatile("s_waitcnt vmcnt(0)" ::: "memory");
    __builtin_amdgcn_sched_barrier(0);
    int c8 = t * 4 + kq;
    bf16x8 pfr = *(const bf16x8*)(U + lr * 4096 + ((c8 ^ (lr & 7)) << 4));
    const char* Vw = Vb + (t & 1) * 8192 + w * 1024;
    bf16x8 vfr = *(const bf16x8*)(Vw + lr * 64 + ((kq ^ (lr & 3)) << 4));
    asm volatile("s_waitcnt lgkmcnt(0)" ::: "memory");
    __builtin_amdgcn_sched_barrier(0);
    if (t + 2 < 64) stageV(t & 1, t + 2);  // reuse just-read buffer
    __builtin_amdgcn_s_setprio(1);
    cfr = __builtin_amdgcn_mfma_f32_16x16x32_bf16(pfr, vfr, cfr, 0, 0, 0);
    __builtin_amdgcn_s_setprio(0);
  }
#pragma unroll
  for (int r = 0; r < 4; ++r) {
    int q = kq * 4 + r;
    ctx[((size_t)(bz * 2048 + q0 + q) * 2048) + hz * 128 + d0 + lr] =
        f2bf(cfr[r]);
  }
}

// ===========================================================================
// 128x128 8-wave GEMM, BK=64 — depth-2 counted-vmcnt, XCD-chunked 1D grid.
// ===========================================================================
template <bool OUT_BF16>
__global__ __launch_bounds__(512, 2) void gemm128(
    const unsigned short* __restrict__ A, const unsigned short* __restrict__ Bt,
    void* __restrict__ C_, int K, int lda, int ldb, int ldc) {
  __shared__ unsigned short As[2][128 * 64];  // 32 KB
  __shared__ unsigned short Bs[2][128 * 64];  // 32 KB
  const int tid = threadIdx.x;
  const int bid = blockIdx.x;
  const int xcd = bid & 7, ii = bid >> 3;       // ii 0..63
  const int my = (xcd >> 1) * 8 + (ii & 7);     // M-block 0..31
  const int nx = (xcd & 1) * 8 + (ii >> 3);     // N-block 0..15
  const int bm0 = my * 128, bn0 = nx * 128;
  const int lane = tid & 63, wid = tid >> 6;
  const int wr = wid >> 2, wc = wid & 3;        // 2M x 4N
  const int lr = lane & 15, kq = lane >> 4;

  f32x4 acc[4][2] = {};

  int sArow[2], sAcc[2];
#pragma unroll
  for (int R = 0; R < 2; ++R) {
    int c = R * 512 + tid;                    // 0..1023
    sArow[R] = c >> 3;
    sAcc[R]  = (c & 7) ^ (sArow[R] & 7);
  }

  auto stage = [&](int buf, int k0) {  // 4 loads/thread
#pragma unroll
    for (int R = 0; R < 2; ++R)
      ASYNC16(&As[buf][(R * 512 + tid) * 8],
              A + (size_t)(bm0 + sArow[R]) * lda + k0 + sAcc[R] * 8);
#pragma unroll
    for (int R = 0; R < 2; ++R)
      ASYNC16(&Bs[buf][(R * 512 + tid) * 8],
              Bt + (size_t)(bn0 + sArow[R]) * ldb + k0 + sAcc[R] * 8);
  };

  const int NT = K >> 6;
  stage(0, 0);
  stage(1, 64);
  int cur = 0;
  for (int t = 0; t < NT; ++t) {
    if (t + 1 < NT) asm volatile("s_waitcnt vmcnt(4)" ::: "memory");
    else            asm volatile("s_waitcnt vmcnt(0)" ::: "memory");
    __builtin_amdgcn_sched_barrier(0);
    __builtin_amdgcn_s_barrier();
    __builtin_amdgcn_sched_barrier(0);
    const unsigned short* Ac = As[cur];
    const unsigned short* Bc = Bs[cur];
    // ---- ks = 0 ----
    bf16x8 afr0[4], bfr0[2];
#pragma unroll
    for (int i = 0; i < 4; ++i) {
      int row = wr * 64 + i * 16 + lr;
      afr0[i] = *(const bf16x8*)&Ac[(row * 8 + (kq ^ (row & 7))) * 8];
    }
#pragma unroll
    for (int j2 = 0; j2 < 2; ++j2) {
      int brow = wc * 32 + j2 * 16 + lr;
      bfr0[j2] = *(const bf16x8*)&Bc[(brow * 8 + (kq ^ (brow & 7))) * 8];
    }
    __builtin_amdgcn_s_setprio(1);
#pragma unroll
    for (int j2 = 0; j2 < 2; ++j2)
#pragma unroll
      for (int i = 0; i < 4; ++i)
        acc[i][j2] = __builtin_amdgcn_mfma_f32_16x16x32_bf16(afr0[i], bfr0[j2],
                                                             acc[i][j2], 0, 0, 0);
    __builtin_amdgcn_s_setprio(0);
    // ---- ks = 1 ----
    bf16x8 afr1[4], bfr1[2];
#pragma unroll
    for (int i = 0; i < 4; ++i) {
      int row = wr * 64 + i * 16 + lr;
      afr1[i] = *(const bf16x8*)&Ac[(row * 8 + ((4 + kq) ^ (row & 7))) * 8];
    }
#pragma unroll
    for (int j2 = 0; j2 < 2; ++j2) {
      int brow = wc * 32 + j2 * 16 + lr;
      bfr1[j2] = *(const bf16x8*)&Bc[(brow * 8 + ((4 + kq) ^ (brow & 7))) * 8];
    }
    asm volatile("s_waitcnt lgkmcnt(0)" ::: "memory");
    __builtin_amdgcn_sched_barrier(0);
    __builtin_amdgcn_s_barrier();   // all waves' reads of buf[cur] done
    __builtin_amdgcn_sched_barrier(0);
    if (t + 2 < NT) stage(cur, (t + 2) << 6);
    __builtin_amdgcn_s_setprio(1);
#pragma unroll
    for (int j2 = 0; j2 < 2; ++j2)
#pragma unroll
      for (int i = 0; i < 4; ++i)
        acc[i][j2] = __builtin_amdgcn_mfma_f32_16x16x32_bf16(afr1[i], bfr1[j2],
                                                             acc[i][j2], 0, 0, 0);
    __builtin_amdgcn_s_setprio(0);
    cur ^= 1;
  }

#pragma unroll
  for (int i = 0; i < 4; ++i)
#pragma unroll
    for (int j = 0; j < 2; ++j) {
      int rowb = bm0 + wr * 64 + i * 16 + kq * 4;
      int col = bn0 + wc * 32 + j * 16 + lr;
#pragma unroll
      for (int r = 0; r < 4; ++r) {
        if constexpr (OUT_BF16)
          ((unsigned short*)C_)[(size_t)(rowb + r) * ldc + col] = f2bf(acc[i][j][r]);
        else
          ((float*)C_)[(size_t)(rowb + r) * ldc + col] = acc[i][j][r];
      }
    }
}

// ---- GeGLU dual GEMM: depth-2 schedule + XCD-chunked 1D grid ---------------
__global__ __launch_bounds__(512, 2) void gemm_geglu256(
    const unsigned short* __restrict__ A, const unsigned short* __restrict__ B1,
    const unsigned short* __restrict__ B2, unsigned short* __restrict__ H_,
    int K, int lda, int ldb, int ldc) {
  __shared__ unsigned short As[2][256 * 64];   // 64 KB
  __shared__ unsigned short B1s[2][128 * 64];  // 32 KB
  __shared__ unsigned short B2s[2][128 * 64];  // 32 KB
  const int tid = threadIdx.x;
  const int bid = blockIdx.x;
  const int xcd = bid & 7, ii = bid >> 3;        // ii 0..127
  const int my = (xcd >> 2) * 8 + (ii & 7);      // M-block 0..15
  const int nx = (xcd & 3) * 16 + (ii >> 3);     // N-block 0..63
  const int bm0 = my * 256, bn0 = nx * 128;
  const int lane = tid & 63, wid = tid >> 6;
  const int wr = wid >> 2, wc = wid & 3;
  const int lr = lane & 15, kq = lane >> 4;

  f32x4 accu[8][2] = {};
  f32x4 accg[8][2] = {};

  int sArow[4], sAcc[4], sBrow[2], sBcc[2];
#pragma unroll
  for (int R = 0; R < 4; ++R) {
    int c = R * 512 + tid;
    sArow[R] = c >> 3;
    sAcc[R]  = (c & 7) ^ (sArow[R] & 7);
  }
#pragma unroll
  for (int R = 0; R < 2; ++R) {
    int c = R * 512 + tid;
    sBrow[R] = c >> 3;
    sBcc[R]  = (c & 7) ^ (sBrow[R] & 7);
  }

  auto stage = [&](int buf, int k0) {  // 8 loads/thread
#pragma unroll
    for (int R = 0; R < 4; ++R)
      ASYNC16(&As[buf][(R * 512 + tid) * 8],
              A + (size_t)(bm0 + sArow[R]) * lda + k0 + sAcc[R] * 8);
#pragma unroll
    for (int R = 0; R < 2; ++R)
      ASYNC16(&B1s[buf][(R * 512 + tid) * 8],
              B1 + (size_t)(bn0 + sBrow[R]) * ldb + k0 + sBcc[R] * 8);
#pragma unroll
    for (int R = 0; R < 2; ++R)
      ASYNC16(&B2s[buf][(R * 512 + tid) * 8],
              B2 + (size_t)(bn0 + sBrow[R]) * ldb + k0 + sBcc[R] * 8);
  };

  const int NT = K >> 6;
  stage(0, 0);
  stage(1, 64);
  int cur = 0;
  for (int t = 0; t < NT; ++t) {
    if (t + 1 < NT) asm volatile("s_waitcnt vmcnt(8)" ::: "memory");
    else            asm volatile("s_waitcnt vmcnt(0)" ::: "memory");
    __builtin_amdgcn_sched_barrier(0);
    __builtin_amdgcn_s_barrier();
    __builtin_amdgcn_sched_barrier(0);
    const unsigned short* Ac = As[cur];
    const unsigned short* B1c = B1s[cur];
    const unsigned short* B2c = B2s[cur];
    // ---- ks = 0 ----
    bf16x8 afr0[8], b10[2], b20[2];
#pragma unroll
    for (int i = 0; i < 8; ++i) {
      int row = wr * 128 + i * 16 + lr;
      afr0[i] = *(const bf16x8*)&Ac[(row * 8 + (kq ^ (row & 7))) * 8];
    }
#pragma unroll
    for (int j2 = 0; j2 < 2; ++j2) {
      int brow = wc * 32 + j2 * 16 + lr;
      b10[j2] = *(const bf16x8*)&B1c[(brow * 8 + (kq ^ (brow & 7))) * 8];
      b20[j2] = *(const bf16x8*)&B2c[(brow * 8 + (kq ^ (brow & 7))) * 8];
    }
    __builtin_amdgcn_s_setprio(1);
#pragma unroll
    for (int j2 = 0; j2 < 2; ++j2)
#pragma unroll
      for (int i = 0; i < 8; ++i) {
        accu[i][j2] = __builtin_amdgcn_mfma_f32_16x16x32_bf16(afr0[i], b10[j2],
                                                              accu[i][j2], 0, 0, 0);
        accg[i][j2] = __builtin_amdgcn_mfma_f32_16x16x32_bf16(afr0[i], b20[j2],
                                                              accg[i][j2], 0, 0, 0);
      }
    __builtin_amdgcn_s_setprio(0);
    // ---- ks = 1 ----
    bf16x8 afr1[8], b11[2], b21[2];
#pragma unroll
    for (int i = 0; i < 8; ++i) {
      int row = wr * 128 + i * 16 + lr;
      afr1[i] = *(const bf16x8*)&Ac[(row * 8 + ((4 + kq) ^ (row & 7))) * 8];
    }
#pragma unroll
    for (int j2 = 0; j2 < 2; ++j2) {
      int brow = wc * 32 + j2 * 16 + lr;
      b11[j2] = *(const bf16x8*)&B1c[(brow * 8 + ((4 + kq) ^ (brow & 7))) * 8];
      b21[j2] = *(const bf16x8*)&B2c[(brow * 8 + ((4 + kq) ^ (brow & 7))) * 8];
    }
    asm volatile("s_waitcnt lgkmcnt(0)" ::: "memory");
    __builtin_amdgcn_sched_barrier(0);
    __builtin_amdgcn_s_barrier();
    __builtin_amdgcn_sched_barrier(0);
    if (t + 2 < NT) stage(cur, (t + 2) << 6);
    __builtin_amdgcn_s_setprio(1);
#pragma unroll
    for (int j2 = 0; j2 < 2; ++j2)
#pragma unroll
      for (int i = 0; i < 8; ++i) {
        accu[i][j2] = __builtin_amdgcn_mfma_f32_16x16x32_bf16(afr1[i], b11[j2],
                                                              accu[i][j2], 0, 0, 0);
        accg[i][j2] = __builtin_amdgcn_mfma_f32_16x16x32_bf16(afr1[i], b21[j2],
                                                              accg[i][j2], 0, 0, 0);
      }
    __builtin_amdgcn_s_setprio(0);
    cur ^= 1;
  }

#pragma unroll
  for (int i = 0; i < 8; ++i)
#pragma unroll
    for (int j = 0; j < 2; ++j) {
      int rowb = bm0 + wr * 128 + i * 16 + kq * 4;
      int col = bn0 + wc * 32 + j * 16 + lr;
#pragma unroll
      for (int r = 0; r < 4; ++r) {
        float u = accu[i][j][r];
        float g = accg[i][j][r];
        float tv = tanhf(0.7978845608028654f * (g + 0.044715f * g * g * g));
        float hv = u * 0.5f * g * (1.0f + tv);
        H_[(size_t)(rowb + r) * ldc + col] = f2bf(hv);
      }
    }
}

// ---------------------------------------------------------------------------
extern "C" void kernel_launch(void* const* d_in, const int* in_sizes, int n_in,
                              void* d_out, int out_size, void* d_ws, size_t ws_size,
                              hipStream_t stream) {
  const float* x   = (const float*)d_in[0];
  const float* wq  = (const float*)d_in[1];
  const float* wk  = (const float*)d_in[2];
  const float* wv  = (const float*)d_in[3];
  const float* wo  = (const float*)d_in[4];
  const float* w1  = (const float*)d_in[5];
  const float* w2  = (const float*)d_in[6];
  const float* n1w = (const float*)d_in[7];
  const float* n2w = (const float*)d_in[8];

  float* out    = (float*)d_out;
  float* x2_out = out;
  float* k_out  = out + 8388608;
  float* v_out  = out + 16777216;
  float* attn   = out + 25165824;  // 134,217,728 f32

  char* ws = (char*)d_ws;
  unsigned short* wqT  = (unsigned short*)(ws + 0);
  unsigned short* wkT  = (unsigned short*)(ws + 8388608);
  unsigned short* wvT  = (unsigned short*)(ws + 10485760);
  unsigned short* woT  = (unsigned short*)(ws + 12582912);
  unsigned short* w1T  = (unsigned short*)(ws + 20971520);
  unsigned short* w2T  = (unsigned short*)(ws + 88080384);
  unsigned short* qh   = (unsigned short*)(ws + 121634816);
  unsigned short* kh   = (unsigned short*)(ws + 138412032);
  unsigned short* vhT  = (unsigned short*)(ws + 142606336);
  unsigned short* ctx  = (unsigned short*)(ws + 146800640);
  unsigned short* aob  = (unsigned short*)(ws + 163577856);  // ao bf16
  unsigned short* hbuf = (unsigned short*)(ws + 121634816);  // alias qh..ao (dead)
  unsigned short* x1b  = (unsigned short*)(ws + 197132288);
  unsigned short* fc   = (unsigned short*)(ws + 213909504);
  // ws total: 230,686,720 bytes

  // bf16 scratch inside not-yet-written attn region of d_out
  unsigned short* xb = (unsigned short*)attn;   // bf16(x), 8,388,608 elems
  unsigned short* xq = xb + 8388608;            // bf16(rope(x))

  dim3 blk(256);
  dim3 blk512(512);

  // 1) weight convert+transpose: wq|wk|wv|wo|w1 fused (contiguous dests), w2
  kconvAll<<<dim3(672, 64), blk, 0, stream>>>(wq, wk, wv, wo, w1, wqT);
  kconvT<<<dim3(64, 256), blk, 0, stream>>>(w2, w2T, 8192, 2048);

  // 2) k_flat = rope(x), v_flat = x, xq/xb bf16 (fused)
  krope<<<16384, blk, 0, stream>>>(x, k_out, v_out, xq, xb);

  // 3) projections (q: 512 blocks = 2/CU, XCD-tiled; k+v merged, pipelined)
  gemm128<true><<<dim3(512), blk512, 0, stream>>>(
      xq, wqT, qh, 2048, 2048, 2048, 2048);
  kvproj<<<dim3(4, 32, 2), blk, 0, stream>>>(xq, xb, wkT, wvT, kh, vhT);

  // 4) fused scores + softmax + attn write + PV -> ctx (XCD-swizzled 1D grid)
  kattn<<<dim3(4096), blk512, 0, stream>>>(qh, kh, vhT, attn, ctx);

  // 5) attn_out = ctx @ wo (bf16 out)
  gemm128<true><<<dim3(512), blk512, 0, stream>>>(
      ctx, woT, aob, 2048, 2048, 2048, 2048);
  // 6) x1b = rmsnorm(x + ao) * n1w
  krms1<<<4096, blk, 0, stream>>>(x, aob, n1w, x1b);
  // 7) h = u * gelu(gate)  (fused dual GEMM, uv never materialized)
  gemm_geglu256<<<dim3(1024), blk512, 0, stream>>>(
      x1b, w1T, w1T + 16777216, hbuf, 2048, 2048, 2048, 8192);
  // 8) fc = h @ w2
  gemm128<true><<<dim3(512), blk512, 0, stream>>>(
      hbuf, w2T, fc, 8192, 8192, 8192, 2048);
  // 9) x2 = rmsnorm(x1 + fc) * n2w
  krms2<<<4096, blk, 0, stream>>>(x1b, fc, n2w, x2_out);
}

// Round 19
// 903.129 us; speedup vs baseline: 1.2962x; 1.0020x over previous
//
#include <hip/hip_runtime.h>
#include <hip/hip_bf16.h>

// ---------------------------------------------------------------------------
// TransformerBlock: B=2 N=2048 E=2048 H=16 G=4 D=128 HID=8192
// out = [ x2 (8.39M f32) | k_flat (8.39M) | v_flat (8.39M) | attn (134.2M) ]
// R19: launch-graph consolidation on R18 (905us):
//  - kprep: kconvAll + kconvT(w2) + krope in ONE launch (block-range dispatch)
//  - qkvgemm: q/k/v projections in ONE 768-block gemm128-style launch
//    (blocks<512 = XCD-tiled q-proj; 512-639 k-proj; 640-767 v-proj w/
//    transposed C-write). k/v upgrade to the 8-wave BK=64 depth-2 schedule.
//  11 -> 8 launches. kattn v9 / gemm128 / geglu / krms unchanged.
// ---------------------------------------------------------------------------

using f32x4  = __attribute__((ext_vector_type(4))) float;
using bf16x8 = __attribute__((ext_vector_type(8))) short;
using bf16x4 = __attribute__((ext_vector_type(4))) short;
using u16x4  = __attribute__((ext_vector_type(4))) unsigned short;

#define DEV __device__ __forceinline__

// async global->LDS, 16B per lane; LDS dest must be wave-uniform base + lane*16
#define ASYNC16(lds, g)                                                        \
  __builtin_amdgcn_global_load_lds(                                           \
      (const __attribute__((address_space(1))) void*)(g),                      \
      (__attribute__((address_space(3))) void*)(lds), 16, 0, 0)

DEV unsigned short f2bf(float f) {
  unsigned int u = __float_as_uint(f);
  return (unsigned short)((u + 0x7fffu + ((u >> 16) & 1u)) >> 16);
}
DEV float bf2f(unsigned short h) {
  return __uint_as_float(((unsigned int)h) << 16);
}

DEV float waveRedSum(float v) {
#pragma unroll
  for (int o = 32; o; o >>= 1) v += __shfl_xor(v, o);
  return v;
}

// ===========================================================================
// kprep: one launch for all prep work (block-range dispatch, 256 thr).
//  blocks [0, 43008)      : conv+transpose of wq|wk|wv|wo|w1 -> dst (bf16)
//  blocks [43008, 59392)  : conv+transpose of w2 [8192,2048] -> w2T
//  blocks [59392, 75776)  : RoPE + v_flat copy + bf16 casts
// ===========================================================================
__global__ __launch_bounds__(256) void kprep(
    const float* __restrict__ wq, const float* __restrict__ wk,
    const float* __restrict__ wv, const float* __restrict__ wo,
    const float* __restrict__ w1, const float* __restrict__ w2,
    unsigned short* __restrict__ dst, unsigned short* __restrict__ w2T,
    const float* __restrict__ x, float* __restrict__ kout,
    float* __restrict__ vout, unsigned short* __restrict__ xq,
    unsigned short* __restrict__ xb) {
  __shared__ float tile[32][33];
  const int bidg = blockIdx.x;
  if (bidg < 43008) {
    // ---- five K=2048 weights -> contiguous [21504][2048] bf16 ----
    int bx = (bidg % 672) * 32;  // out-row (= src col) 0..21503
    int by = (bidg / 672) * 32;  // K dim 0..2047
    const float* src; int nsrc, c0;
    if (bx < 2048)      { src = wq; nsrc = 2048;  c0 = bx; }
    else if (bx < 2560) { src = wk; nsrc = 512;   c0 = bx - 2048; }
    else if (bx < 3072) { src = wv; nsrc = 512;   c0 = bx - 2560; }
    else if (bx < 5120) { src = wo; nsrc = 2048;  c0 = bx - 3072; }
    else                { src = w1; nsrc = 16384; c0 = bx - 5120; }
    int tx = threadIdx.x & 31;
    int ty = threadIdx.x >> 5;  // 0..7
#pragma unroll
    for (int i = 0; i < 32; i += 8)
      tile[ty + i][tx] = src[(size_t)(by + ty + i) * nsrc + c0 + tx];
    __syncthreads();
#pragma unroll
    for (int i = 0; i < 32; i += 8)
      dst[(size_t)(bx + ty + i) * 2048 + by + tx] = f2bf(tile[tx][ty + i]);
  } else if (bidg < 59392) {
    // ---- w2 [8192 K][2048 N] f32 -> w2T [2048][8192] bf16 ----
    int l = bidg - 43008;
    int bx = (l & 63) * 32;   // N dim 0..2047
    int by = (l >> 6) * 32;   // K dim 0..8191
    int tx = threadIdx.x & 31;
    int ty = threadIdx.x >> 5;
#pragma unroll
    for (int i = 0; i < 32; i += 8)
      tile[ty + i][tx] = w2[(size_t)(by + ty + i) * 2048 + bx + tx];
    __syncthreads();
#pragma unroll
    for (int i = 0; i < 32; i += 8)
      w2T[(size_t)(bx + ty + i) * 8192 + by + tx] = f2bf(tile[tx][ty + i]);
  } else {
    // ---- RoPE + v copy + bf16 casts ----
    int idx = (bidg - 59392) * 256 + threadIdx.x;  // 0..4,194,303
    int f  = idx & 63;
    int h  = (idx >> 6) & 15;
    int bn = idx >> 10;
    int n  = bn & 2047;
    size_t base = (size_t)bn * 2048 + h * 128;
    float inv = exp2f((float)f * (-13.287712379549449f / 64.0f));
    float ang = (float)n * inv;
    float c = cosf(ang), s = sinf(ang);
    float a = x[base + f], b = x[base + f + 64];
    float k1 = a * c - b * s;
    float k2 = b * c + a * s;
    __builtin_nontemporal_store(k1, kout + base + f);
    __builtin_nontemporal_store(k2, kout + base + f + 64);
    xq[base + f]      = f2bf(k1);
    xq[base + f + 64] = f2bf(k2);
    __builtin_nontemporal_store(a, vout + base + f);
    __builtin_nontemporal_store(b, vout + base + f + 64);
    xb[base + f]      = f2bf(a);
    xb[base + f + 64] = f2bf(b);
  }
}

// ---- x1b = bf16(rmsnorm(x + ao_bf16) * w) ----------------------------------
__global__ __launch_bounds__(256) void krms1(const float* __restrict__ x,
                                             const unsigned short* __restrict__ ao,
                                             const float* __restrict__ w,
                                             unsigned short* __restrict__ x1b) {
  size_t row = blockIdx.x;
  const f32x4* xp = (const f32x4*)(x + row * 2048);
  const u16x4* ap = (const u16x4*)(ao + row * 2048);
  int tid = threadIdx.x;
  f32x4 x0 = xp[tid * 2], x1v = xp[tid * 2 + 1];
  u16x4 a0 = ap[tid * 2], a1 = ap[tid * 2 + 1];
  f32x4 t0, t1;
#pragma unroll
  for (int i = 0; i < 4; ++i) {
    t0[i] = x0[i] + bf2f(a0[i]);
    t1[i] = x1v[i] + bf2f(a1[i]);
  }
  float ss = 0.f;
#pragma unroll
  for (int i = 0; i < 4; ++i) ss += t0[i] * t0[i] + t1[i] * t1[i];
  ss = waveRedSum(ss);
  __shared__ float red[4];
  int wid = tid >> 6, lane = tid & 63;
  if (!lane) red[wid] = ss;
  __syncthreads();
  ss = red[0] + red[1] + red[2] + red[3];
  float rr = rsqrtf(ss * (1.0f / 2048.0f) + 1e-6f);
  const f32x4* wp = (const f32x4*)w;
  f32x4 w0 = wp[tid * 2], w1 = wp[tid * 2 + 1];
  u16x4 o0, o1;
#pragma unroll
  for (int i = 0; i < 4; ++i) {
    o0[i] = f2bf(t0[i] * rr * w0[i]);
    o1[i] = f2bf(t1[i] * rr * w1[i]);
  }
  u16x4* op = (u16x4*)(x1b + row * 2048);
  op[tid * 2] = o0;
  op[tid * 2 + 1] = o1;
}

// ---- x2 = f32(rmsnorm(x1b + fc) * w) -> d_out (nontemporal) ----------------
__global__ __launch_bounds__(256) void krms2(const unsigned short* __restrict__ x1b,
                                             const unsigned short* __restrict__ fc,
                                             const float* __restrict__ w,
                                             float* __restrict__ out) {
  size_t row = blockIdx.x;
  const u16x4* xp = (const u16x4*)(x1b + row * 2048);
  const u16x4* fp = (const u16x4*)(fc + row * 2048);
  int tid = threadIdx.x;
  u16x4 a0 = xp[tid * 2], a1 = xp[tid * 2 + 1];
  u16x4 b0 = fp[tid * 2], b1 = fp[tid * 2 + 1];
  f32x4 t0, t1;
#pragma unroll
  for (int i = 0; i < 4; ++i) {
    t0[i] = bf2f(a0[i]) + bf2f(b0[i]);
    t1[i] = bf2f(a1[i]) + bf2f(b1[i]);
  }
  float ss = 0.f;
#pragma unroll
  for (int i = 0; i < 4; ++i) ss += t0[i] * t0[i] + t1[i] * t1[i];
  ss = waveRedSum(ss);
  __shared__ float red[4];
  int wid = tid >> 6, lane = tid & 63;
  if (!lane) red[wid] = ss;
  __syncthreads();
  ss = red[0] + red[1] + red[2] + red[3];
  float rr = rsqrtf(ss * (1.0f / 2048.0f) + 1e-6f);
  const f32x4* wp = (const f32x4*)w;
  f32x4 w0 = wp[tid * 2], w1 = wp[tid * 2 + 1];
  f32x4* op = (f32x4*)(out + row * 2048);
  f32x4 o0 = t0 * rr * w0;
  f32x4 o1 = t1 * rr * w1;
  __builtin_nontemporal_store(o0, op + tid * 2);
  __builtin_nontemporal_store(o1, op + tid * 2 + 1);
}

// ===========================================================================
// qkvgemm: q/k/v projections in ONE launch (768 blocks, 512 thr).
//  bid < 512 : q-proj, XCD-chunked (M32 x N16), A=xq B=wqT C=qh ld 2048
//  512..639  : k-proj, (M32 x N4),  A=xq B=wkT C=kh ld 512
//  640..767  : v-proj, (M32 x N4),  A=xb B=wvT C=vhT TRANSPOSED (col*4096+row)
// Inner loop = gemm128 depth-2 counted-vmcnt schedule (K=2048, lda=ldb=2048).
// ===========================================================================
__global__ __launch_bounds__(512, 2) void qkvgemm(
    const unsigned short* __restrict__ xq, const unsigned short* __restrict__ xb,
    const unsigned short* __restrict__ wqT, const unsigned short* __restrict__ wkT,
    const unsigned short* __restrict__ wvT, unsigned short* __restrict__ qh,
    unsigned short* __restrict__ kh, unsigned short* __restrict__ vhT) {
  __shared__ unsigned short As[2][128 * 64];  // 32 KB
  __shared__ unsigned short Bs[2][128 * 64];  // 32 KB
  const int tid = threadIdx.x;
  const int bid = blockIdx.x;
  const unsigned short *A, *Bt;
  int bm0, bn0, mode;
  if (bid < 512) {
    const int xcd = bid & 7, ii = bid >> 3;
    bm0 = ((xcd >> 1) * 8 + (ii & 7)) * 128;
    bn0 = ((xcd & 1) * 8 + (ii >> 3)) * 128;
    A = xq; Bt = wqT; mode = 0;
  } else if (bid < 640) {
    int l = bid - 512;                  // 0..127
    bm0 = (l >> 2) * 128;               // M-block 0..31
    bn0 = (l & 3) * 128;                // N-block 0..3
    A = xq; Bt = wkT; mode = 1;
  } else {
    int l = bid - 640;
    bm0 = (l >> 2) * 128;
    bn0 = (l & 3) * 128;
    A = xb; Bt = wvT; mode = 2;
  }
  const int lane = tid & 63, wid = tid >> 6;
  const int wr = wid >> 2, wc = wid & 3;        // 2M x 4N
  const int lr = lane & 15, kq = lane >> 4;

  f32x4 acc[4][2] = {};

  int sArow[2], sAcc[2];
#pragma unroll
  for (int R = 0; R < 2; ++R) {
    int c = R * 512 + tid;                    // 0..1023
    sArow[R] = c >> 3;
    sAcc[R]  = (c & 7) ^ (sArow[R] & 7);
  }

  auto stage = [&](int buf, int k0) {  // 4 loads/thread
#pragma unroll
    for (int R = 0; R < 2; ++R)
      ASYNC16(&As[buf][(R * 512 + tid) * 8],
              A + (size_t)(bm0 + sArow[R]) * 2048 + k0 + sAcc[R] * 8);
#pragma unroll
    for (int R = 0; R < 2; ++R)
      ASYNC16(&Bs[buf][(R * 512 + tid) * 8],
              Bt + (size_t)(bn0 + sArow[R]) * 2048 + k0 + sAcc[R] * 8);
  };

  const int NT = 32;  // 2048 / 64
  stage(0, 0);
  stage(1, 64);
  int cur = 0;
  for (int t = 0; t < NT; ++t) {
    if (t + 1 < NT) asm volatile("s_waitcnt vmcnt(4)" ::: "memory");
    else            asm volatile("s_waitcnt vmcnt(0)" ::: "memory");
    __builtin_amdgcn_sched_barrier(0);
    __builtin_amdgcn_s_barrier();
    __builtin_amdgcn_sched_barrier(0);
    const unsigned short* Ac = As[cur];
    const unsigned short* Bc = Bs[cur];
    // ---- ks = 0 ----
    bf16x8 afr0[4], bfr0[2];
#pragma unroll
    for (int i = 0; i < 4; ++i) {
      int row = wr * 64 + i * 16 + lr;
      afr0[i] = *(const bf16x8*)&Ac[(row * 8 + (kq ^ (row & 7))) * 8];
    }
#pragma unroll
    for (int j2 = 0; j2 < 2; ++j2) {
      int brow = wc * 32 + j2 * 16 + lr;
      bfr0[j2] = *(const bf16x8*)&Bc[(brow * 8 + (kq ^ (brow & 7))) * 8];
    }
    __builtin_amdgcn_s_setprio(1);
#pragma unroll
    for (int j2 = 0; j2 < 2; ++j2)
#pragma unroll
      for (int i = 0; i < 4; ++i)
        acc[i][j2] = __builtin_amdgcn_mfma_f32_16x16x32_bf16(afr0[i], bfr0[j2],
                                                             acc[i][j2], 0, 0, 0);
    __builtin_amdgcn_s_setprio(0);
    // ---- ks = 1 ----
    bf16x8 afr1[4], bfr1[2];
#pragma unroll
    for (int i = 0; i < 4; ++i) {
      int row = wr * 64 + i * 16 + lr;
      afr1[i] = *(const bf16x8*)&Ac[(row * 8 + ((4 + kq) ^ (row & 7))) * 8];
    }
#pragma unroll
    for (int j2 = 0; j2 < 2; ++j2) {
      int brow = wc * 32 + j2 * 16 + lr;
      bfr1[j2] = *(const bf16x8*)&Bc[(brow * 8 + ((4 + kq) ^ (brow & 7))) * 8];
    }
    asm volatile("s_waitcnt lgkmcnt(0)" ::: "memory");
    __builtin_amdgcn_sched_barrier(0);
    __builtin_amdgcn_s_barrier();   // all waves' reads of buf[cur] done
    __builtin_amdgcn_sched_barrier(0);
    if (t + 2 < NT) stage(cur, (t + 2) << 6);
    __builtin_amdgcn_s_setprio(1);
#pragma unroll
    for (int j2 = 0; j2 < 2; ++j2)
#pragma unroll
      for (int i = 0; i < 4; ++i)
        acc[i][j2] = __builtin_amdgcn_mfma_f32_16x16x32_bf16(afr1[i], bfr1[j2],
                                                             acc[i][j2], 0, 0, 0);
    __builtin_amdgcn_s_setprio(0);
    cur ^= 1;
  }

#pragma unroll
  for (int i = 0; i < 4; ++i)
#pragma unroll
    for (int j = 0; j < 2; ++j) {
      int rowb = bm0 + wr * 64 + i * 16 + kq * 4;
      int col = bn0 + wc * 32 + j * 16 + lr;
#pragma unroll
      for (int r = 0; r < 4; ++r) {
        unsigned short v = f2bf(acc[i][j][r]);
        if (mode == 0)      qh[(size_t)(rowb + r) * 2048 + col] = v;
        else if (mode == 1) kh[(size_t)(rowb + r) * 512 + col] = v;
        else                vhT[(size_t)col * 4096 + (rowb + r)] = v;
      }
    }
}

// ===========================================================================
// Fused attention v9 (unchanged from R18): counted-vmcnt pipelines, single-
// barrier two-level softmax, NT attn stores, T5 setprio, XCD swizzle.
// ===========================================================================
__global__ __launch_bounds__(512, 4) void kattn(
    const unsigned short* __restrict__ qh,   // [b][n][h*128+d] ld 2048
    const unsigned short* __restrict__ kh,   // [b][n][g*128+d] ld 512
    const unsigned short* __restrict__ vT,   // [g*128+d][b*2048+key] ld 4096
    float* __restrict__ attn,                // [b][h][q][key]
    unsigned short* __restrict__ ctx) {      // [b][n][h*128+d] ld 2048
  __shared__ __align__(16) char U[65536];
  __shared__ __align__(16) char Vb[16384];
  float* redm = (float*)Vb;         // [8][16]
  float* reds = redm + 128;         // [8][16]

  const int tid = threadIdx.x;
  const int lane = tid & 63, w = tid >> 6;   // w 0..7
  const int lr = lane & 15, kq = lane >> 4;  // q = lr, quarter = kq
  const int bid = blockIdx.x;
  const int g8 = bid & 7;          // (b,g) slice, 0..7
  const int j  = bid >> 3;         // 0..511
  const int bz = g8 >> 2;          // batch
  const int gz = g8 & 3;           // kv group
  const int hz = gz * 4 + (j & 3); // head (hz>>2 == gz)
  const int q0 = (j >> 2) << 4;    // q-tile * 16
  const int z  = bz * 16 + hz;

  const unsigned short* Aq =
      qh + ((size_t)(bz * 2048 + q0 + lr) * 2048 + hz * 128);
  bf16x8 qfr[4];
#pragma unroll
  for (int kk = 0; kk < 4; ++kk)
    qfr[kk] = *(const bf16x8*)(Aq + kk * 32 + kq * 8);

  // --- scores: wave-private K staging, counted-vmcnt pipeline --------------
  const unsigned short* Kb =
      kh + ((size_t)(bz * 2048) * 512 + gz * 128);
  int krow[4], kcs[4];
#pragma unroll
  for (int R = 0; R < 4; ++R) {
    int idx = R * 64 + lane;
    krow[R] = idx >> 4;
    kcs[R] = (idx & 15) ^ (krow[R] & 7);  // pre-swizzled source chunk
  }
  auto stageK = [&](int buf, int t) {
#pragma unroll
    for (int R = 0; R < 4; ++R)
      ASYNC16(U + buf * 32768 + w * 4096 + (R * 64 + lane) * 16,
              Kb + (size_t)(t * 128 + w * 16 + krow[R]) * 512 + kcs[R] * 8);
  };

  f32x4 acc[16];
#pragma unroll
  for (int t = 0; t < 16; ++t) acc[t] = f32x4{0.f, 0.f, 0.f, 0.f};

  stageK(0, 0);
  stageK(1, 1);
#pragma unroll
  for (int t = 0; t < 16; ++t) {
    if (t < 15) asm volatile("s_waitcnt vmcnt(4)" ::: "memory");
    else        asm volatile("s_waitcnt vmcnt(0)" ::: "memory");
    __builtin_amdgcn_sched_barrier(0);
    const char* Kw = U + (t & 1) * 32768 + w * 4096;
    bf16x8 kfr[4];
#pragma unroll
    for (int kk = 0; kk < 4; ++kk) {
      int cch = (kk * 4 + kq) ^ (lr & 7);
      kfr[kk] = *(const bf16x8*)(Kw + lr * 256 + cch * 16);
    }
    asm volatile("s_waitcnt lgkmcnt(0)" ::: "memory");
    __builtin_amdgcn_sched_barrier(0);
    if (t + 2 < 16) stageK(t & 1, t + 2);  // reuse just-read buffer
    __builtin_amdgcn_s_setprio(1);
#pragma unroll
    for (int kk = 0; kk < 4; ++kk)
      acc[t] = __builtin_amdgcn_mfma_f32_16x16x32_bf16(kfr[kk], qfr[kk],
                                                       acc[t], 0, 0, 0);
    __builtin_amdgcn_s_setprio(0);
  }

  // --- softmax: two-level online reduce, ONE barrier -----------------------
  const float scale = 0.08838834764831845f;
  float mx = -3.4e38f;
#pragma unroll
  for (int t = 0; t < 16; ++t) {
    acc[t] *= scale;
#pragma unroll
    for (int r = 0; r < 4; ++r) mx = fmaxf(mx, acc[t][r]);
  }
  mx = fmaxf(mx, __shfl_xor(mx, 16));
  mx = fmaxf(mx, __shfl_xor(mx, 32));   // mx = wave-local row max
  float sm = 0.f;
#pragma unroll
  for (int t = 0; t < 16; ++t) {
#pragma unroll
    for (int r = 0; r < 4; ++r) {
      float e = __expf(acc[t][r] - mx);
      acc[t][r] = e;
      sm += e;
    }
  }
  sm += __shfl_xor(sm, 16);
  sm += __shfl_xor(sm, 32);            // sm = wave-local sum of exp(x-mx)
  if (kq == 0) { redm[w * 16 + lr] = mx; reds[w * 16 + lr] = sm; }
  __syncthreads();  // single softmax barrier
  float m = redm[lr];
#pragma unroll
  for (int ww = 1; ww < 8; ++ww) m = fmaxf(m, redm[ww * 16 + lr]);
  float s = 0.f;
#pragma unroll
  for (int ww = 0; ww < 8; ++ww)
    s += reds[ww * 16 + lr] * __expf(redm[ww * 16 + lr] - m);
  float invw = __expf(mx - m) / s;     // per-wave rescale folded into write

  // --- write attn f32 (NT) + P bf16 into U (swizzled chunks) ---------------
  float* arow = attn + (((size_t)z * 2048 + q0 + lr) * 2048);
#pragma unroll
  for (int t = 0; t < 16; ++t) {
    int key = t * 128 + w * 16 + kq * 4;
    f32x4 p = acc[t] * invw;
    __builtin_nontemporal_store(p, (f32x4*)(arow + key));
    bf16x4 pb;
#pragma unroll
    for (int r = 0; r < 4; ++r) pb[r] = (short)f2bf(p[r]);
    int c8 = key >> 3;  // 16B chunk index in q-row
    *(bf16x4*)(U + lr * 4096 + ((c8 ^ (lr & 7)) << 4) + ((key & 7) << 1)) = pb;
  }
  __syncthreads();  // barrier: P ready, red reads done, K staging drained

  // --- PV: wave-private V staging, counted-vmcnt pipeline ------------------
  const unsigned short* Bv = vT + (size_t)gz * 524288 + bz * 2048;
  const int d0 = w * 16;
  const int vd = lane >> 2;                 // 0..15 local d-row
  const int vcs = (lane & 3) ^ (vd & 3);    // pre-swizzled source chunk
  auto stageV = [&](int buf, int t) {
    ASYNC16(Vb + buf * 8192 + w * 1024 + lane * 16,
            Bv + (size_t)(d0 + vd) * 4096 + t * 32 + vcs * 8);
  };

  f32x4 cfr = {};
  stageV(0, 0);
  stageV(1, 1);
#pragma unroll
  for (int t = 0; t < 64; ++t) {
    if (t < 63) asm volatile("s_waitcnt vmcnt(1)" ::: "memory");
    else        asm volatile("s_waitcnt vmcnt(0)" ::: "memory");
    __builtin_amdgcn_sched_barrier(0);
    int c8 = t * 4 + kq;
    bf16x8 pfr = *(const bf16x8*)(U + lr * 4096 + ((c8 ^ (lr & 7)) << 4));
    const char* Vw = Vb + (t & 1) * 8192 + w * 1024;
    bf16x8 vfr = *(const bf16x8*)(Vw + lr * 64 + ((kq ^ (lr & 3)) << 4));
    asm volatile("s_waitcnt lgkmcnt(0)" ::: "memory");
    __builtin_amdgcn_sched_barrier(0);
    if (t + 2 < 64) stageV(t & 1, t + 2);  // reuse just-read buffer
    __builtin_amdgcn_s_setprio(1);
    cfr = __builtin_amdgcn_mfma_f32_16x16x32_bf16(pfr, vfr, cfr, 0, 0, 0);
    __builtin_amdgcn_s_setprio(0);
  }
#pragma unroll
  for (int r = 0; r < 4; ++r) {
    int q = kq * 4 + r;
    ctx[((size_t)(bz * 2048 + q0 + q) * 2048) + hz * 128 + d0 + lr] =
        f2bf(cfr[r]);
  }
}

// ===========================================================================
// 128x128 8-wave GEMM, BK=64 — depth-2 counted-vmcnt, XCD-chunked 1D grid.
// (wo and fc)
// ===========================================================================
template <bool OUT_BF16>
__global__ __launch_bounds__(512, 2) void gemm128(
    const unsigned short* __restrict__ A, const unsigned short* __restrict__ Bt,
    void* __restrict__ C_, int K, int lda, int ldb, int ldc) {
  __shared__ unsigned short As[2][128 * 64];  // 32 KB
  __shared__ unsigned short Bs[2][128 * 64];  // 32 KB
  const int tid = threadIdx.x;
  const int bid = blockIdx.x;
  const int xcd = bid & 7, ii = bid >> 3;       // ii 0..63
  const int my = (xcd >> 1) * 8 + (ii & 7);     // M-block 0..31
  const int nx = (xcd & 1) * 8 + (ii >> 3);     // N-block 0..15
  const int bm0 = my * 128, bn0 = nx * 128;
  const int lane = tid & 63, wid = tid >> 6;
  const int wr = wid >> 2, wc = wid & 3;        // 2M x 4N
  const int lr = lane & 15, kq = lane >> 4;

  f32x4 acc[4][2] = {};

  int sArow[2], sAcc[2];
#pragma unroll
  for (int R = 0; R < 2; ++R) {
    int c = R * 512 + tid;                    // 0..1023
    sArow[R] = c >> 3;
    sAcc[R]  = (c & 7) ^ (sArow[R] & 7);
  }

  auto stage = [&](int buf, int k0) {  // 4 loads/thread
#pragma unroll
    for (int R = 0; R < 2; ++R)
      ASYNC16(&As[buf][(R * 512 + tid) * 8],
              A + (size_t)(bm0 + sArow[R]) * lda + k0 + sAcc[R] * 8);
#pragma unroll
    for (int R = 0; R < 2; ++R)
      ASYNC16(&Bs[buf][(R * 512 + tid) * 8],
              Bt + (size_t)(bn0 + sArow[R]) * ldb + k0 + sAcc[R] * 8);
  };

  const int NT = K >> 6;
  stage(0, 0);
  stage(1, 64);
  int cur = 0;
  for (int t = 0; t < NT; ++t) {
    if (t + 1 < NT) asm volatile("s_waitcnt vmcnt(4)" ::: "memory");
    else            asm volatile("s_waitcnt vmcnt(0)" ::: "memory");
    __builtin_amdgcn_sched_barrier(0);
    __builtin_amdgcn_s_barrier();
    __builtin_amdgcn_sched_barrier(0);
    const unsigned short* Ac = As[cur];
    const unsigned short* Bc = Bs[cur];
    // ---- ks = 0 ----
    bf16x8 afr0[4], bfr0[2];
#pragma unroll
    for (int i = 0; i < 4; ++i) {
      int row = wr * 64 + i * 16 + lr;
      afr0[i] = *(const bf16x8*)&Ac[(row * 8 + (kq ^ (row & 7))) * 8];
    }
#pragma unroll
    for (int j2 = 0; j2 < 2; ++j2) {
      int brow = wc * 32 + j2 * 16 + lr;
      bfr0[j2] = *(const bf16x8*)&Bc[(brow * 8 + (kq ^ (brow & 7))) * 8];
    }
    __builtin_amdgcn_s_setprio(1);
#pragma unroll
    for (int j2 = 0; j2 < 2; ++j2)
#pragma unroll
      for (int i = 0; i < 4; ++i)
        acc[i][j2] = __builtin_amdgcn_mfma_f32_16x16x32_bf16(afr0[i], bfr0[j2],
                                                             acc[i][j2], 0, 0, 0);
    __builtin_amdgcn_s_setprio(0);
    // ---- ks = 1 ----
    bf16x8 afr1[4], bfr1[2];
#pragma unroll
    for (int i = 0; i < 4; ++i) {
      int row = wr * 64 + i * 16 + lr;
      afr1[i] = *(const bf16x8*)&Ac[(row * 8 + ((4 + kq) ^ (row & 7))) * 8];
    }
#pragma unroll
    for (int j2 = 0; j2 < 2; ++j2) {
      int brow = wc * 32 + j2 * 16 + lr;
      bfr1[j2] = *(const bf16x8*)&Bc[(brow * 8 + ((4 + kq) ^ (brow & 7))) * 8];
    }
    asm volatile("s_waitcnt lgkmcnt(0)" ::: "memory");
    __builtin_amdgcn_sched_barrier(0);
    __builtin_amdgcn_s_barrier();   // all waves' reads of buf[cur] done
    __builtin_amdgcn_sched_barrier(0);
    if (t + 2 < NT) stage(cur, (t + 2) << 6);
    __builtin_amdgcn_s_setprio(1);
#pragma unroll
    for (int j2 = 0; j2 < 2; ++j2)
#pragma unroll
      for (int i = 0; i < 4; ++i)
        acc[i][j2] = __builtin_amdgcn_mfma_f32_16x16x32_bf16(afr1[i], bfr1[j2],
                                                             acc[i][j2], 0, 0, 0);
    __builtin_amdgcn_s_setprio(0);
    cur ^= 1;
  }

#pragma unroll
  for (int i = 0; i < 4; ++i)
#pragma unroll
    for (int j = 0; j < 2; ++j) {
      int rowb = bm0 + wr * 64 + i * 16 + kq * 4;
      int col = bn0 + wc * 32 + j * 16 + lr;
#pragma unroll
      for (int r = 0; r < 4; ++r) {
        if constexpr (OUT_BF16)
          ((unsigned short*)C_)[(size_t)(rowb + r) * ldc + col] = f2bf(acc[i][j][r]);
        else
          ((float*)C_)[(size_t)(rowb + r) * ldc + col] = acc[i][j][r];
      }
    }
}

// ---- GeGLU dual GEMM: depth-2 schedule + XCD-chunked 1D grid ---------------
__global__ __launch_bounds__(512, 2) void gemm_geglu256(
    const unsigned short* __restrict__ A, const unsigned short* __restrict__ B1,
    const unsigned short* __restrict__ B2, unsigned short* __restrict__ H_,
    int K, int lda, int ldb, int ldc) {
  __shared__ unsigned short As[2][256 * 64];   // 64 KB
  __shared__ unsigned short B1s[2][128 * 64];  // 32 KB
  __shared__ unsigned short B2s[2][128 * 64];  // 32 KB
  const int tid = threadIdx.x;
  const int bid = blockIdx.x;
  const int xcd = bid & 7, ii = bid >> 3;        // ii 0..127
  const int my = (xcd >> 2) * 8 + (ii & 7);      // M-block 0..15
  const int nx = (xcd & 3) * 16 + (ii >> 3);     // N-block 0..63
  const int bm0 = my * 256, bn0 = nx * 128;
  const int lane = tid & 63, wid = tid >> 6;
  const int wr = wid >> 2, wc = wid & 3;
  const int lr = lane & 15, kq = lane >> 4;

  f32x4 accu[8][2] = {};
  f32x4 accg[8][2] = {};

  int sArow[4], sAcc[4], sBrow[2], sBcc[2];
#pragma unroll
  for (int R = 0; R < 4; ++R) {
    int c = R * 512 + tid;
    sArow[R] = c >> 3;
    sAcc[R]  = (c & 7) ^ (sArow[R] & 7);
  }
#pragma unroll
  for (int R = 0; R < 2; ++R) {
    int c = R * 512 + tid;
    sBrow[R] = c >> 3;
    sBcc[R]  = (c & 7) ^ (sBrow[R] & 7);
  }

  auto stage = [&](int buf, int k0) {  // 8 loads/thread
#pragma unroll
    for (int R = 0; R < 4; ++R)
      ASYNC16(&As[buf][(R * 512 + tid) * 8],
              A + (size_t)(bm0 + sArow[R]) * lda + k0 + sAcc[R] * 8);
#pragma unroll
    for (int R = 0; R < 2; ++R)
      ASYNC16(&B1s[buf][(R * 512 + tid) * 8],
              B1 + (size_t)(bn0 + sBrow[R]) * ldb + k0 + sBcc[R] * 8);
#pragma unroll
    for (int R = 0; R < 2; ++R)
      ASYNC16(&B2s[buf][(R * 512 + tid) * 8],
              B2 + (size_t)(bn0 + sBrow[R]) * ldb + k0 + sBcc[R] * 8);
  };

  const int NT = K >> 6;
  stage(0, 0);
  stage(1, 64);
  int cur = 0;
  for (int t = 0; t < NT; ++t) {
    if (t + 1 < NT) asm volatile("s_waitcnt vmcnt(8)" ::: "memory");
    else            asm volatile("s_waitcnt vmcnt(0)" ::: "memory");
    __builtin_amdgcn_sched_barrier(0);
    __builtin_amdgcn_s_barrier();
    __builtin_amdgcn_sched_barrier(0);
    const unsigned short* Ac = As[cur];
    const unsigned short* B1c = B1s[cur];
    const unsigned short* B2c = B2s[cur];
    // ---- ks = 0 ----
    bf16x8 afr0[8], b10[2], b20[2];
#pragma unroll
    for (int i = 0; i < 8; ++i) {
      int row = wr * 128 + i * 16 + lr;
      afr0[i] = *(const bf16x8*)&Ac[(row * 8 + (kq ^ (row & 7))) * 8];
    }
#pragma unroll
    for (int j2 = 0; j2 < 2; ++j2) {
      int brow = wc * 32 + j2 * 16 + lr;
      b10[j2] = *(const bf16x8*)&B1c[(brow * 8 + (kq ^ (brow & 7))) * 8];
      b20[j2] = *(const bf16x8*)&B2c[(brow * 8 + (kq ^ (brow & 7))) * 8];
    }
    __builtin_amdgcn_s_setprio(1);
#pragma unroll
    for (int j2 = 0; j2 < 2; ++j2)
#pragma unroll
      for (int i = 0; i < 8; ++i) {
        accu[i][j2] = __builtin_amdgcn_mfma_f32_16x16x32_bf16(afr0[i], b10[j2],
                                                              accu[i][j2], 0, 0, 0);
        accg[i][j2] = __builtin_amdgcn_mfma_f32_16x16x32_bf16(afr0[i], b20[j2],
                                                              accg[i][j2], 0, 0, 0);
      }
    __builtin_amdgcn_s_setprio(0);
    // ---- ks = 1 ----
    bf16x8 afr1[8], b11[2], b21[2];
#pragma unroll
    for (int i = 0; i < 8; ++i) {
      int row = wr * 128 + i * 16 + lr;
      afr1[i] = *(const bf16x8*)&Ac[(row * 8 + ((4 + kq) ^ (row & 7))) * 8];
    }
#pragma unroll
    for (int j2 = 0; j2 < 2; ++j2) {
      int brow = wc * 32 + j2 * 16 + lr;
      b11[j2] = *(const bf16x8*)&B1c[(brow * 8 + ((4 + kq) ^ (brow & 7))) * 8];
      b21[j2] = *(const bf16x8*)&B2c[(brow * 8 + ((4 + kq) ^ (brow & 7))) * 8];
    }
    asm volatile("s_waitcnt lgkmcnt(0)" ::: "memory");
    __builtin_amdgcn_sched_barrier(0);
    __builtin_amdgcn_s_barrier();
    __builtin_amdgcn_sched_barrier(0);
    if (t + 2 < NT) stage(cur, (t + 2) << 6);
    __builtin_amdgcn_s_setprio(1);
#pragma unroll
    for (int j2 = 0; j2 < 2; ++j2)
#pragma unroll
      for (int i = 0; i < 8; ++i) {
        accu[i][j2] = __builtin_amdgcn_mfma_f32_16x16x32_bf16(afr1[i], b11[j2],
                                                              accu[i][j2], 0, 0, 0);
        accg[i][j2] = __builtin_amdgcn_mfma_f32_16x16x32_bf16(afr1[i], b21[j2],
                                                              accg[i][j2], 0, 0, 0);
      }
    __builtin_amdgcn_s_setprio(0);
    cur ^= 1;
  }

#pragma unroll
  for (int i = 0; i < 8; ++i)
#pragma unroll
    for (int j = 0; j < 2; ++j) {
      int rowb = bm0 + wr * 128 + i * 16 + kq * 4;
      int col = bn0 + wc * 32 + j * 16 + lr;
#pragma unroll
      for (int r = 0; r < 4; ++r) {
        float u = accu[i][j][r];
        float g = accg[i][j][r];
        float tv = tanhf(0.7978845608028654f * (g + 0.044715f * g * g * g));
        float hv = u * 0.5f * g * (1.0f + tv);
        H_[(size_t)(rowb + r) * ldc + col] = f2bf(hv);
      }
    }
}

// ---------------------------------------------------------------------------
extern "C" void kernel_launch(void* const* d_in, const int* in_sizes, int n_in,
                              void* d_out, int out_size, void* d_ws, size_t ws_size,
                              hipStream_t stream) {
  const float* x   = (const float*)d_in[0];
  const float* wq  = (const float*)d_in[1];
  const float* wk  = (const float*)d_in[2];
  const float* wv  = (const float*)d_in[3];
  const float* wo  = (const float*)d_in[4];
  const float* w1  = (const float*)d_in[5];
  const float* w2  = (const float*)d_in[6];
  const float* n1w = (const float*)d_in[7];
  const float* n2w = (const float*)d_in[8];

  float* out    = (float*)d_out;
  float* x2_out = out;
  float* k_out  = out + 8388608;
  float* v_out  = out + 16777216;
  float* attn   = out + 25165824;  // 134,217,728 f32

  char* ws = (char*)d_ws;
  unsigned short* wqT  = (unsigned short*)(ws + 0);
  unsigned short* wkT  = (unsigned short*)(ws + 8388608);
  unsigned short* wvT  = (unsigned short*)(ws + 10485760);
  unsigned short* woT  = (unsigned short*)(ws + 12582912);
  unsigned short* w1T  = (unsigned short*)(ws + 20971520);
  unsigned short* w2T  = (unsigned short*)(ws + 88080384);
  unsigned short* qh   = (unsigned short*)(ws + 121634816);
  unsigned short* kh   = (unsigned short*)(ws + 138412032);
  unsigned short* vhT  = (unsigned short*)(ws + 142606336);
  unsigned short* ctx  = (unsigned short*)(ws + 146800640);
  unsigned short* aob  = (unsigned short*)(ws + 163577856);  // ao bf16
  unsigned short* hbuf = (unsigned short*)(ws + 121634816);  // alias qh..ao (dead)
  unsigned short* x1b  = (unsigned short*)(ws + 197132288);
  unsigned short* fc   = (unsigned short*)(ws + 213909504);
  // ws total: 230,686,720 bytes

  // bf16 scratch inside not-yet-written attn region of d_out
  unsigned short* xb = (unsigned short*)attn;   // bf16(x), 8,388,608 elems
  unsigned short* xq = xb + 8388608;            // bf16(rope(x))

  dim3 blk(256);
  dim3 blk512(512);

  // 1) prep: all weight conversions + RoPE/copy/casts in ONE launch
  kprep<<<dim3(75776), blk, 0, stream>>>(wq, wk, wv, wo, w1, w2, wqT, w2T,
                                         x, k_out, v_out, xq, xb);

  // 2) q/k/v projections in ONE launch (768 blocks)
  qkvgemm<<<dim3(768), blk512, 0, stream>>>(xq, xb, wqT, wkT, wvT, qh, kh, vhT);

  // 3) fused scores + softmax + attn write + PV -> ctx (XCD-swizzled 1D grid)
  kattn<<<dim3(4096), blk512, 0, stream>>>(qh, kh, vhT, attn, ctx);

  // 4) attn_out = ctx @ wo (bf16 out)
  gemm128<true><<<dim3(512), blk512, 0, stream>>>(
      ctx, woT, aob, 2048, 2048, 2048, 2048);
  // 5) x1b = rmsnorm(x + ao) * n1w
  krms1<<<4096, blk, 0, stream>>>(x, aob, n1w, x1b);
  // 6) h = u * gelu(gate)  (fused dual GEMM, uv never materialized)
  gemm_geglu256<<<dim3(1024), blk512, 0, stream>>>(
      x1b, w1T, w1T + 16777216, hbuf, 2048, 2048, 2048, 8192);
  // 7) fc = h @ w2
  gemm128<true><<<dim3(512), blk512, 0, stream>>>(
      hbuf, w2T, fc, 8192, 8192, 8192, 2048);
  // 8) x2 = rmsnorm(x1 + fc) * n2w
  krms2<<<4096, blk, 0, stream>>>(x1b, fc, n2w, x2_out);
}